// Round 1
// 1033.592 us; speedup vs baseline: 1.0498x; 1.0498x over previous
//
#include <hip/hip_runtime.h>

#define NN      50000
#define NE      800000
#define INCH    8
#define CH      128
#define EA      6
#define NB      2000
#define NB_PAD  2048
#define NCLS    32
#define FUS     384
#define K1      2816   // 1408 + 1024 + 384
#define SCAN_NBLK 49   // (NN + 1023) / 1024

typedef _Float16 half8 __attribute__((ext_vector_type(8)));
typedef _Float16 h2 __attribute__((ext_vector_type(2)));
typedef float f32x4 __attribute__((ext_vector_type(4)));

// ---------- degree of dst nodes ----------
__global__ __launch_bounds__(256) void k_deg(const int* __restrict__ edge,
                                             int* __restrict__ deg) {
  int e = blockIdx.x * 256 + threadIdx.x;
  if (e < NE) atomicAdd(&deg[edge[NE + e]], 1);
}

// ---------- parallel scan, phase 1: per-block inclusive scan + block sums ----
__global__ __launch_bounds__(1024) void k_scan1(const int* __restrict__ deg,
                                                int* __restrict__ row_ptr,
                                                int* __restrict__ bsum) {
  __shared__ int wsum[16];
  const int t = threadIdx.x, lane = t & 63, w = t >> 6;
  const int i = blockIdx.x * 1024 + t;
  int x = (i < NN) ? deg[i] : 0;
#pragma unroll
  for (int off = 1; off < 64; off <<= 1) {
    int y = __shfl_up(x, off, 64);
    if (lane >= off) x += y;
  }
  if (lane == 63) wsum[w] = x;
  __syncthreads();
  if (w == 0 && lane < 16) {
    int s = wsum[lane];
#pragma unroll
    for (int off = 1; off < 16; off <<= 1) {
      int y = __shfl_up(s, off, 64);
      if (lane >= off) s += y;
    }
    wsum[lane] = s;
  }
  __syncthreads();
  int incl = x + ((w == 0) ? 0 : wsum[w - 1]);
  if (i < NN) row_ptr[i + 1] = incl;
  if (t == 1023) bsum[blockIdx.x] = incl;
}

// ---------- phase 2: single-wave exclusive scan of block sums ----------
__global__ __launch_bounds__(64) void k_scan2(int* __restrict__ bsum) {
  const int t = threadIdx.x;
  int x = (t < SCAN_NBLK) ? bsum[t] : 0;
#pragma unroll
  for (int off = 1; off < 64; off <<= 1) {
    int y = __shfl_up(x, off, 64);
    if (t >= off) x += y;
  }
  int ex = __shfl_up(x, 1, 64);
  if (t == 0) ex = 0;
  if (t < SCAN_NBLK) bsum[t] = ex;
}

// ---------- phase 3: add block offsets ----------
__global__ __launch_bounds__(256) void k_scan3(const int* __restrict__ bsum,
                                               int* __restrict__ row_ptr) {
  const int i = blockIdx.x * 256 + threadIdx.x;
  if (i == 0) row_ptr[0] = 0;
  if (i < NN) row_ptr[i + 1] += bsum[i >> 10];
}

// ---------- fill CSR payload: dst-sorted src + f16 e_attr ----------
__global__ __launch_bounds__(256) void k_fill(
    const int* __restrict__ edge, const float* __restrict__ eattr,
    const int* __restrict__ row_ptr, int* __restrict__ cursor,
    int* __restrict__ ssrc, _Float16* __restrict__ sea8) {
  int e = blockIdx.x * 256 + threadIdx.x;
  if (e >= NE) return;
  int s = edge[e], d = edge[NE + e];
  int idx = row_ptr[d] + atomicAdd(&cursor[d], 1);
  ssrc[idx] = s;
  half8 v;
#pragma unroll
  for (int j = 0; j < EA; ++j) v[j] = (_Float16)eattr[(size_t)e * EA + j];
  v[6] = (_Float16)0.f; v[7] = (_Float16)0.f;
  *(half8*)(sea8 + (size_t)idx * 8) = v;
}

// ---------- segment starts from sorted bbox_idx ----------
__global__ __launch_bounds__(256) void k_segstart(const int* __restrict__ bbox,
                                                  int* __restrict__ seg) {
  int i = blockIdx.x * 256 + threadIdx.x;
  if (i >= NN) return;
  int bc = bbox[i];
  int bp = (i == 0) ? -1 : bbox[i - 1];
  for (int j = bp + 1; j <= bc; ++j) seg[j] = i;
  if (i == NN - 1)
    for (int j = bc + 1; j <= NB; ++j) seg[j] = NN;
}

// ---------- head node transform (K=8): scalar path -> interleaved f16 ----------
__global__ __launch_bounds__(256) void k_node_pq(
    const float* __restrict__ X, int ldx, int K,
    const float* __restrict__ W, const float* __restrict__ bias,
    _Float16* __restrict__ PQi, _Float16* __restrict__ Qi, int sel) {
  const int t = threadIdx.x, lane = t & 63, wv = t >> 6;
  const int nbase = blockIdx.x * 32 + wv * 8;
  const int c = lane * 2;
  const float2 bv = *(const float2*)(bias + c);
  float2 pacc[8], qacc[8];
#pragma unroll
  for (int u = 0; u < 8; ++u) { pacc[u] = bv; qacc[u] = make_float2(0.f, 0.f); }
  const int xrow = min(nbase + (lane >> 3), NN - 1);
  const int xk = lane & 7;
  for (int k0 = 0; k0 < K; k0 += 8) {
    const float xv = X[(size_t)xrow * ldx + k0 + xk];
#pragma unroll
    for (int j = 0; j < 8; ++j) {
      const float2 w1 = *(const float2*)(W + (size_t)(k0 + j) * CH + c);
      const float2 w2 = *(const float2*)(W + (size_t)(K + k0 + j) * CH + c);
      const float2 wd = {w1.x - w2.x, w1.y - w2.y};
#pragma unroll
      for (int u = 0; u < 8; ++u) {
        const float xs = __shfl(xv, u * 8 + j, 64);
        pacc[u].x += xs * wd.x; pacc[u].y += xs * wd.y;
        qacc[u].x += xs * w2.x; qacc[u].y += xs * w2.y;
      }
    }
  }
#pragma unroll
  for (int u = 0; u < 8; ++u) {
    const int node = nbase + u;
    if (node < NN) {
      const size_t o = ((size_t)node * 64 + lane) * 4 + sel * 2;
      *(h2*)(PQi + o) = (h2){(_Float16)pacc[u].x, (_Float16)pacc[u].y};
      *(h2*)(Qi + o)  = (h2){(_Float16)qacc[u].x, (_Float16)qacc[u].y};
    }
  }
}

// ---------- pack [W1-W2 | W2] (K=128 x N=256) into f16 B-fragments ----------
__global__ __launch_bounds__(64) void k_cvtWnpq(
    const float* __restrict__ WN, const float* __restrict__ WS,
    _Float16* __restrict__ whN, _Float16* __restrict__ whS) {
  const float* W = blockIdx.y ? WS : WN;
  _Float16* wh   = blockIdx.y ? whS : whN;
  const int c = blockIdx.x >> 4, tile = blockIdx.x & 15;
  const int L = threadIdx.x;
  const int n = tile * 16 + (L & 15);
  const int k0 = c * 32 + (L >> 4) * 8;
  half8 v;
#pragma unroll
  for (int j = 0; j < 8; ++j) {
    const int k = k0 + j;
    float val;
    if (n < CH) val = W[(size_t)k * CH + n] - W[(size_t)(CH + k) * CH + n];
    else        val = W[(size_t)(CH + k) * CH + (n - CH)];
    v[j] = (_Float16)val;
  }
  *(half8*)(wh + (((size_t)(c * 16 + tile)) * 64 + L) * 8) = v;
}

// ---------- residual node transform on matrix cores (both streams) ----------
__global__ __launch_bounds__(256) void k_npq_mfma(
    const float* __restrict__ Xn, const float* __restrict__ Xs, int ldx,
    const _Float16* __restrict__ whN, const _Float16* __restrict__ whS,
    const float* __restrict__ biasN, const float* __restrict__ biasS,
    _Float16* __restrict__ PQi, _Float16* __restrict__ Qi) {
  const int sel = blockIdx.y;
  const float* X = sel ? Xs : Xn;
  const _Float16* wh = sel ? whS : whN;
  const float* bias = sel ? biasS : biasN;
  const int t = threadIdx.x, lane = t & 63, wv = t >> 6;
  const int nbase = blockIdx.x * 64;
  const int m = lane & 15, quad = lane >> 4;
  f32x4 acc[4][4];
#pragma unroll
  for (int i = 0; i < 4; ++i)
#pragma unroll
    for (int nt = 0; nt < 4; ++nt) acc[i][nt] = (f32x4){0.f, 0.f, 0.f, 0.f};
#pragma unroll
  for (int ks = 0; ks < 4; ++ks) {
    half8 b[4];
#pragma unroll
    for (int nt = 0; nt < 4; ++nt)
      b[nt] = *(const half8*)(wh + (((size_t)(ks * 16 + wv * 4 + nt)) * 64 + lane) * 8);
#pragma unroll
    for (int i = 0; i < 4; ++i) {
      const int row = min(nbase + i * 16 + m, NN - 1);
      const float* src = X + (size_t)row * ldx + ks * 32 + quad * 8;
      const float4 f0 = *(const float4*)src;
      const float4 f1 = *(const float4*)(src + 4);
      half8 a;
      a[0] = (_Float16)f0.x; a[1] = (_Float16)f0.y;
      a[2] = (_Float16)f0.z; a[3] = (_Float16)f0.w;
      a[4] = (_Float16)f1.x; a[5] = (_Float16)f1.y;
      a[6] = (_Float16)f1.z; a[7] = (_Float16)f1.w;
#pragma unroll
      for (int nt = 0; nt < 4; ++nt)
        acc[i][nt] = __builtin_amdgcn_mfma_f32_16x16x32_f16(a, b[nt], acc[i][nt],
                                                            0, 0, 0);
    }
  }
#pragma unroll
  for (int i = 0; i < 4; ++i)
#pragma unroll
    for (int nt = 0; nt < 4; ++nt) {
      const int col = wv * 64 + nt * 16 + m;
      const float bv = (col < CH) ? bias[col] : 0.f;
#pragma unroll
      for (int r = 0; r < 4; ++r) {
        const int row = nbase + i * 16 + quad * 4 + r;
        if (row < NN) {
          const float v = acc[i][nt][r] + bv;
          if (col < CH)
            PQi[((size_t)row * 64 + (col >> 1)) * 4 + sel * 2 + (col & 1)] =
                (_Float16)v;
          else {
            const int qc = col - CH;
            Qi[((size_t)row * 64 + (qc >> 1)) * 4 + sel * 2 + (qc & 1)] =
                (_Float16)v;
          }
        }
      }
    }
}

// ---------- fused dual-stream CSR conv: interleaved PQ (1 gather/edge) ----------
__global__ __launch_bounds__(256) void k_conv2(
    const int* __restrict__ row_ptr, const int* __restrict__ ssrc,
    const _Float16* __restrict__ sea8,
    const _Float16* __restrict__ PQi, const _Float16* __restrict__ Qi,
    const float* __restrict__ Cn, const float* __restrict__ Cs,
    float* __restrict__ feats, float* __restrict__ sfeats,
    int cur, int prev) {
  const int t = threadIdx.x;
  const int lane = t & 63;
  const int node = blockIdx.x * 4 + (t >> 6);
  const int c = lane * 2;
  float2 cwn[EA], cws[EA];
#pragma unroll
  for (int j = 0; j < EA; ++j) {
    cwn[j] = *(const float2*)(Cn + j * CH + c);
    cws[j] = *(const float2*)(Cs + j * CH + c);
  }
  int i0 = __builtin_amdgcn_readfirstlane(row_ptr[node]);
  int i1 = __builtin_amdgcn_readfirstlane(row_ptr[node + 1]);
  const uint2 qv = *(const uint2*)(Qi + ((size_t)node * 64 + lane) * 4);
  const h2 qnh = *(const h2*)&qv.x;
  const h2 qsh = *(const h2*)&qv.y;
  const float2 qn = {(float)qnh[0], (float)qnh[1]};
  const float2 qs = {(float)qsh[0], (float)qsh[1]};
  float an0 = 0.f, an1 = 0.f, as0 = 0.f, as1 = 0.f;
  for (int base = i0; base < i1; base += 64) {
    const int cnt = min(64, i1 - base);
    int s_l = 0;
    uint4 ea_l = {0u, 0u, 0u, 0u};
    if (lane < cnt) {
      s_l = ssrc[base + lane];
      ea_l = *(const uint4*)(sea8 + (size_t)(base + lane) * 8);
    }
#define EDGE_BODY(J)                                                       \
    {                                                                      \
      int s = __shfl(s_l, (J), 64);                                        \
      unsigned w0 = __shfl((int)ea_l.x, (J), 64);                          \
      unsigned w1 = __shfl((int)ea_l.y, (J), 64);                          \
      unsigned w2 = __shfl((int)ea_l.z, (J), 64);                          \
      const h2 ha = *(const h2*)&w0;                                       \
      const h2 hb = *(const h2*)&w1;                                       \
      const h2 hc = *(const h2*)&w2;                                       \
      const float e0 = (float)ha[0], e1 = (float)ha[1];                    \
      const float e2 = (float)hb[0], e3 = (float)hb[1];                    \
      const float e4 = (float)hc[0], e5 = (float)hc[1];                    \
      const uint2 pv = *(const uint2*)(PQi + ((size_t)s * 64 + lane) * 4); \
      const h2 pnv = *(const h2*)&pv.x;                                    \
      const h2 psv = *(const h2*)&pv.y;                                    \
      float vn0 = (float)pnv[0] + qn.x, vn1 = (float)pnv[1] + qn.y;        \
      float vs0 = (float)psv[0] + qs.x, vs1 = (float)psv[1] + qs.y;        \
      vn0 += e0 * cwn[0].x; vn1 += e0 * cwn[0].y;                          \
      vs0 += e0 * cws[0].x; vs1 += e0 * cws[0].y;                          \
      vn0 += e1 * cwn[1].x; vn1 += e1 * cwn[1].y;                          \
      vs0 += e1 * cws[1].x; vs1 += e1 * cws[1].y;                          \
      vn0 += e2 * cwn[2].x; vn1 += e2 * cwn[2].y;                          \
      vs0 += e2 * cws[2].x; vs1 += e2 * cws[2].y;                          \
      vn0 += e3 * cwn[3].x; vn1 += e3 * cwn[3].y;                          \
      vs0 += e3 * cws[3].x; vs1 += e3 * cws[3].y;                          \
      vn0 += e4 * cwn[4].x; vn1 += e4 * cwn[4].y;                          \
      vs0 += e4 * cws[4].x; vs1 += e4 * cws[4].y;                          \
      vn0 += e5 * cwn[5].x; vn1 += e5 * cwn[5].y;                          \
      vs0 += e5 * cws[5].x; vs1 += e5 * cws[5].y;                          \
      an0 = fmaxf(an0, vn0); an1 = fmaxf(an1, vn1);                        \
      as0 += fmaxf(vs0, 0.f); as1 += fmaxf(vs1, 0.f);                      \
    }
    int j = 0;
    for (; j + 4 <= cnt; j += 4) {
      EDGE_BODY(j) EDGE_BODY(j + 1) EDGE_BODY(j + 2) EDGE_BODY(j + 3)
    }
    for (; j < cnt; ++j) EDGE_BODY(j)
#undef EDGE_BODY
  }
  const float inv = 1.f / fmaxf((float)(i1 - i0), 1.f);
  as0 *= inv; as1 *= inv;
  const size_t o = (size_t)node * FUS + (size_t)cur * CH + c;
  if (prev >= 0) {
    const size_t op = (size_t)node * FUS + (size_t)prev * CH + c;
    const float2 prn = *(const float2*)(feats + op);
    const float2 prs = *(const float2*)(sfeats + op);
    an0 += prn.x; an1 += prn.y;
    as0 += prs.x; as1 += prs.y;
  }
  float2 on = {an0, an1}, os = {as0, as1};
  *(float2*)(feats + o) = on;
  *(float2*)(sfeats + o) = os;
}

// ---------- pack feats -> f16 A-fragments: [rb][ks][i][lane][8] ----------
__global__ __launch_bounds__(64) void k_cvtApack(const float* __restrict__ feats,
                                                 _Float16* __restrict__ ap) {
  const int rb = blockIdx.x / 12, ks = blockIdx.x % 12;
  const int L = threadIdx.x, m = L & 15, quad = L >> 4;
#pragma unroll
  for (int i = 0; i < 4; ++i) {
    const int row = rb * 64 + i * 16 + m;
    const int rowc = min(row, NN - 1);
    const float* src = feats + (size_t)rowc * FUS + ks * 32 + quad * 8;
    half8 v;
    if (row < NN) {
      const float4 f0 = *(const float4*)src;
      const float4 f1 = *(const float4*)(src + 4);
      v[0] = (_Float16)f0.x; v[1] = (_Float16)f0.y;
      v[2] = (_Float16)f0.z; v[3] = (_Float16)f0.w;
      v[4] = (_Float16)f1.x; v[5] = (_Float16)f1.y;
      v[6] = (_Float16)f1.z; v[7] = (_Float16)f1.w;
    } else {
#pragma unroll
      for (int j = 0; j < 8; ++j) v[j] = (_Float16)0.f;
    }
    *(half8*)(ap + (((size_t)(rb * 12 + ks) * 4 + i) * 64 + L) * 8) = v;
  }
}

// ---------- convert + pack W (KxN f32) into f16 B-fragment order ----------
template <int N, int NT>
__global__ __launch_bounds__(64) void k_cvtB(const float* __restrict__ W,
                                             _Float16* __restrict__ wh) {
  const int c = blockIdx.x / NT;
  const int tile = blockIdx.x % NT;
  const int L = threadIdx.x;
  const int n = tile * 16 + (L & 15);
  const int k0 = c * 32 + (L >> 4) * 8;
  half8 v;
#pragma unroll
  for (int j = 0; j < 8; ++j) v[j] = (_Float16)W[(size_t)(k0 + j) * N + n];
  *(half8*)(wh + (((size_t)(c * NT + tile)) * 64 + L) * 8) = v;
}

// ---------- fusion GEMM + segment max ----
// 1D grid 784*8, XCD swizzle (xcd=fid&7). cg is now the FASTEST-varying
// index within an XCD (cg = slot&7, rb = xcd*98 + slot>>3): the 8 blocks
// sharing one rb's A-tile (49KB) dispatch back-to-back on the same XCD,
// so A re-reads hit the 4MB XCD L2 instead of thrashing it (old mapping
// streamed 98 rb x 49KB = 4.8MB between reuses -> HBM re-fetch).
__global__ __launch_bounds__(256) void k_pool_mfma(
    const _Float16* __restrict__ aP, const _Float16* __restrict__ wh,
    const int* __restrict__ bbox, const float* __restrict__ bf,
    float* __restrict__ pooled) {
  __shared__ float cl[64 * 132];
  const int t = threadIdx.x, lane = t & 63, wv = t >> 6;
  const int fid = blockIdx.x;
  const int xcd = fid & 7, slot = fid >> 3;
  const int cg = slot & 7;
  const int rb = xcd * 98 + (slot >> 3);
  const int nbase = rb * 64;
  const int m = lane & 15, quad = lane >> 4;
  f32x4 acc[4][2];
#pragma unroll
  for (int i = 0; i < 4; ++i)
#pragma unroll
    for (int nt = 0; nt < 2; ++nt) acc[i][nt] = (f32x4){0.f, 0.f, 0.f, 0.f};
  const _Float16* apb = aP + (size_t)rb * 12 * 2048 + (size_t)lane * 8;
  const _Float16* bp = wh + ((size_t)(cg * 8 + wv * 2) * 64 + lane) * 8;
#pragma unroll
  for (int ks = 0; ks < 12; ++ks) {
    const half8 b0 = *(const half8*)(bp + (size_t)ks * 32768);
    const half8 b1 = *(const half8*)(bp + (size_t)ks * 32768 + 512);
#pragma unroll
    for (int i = 0; i < 4; ++i) {
      const half8 a = *(const half8*)(apb + ((size_t)ks * 4 + i) * 512);
      acc[i][0] = __builtin_amdgcn_mfma_f32_16x16x32_f16(a, b0, acc[i][0], 0, 0, 0);
      acc[i][1] = __builtin_amdgcn_mfma_f32_16x16x32_f16(a, b1, acc[i][1], 0, 0, 0);
    }
  }
#pragma unroll
  for (int i = 0; i < 4; ++i)
#pragma unroll
    for (int nt = 0; nt < 2; ++nt) {
      const int col = wv * 32 + nt * 16 + m;
#pragma unroll
      for (int r = 0; r < 4; ++r)
        cl[(i * 16 + quad * 4 + r) * 132 + col] = acc[i][nt][r];
    }
  __syncthreads();
  {
    const int col = t & 127, rh = t >> 7;
    const int gcol = cg * 128 + col;
    const float bias = bf[gcol];
    int curb = -1;
    float mx = 0.f;
    for (int rr = 0; rr < 32; ++rr) {
      const int row = rh * 32 + rr;
      const int node = nbase + row;
      if (node >= NN) break;
      const int bid = bbox[node];
      const float v = fmaxf(cl[row * 132 + col] + bias, 0.f);
      if (bid != curb) {
        if (curb >= 0)
          atomicMax((unsigned*)(pooled + (size_t)curb * 1408 + gcol),
                    __float_as_uint(mx));
        curb = bid;
        mx = v;
      } else {
        mx = fmaxf(mx, v);
      }
    }
    if (curb >= 0)
      atomicMax((unsigned*)(pooled + (size_t)curb * 1408 + gcol),
                __float_as_uint(mx));
  }
}

// ---------- raw-feats bbox max + sfeats bbox mean ----------
__global__ __launch_bounds__(256) void k_poolraw(
    const float* __restrict__ feats, const float* __restrict__ sfeats,
    const int* __restrict__ seg, float* __restrict__ pooled,
    float* __restrict__ sb) {
  const int b = blockIdx.x, t = threadIdx.x;
  if (t >= 192) return;
  const int c2 = t * 2;
  const int n0 = __builtin_amdgcn_readfirstlane(seg[b]);
  const int n1 = __builtin_amdgcn_readfirstlane(seg[b + 1]);
  float2 fmx = {0.f, 0.f}, ss = {0.f, 0.f};
  for (int n = n0; n < n1; ++n) {
    const float2 f2 = *(const float2*)(feats + (size_t)n * FUS + c2);
    fmx.x = fmaxf(fmx.x, f2.x); fmx.y = fmaxf(fmx.y, f2.y);
    const float2 s2 = *(const float2*)(sfeats + (size_t)n * FUS + c2);
    ss.x += s2.x; ss.y += s2.y;
  }
  *(float2*)(pooled + (size_t)b * 1408 + 1024 + c2) = fmx;
  const float inv = 1.f / fmaxf((float)(n1 - n0), 1.f);
  float2 o = {ss.x * inv, ss.y * inv};
  *(float2*)(sb + (size_t)b * FUS + c2) = o;
}

// ---------- fusion_super = relu(sb @ Wfs + bfs), lane-distributed x ----------
__global__ __launch_bounds__(256) void k_fusion_super(
    const float* __restrict__ sb, const float* __restrict__ Wfs,
    const float* __restrict__ bfs, float* __restrict__ fs) {
  const int t = threadIdx.x, lane = t & 63, wv = t >> 6;
  const int r0 = blockIdx.x * 4;
  const int c = (blockIdx.y * 4 + wv) * 128 + lane * 2;
  float2 acc[4];
#pragma unroll
  for (int u = 0; u < 4; ++u) acc[u] = make_float2(0.f, 0.f);
  const int xr = r0 + (lane >> 4), xk = lane & 15;
  for (int k0 = 0; k0 < FUS; k0 += 16) {
    const float xv = sb[(size_t)xr * FUS + k0 + xk];
#pragma unroll
    for (int j = 0; j < 16; ++j) {
      const float2 w = *(const float2*)(Wfs + (size_t)(k0 + j) * 1024 + c);
#pragma unroll
      for (int u = 0; u < 4; ++u) {
        const float xs = __shfl(xv, u * 16 + j, 64);
        acc[u].x += xs * w.x; acc[u].y += xs * w.y;
      }
    }
  }
  const float2 b = *(const float2*)(bfs + c);
#pragma unroll
  for (int u = 0; u < 4; ++u) {
    float2 o = {fmaxf(acc[u].x + b.x, 0.f), fmaxf(acc[u].y + b.y, 0.f)};
    *(float2*)(fs + (size_t)(r0 + u) * 1024 + c) = o;
  }
}

// ---------- concat [pooled | fsup | sb] -> f16 bbH[NB_PAD][K1], zero-padded ----
__global__ __launch_bounds__(256) void k_cvt_cat(
    const float* __restrict__ pooled, const float* __restrict__ fsup,
    const float* __restrict__ sb, _Float16* __restrict__ bbH) {
  const size_t off = ((size_t)blockIdx.x * 256 + threadIdx.x) * 8;
  const int row = (int)(off / K1);
  const int col = (int)(off - (size_t)row * K1);
  half8 v;
  if (row < NB) {
    const float* src;
    if (col < 1408)      src = pooled + (size_t)row * 1408 + col;
    else if (col < 2432) src = fsup + (size_t)row * 1024 + (col - 1408);
    else                 src = sb + (size_t)row * FUS + (col - 2432);
    const float4 f0 = *(const float4*)src;
    const float4 f1 = *(const float4*)(src + 4);
    v[0] = (_Float16)f0.x; v[1] = (_Float16)f0.y;
    v[2] = (_Float16)f0.z; v[3] = (_Float16)f0.w;
    v[4] = (_Float16)f1.x; v[5] = (_Float16)f1.y;
    v[6] = (_Float16)f1.z; v[7] = (_Float16)f1.w;
  } else {
#pragma unroll
    for (int j = 0; j < 8; ++j) v[j] = (_Float16)0.f;
  }
  *(half8*)(bbH + off) = v;
}

// ---------- h1 = relu(bbH @ W1 + b1) on matrix cores ----------
__global__ __launch_bounds__(256) void k_mlp1_mfma(
    const _Float16* __restrict__ bbH, const _Float16* __restrict__ wh,
    const float* __restrict__ b1, float* __restrict__ h1) {
  const int t = threadIdx.x, lane = t & 63, wv = t >> 6;
  const int nbase = blockIdx.x * 64;
  const int cg = blockIdx.y;
  const int m = lane & 15, quad = lane >> 4;
  f32x4 acc[4][2];
#pragma unroll
  for (int i = 0; i < 4; ++i)
#pragma unroll
    for (int nt = 0; nt < 2; ++nt) acc[i][nt] = (f32x4){0.f, 0.f, 0.f, 0.f};
  const _Float16* ap = bbH + (size_t)(nbase + m) * K1 + quad * 8;
  const _Float16* bp = wh + ((size_t)(cg * 8 + wv * 2) * 64 + lane) * 8;
#pragma unroll 4
  for (int ks = 0; ks < 88; ++ks) {
    const half8 b0 = *(const half8*)(bp + (size_t)ks * 16384);
    const half8 b1v = *(const half8*)(bp + (size_t)ks * 16384 + 512);
#pragma unroll
    for (int i = 0; i < 4; ++i) {
      const half8 a = *(const half8*)(ap + (size_t)(i * 16) * K1 + ks * 32);
      acc[i][0] = __builtin_amdgcn_mfma_f32_16x16x32_f16(a, b0, acc[i][0], 0, 0, 0);
      acc[i][1] = __builtin_amdgcn_mfma_f32_16x16x32_f16(a, b1v, acc[i][1], 0, 0, 0);
    }
  }
#pragma unroll
  for (int i = 0; i < 4; ++i)
#pragma unroll
    for (int nt = 0; nt < 2; ++nt) {
      const int gcol = cg * 128 + wv * 32 + nt * 16 + m;
      const float bias = b1[gcol];
#pragma unroll
      for (int r = 0; r < 4; ++r) {
        const int row = nbase + i * 16 + quad * 4 + r;
        if (row < NB)
          h1[(size_t)row * 512 + gcol] = fmaxf(acc[i][nt][r] + bias, 0.f);
      }
    }
}

// ---------- h2 = relu(h1 @ W2 + b2) ----------
__global__ __launch_bounds__(256) void k_mlp2(
    const float* __restrict__ h1, const float* __restrict__ W2,
    const float* __restrict__ b2, float* __restrict__ h2o) {
  const int r0 = blockIdx.x * 8, t = threadIdx.x;
  float acc[8];
#pragma unroll
  for (int u = 0; u < 8; ++u) acc[u] = 0.f;
  for (int k = 0; k < 512; ++k) {
    float w = W2[(size_t)k * 256 + t];
#pragma unroll
    for (int u = 0; u < 8; ++u) acc[u] += h1[(size_t)(r0 + u) * 512 + k] * w;
  }
  float bv = b2[t];
#pragma unroll
  for (int u = 0; u < 8; ++u)
    h2o[(size_t)(r0 + u) * 256 + t] = fmaxf(acc[u] + bv, 0.f);
}

// ---------- logits = h2 @ W3 + b3 ----------
__global__ __launch_bounds__(256) void k_mlp3(
    const float* __restrict__ h2i, const float* __restrict__ W3,
    const float* __restrict__ b3, float* __restrict__ out) {
  const int r0 = blockIdx.x * 8, t = threadIdx.x;
  const int u = t >> 5, oc = t & 31;
  const float* x = h2i + (size_t)(r0 + u) * 256;
  float acc = 0.f;
  for (int k = 0; k < 256; ++k) acc += x[k] * W3[(size_t)k * 32 + oc];
  out[(size_t)(r0 + u) * 32 + oc] = acc + b3[oc];
}

extern "C" void kernel_launch(void* const* d_in, const int* in_sizes, int n_in,
                              void* d_out, int out_size, void* d_ws, size_t ws_size,
                              hipStream_t stream) {
  const float* x     = (const float*)d_in[0];
  const float* eattr = (const float*)d_in[1];
  const float* W_h   = (const float*)d_in[2];
  const float* b_h   = (const float*)d_in[3];
  const float* Ws_h  = (const float*)d_in[4];
  const float* bs_h  = (const float*)d_in[5];
  const float* Wb    = (const float*)d_in[6];
  const float* bb    = (const float*)d_in[7];
  const float* Wbs   = (const float*)d_in[8];
  const float* bbs   = (const float*)d_in[9];
  const float* W_f   = (const float*)d_in[10];
  const float* b_f   = (const float*)d_in[11];
  const float* W_fs  = (const float*)d_in[12];
  const float* b_fs  = (const float*)d_in[13];
  const float* W1    = (const float*)d_in[14];
  const float* b1    = (const float*)d_in[15];
  const float* W2    = (const float*)d_in[16];
  const float* b2    = (const float*)d_in[17];
  const float* W3    = (const float*)d_in[18];
  const float* b3    = (const float*)d_in[19];
  const int*   edge  = (const int*)d_in[20];
  const int*   bbox  = (const int*)d_in[21];
  float* out = (float*)d_out;

  // ---- workspace layout (~221.5 MB; known-good budget >= 233 MB) ----
  float* p = (float*)d_ws;
  float* feats  = p; p += (size_t)NN * FUS;
  float* sfeats = p; p += (size_t)NN * FUS;
  float* PQ     = p; p += (size_t)2 * NN * CH;    // 12.8M floats
  _Float16* PQi = (_Float16*)PQ;
  _Float16* Qi  = PQi + (size_t)NN * 256;
  // overlays inside PQ (live only AFTER the last k_conv2):
  _Float16* aPack = (_Float16*)PQ;
  _Float16* WfH   = aPack + (size_t)784 * 12 * 2048;
  float* pooled   = (float*)(WfH + (size_t)FUS * 1024);
  float* sb   = PQ;
  float* fsup = sb + (size_t)NB * FUS;
  float* h1   = fsup + (size_t)NB * 1024;
  float* h2b  = h1 + (size_t)NB * 512;
  _Float16* bbH = (_Float16*)(h2b + (size_t)NB * 256);
  _Float16* W1H = bbH + (size_t)NB_PAD * K1;
  // CSR payload + misc after PQ region:
  _Float16* sea8 = (_Float16*)p;
  int* ssrc    = (int*)(sea8 + (size_t)NE * 8);
  int* row_ptr = ssrc + NE;
  int* deg     = row_ptr + NN + 1;
  int* cursor  = deg + NN;
  int* seg     = cursor + NN;
  _Float16* WcatN = (_Float16*)(seg + NB + 1);
  _Float16* WcatS = WcatN + (size_t)128 * 256;
  int* bsum = (int*)(WcatS + (size_t)128 * 256);

  hipMemsetAsync(deg, 0, 2 * NN * sizeof(int), stream);  // deg + cursor

  // ---- CSR build (dst-sorted payload, parallel scan) + bbox segments ----
  k_deg<<<(NE + 255) / 256, 256, 0, stream>>>(edge, deg);
  k_scan1<<<SCAN_NBLK, 1024, 0, stream>>>(deg, row_ptr, bsum);
  k_scan2<<<1, 64, 0, stream>>>(bsum);
  k_scan3<<<(NN + 255) / 256, 256, 0, stream>>>(bsum, row_ptr);
  k_fill<<<(NE + 255) / 256, 256, 0, stream>>>(edge, eattr, row_ptr, cursor,
                                               ssrc, sea8);
  k_segstart<<<(NN + 255) / 256, 256, 0, stream>>>(bbox, seg);

  const int npq_grid = (NN + 31) / 32;

  // ---- conv 0 (head): both streams read x (K=8), scalar node transform ----
  k_node_pq<<<npq_grid, 256, 0, stream>>>(x, INCH, INCH, W_h, b_h, PQi, Qi, 0);
  k_node_pq<<<npq_grid, 256, 0, stream>>>(x, INCH, INCH, Ws_h, bs_h, PQi, Qi, 1);
  k_conv2<<<NN / 4, 256, 0, stream>>>(row_ptr, ssrc, sea8, PQi, Qi,
                                      W_h + 2 * INCH * CH, Ws_h + 2 * INCH * CH,
                                      feats, sfeats, 0, -1);

  // ---- residual blocks (K=128): MFMA node transform, both streams ----
  for (int i = 0; i < 2; ++i) {
    const float* Wi  = Wb  + (size_t)i * 262 * CH;
    const float* bi  = bb  + (size_t)i * CH;
    const float* Wsi = Wbs + (size_t)i * 262 * CH;
    const float* bsi = bbs + (size_t)i * CH;
    k_cvtWnpq<<<dim3(64, 2), 64, 0, stream>>>(Wi, Wsi, WcatN, WcatS);
    k_npq_mfma<<<dim3((NN + 63) / 64, 2), 256, 0, stream>>>(
        feats + i * CH, sfeats + i * CH, FUS, WcatN, WcatS, bi, bsi, PQi, Qi);
    k_conv2<<<NN / 4, 256, 0, stream>>>(row_ptr, ssrc, sea8, PQi, Qi,
                                        Wi + 2 * CH * CH, Wsi + 2 * CH * CH,
                                        feats, sfeats, i + 1, i);
  }

  // ---- pooling: packed-A f16 convert + MFMA GEMM + atomicMax ----
  k_cvtApack<<<784 * 12, 64, 0, stream>>>(feats, aPack);
  k_cvtB<1024, 64><<<12 * 64, 64, 0, stream>>>(W_f, WfH);
  hipMemsetAsync(pooled, 0, (size_t)NB * 1408 * sizeof(float), stream);
  k_pool_mfma<<<784 * 8, 256, 0, stream>>>(aPack, WfH, bbox, b_f, pooled);
  k_poolraw<<<NB, 256, 0, stream>>>(feats, sfeats, seg, pooled, sb);
  k_fusion_super<<<dim3(NB / 4, 2), 256, 0, stream>>>(sb, W_fs, b_fs, fsup);

  // ---- head MLP: concat->f16, W1->f16 frag, MFMA GEMM, then small MLPs ----
  k_cvt_cat<<<(int)(((size_t)NB_PAD * K1 / 8) / 256), 256, 0, stream>>>(
      pooled, fsup, sb, bbH);
  k_cvtB<512, 32><<<88 * 32, 64, 0, stream>>>(W1, W1H);
  k_mlp1_mfma<<<dim3(NB_PAD / 64, 4), 256, 0, stream>>>(bbH, W1H, b1, h1);
  k_mlp2<<<NB / 8, 256, 0, stream>>>(h1, W2, b2, h2b);
  k_mlp3<<<NB / 8, 256, 0, stream>>>(h2b, W3, b3, out);
}

// Round 2
// 1008.425 us; speedup vs baseline: 1.0760x; 1.0250x over previous
//
#include <hip/hip_runtime.h>

#define NN      50000
#define NE      800000
#define INCH    8
#define CH      128
#define EA      6
#define NB      2000
#define NB_PAD  2048
#define NCLS    32
#define FUS     384
#define K1      2816   // 1408 + 1024 + 384
#define SCAN_NBLK 49   // (NN + 1023) / 1024

typedef _Float16 half8 __attribute__((ext_vector_type(8)));
typedef _Float16 h2 __attribute__((ext_vector_type(2)));
typedef float f32x4 __attribute__((ext_vector_type(4)));

// ---------- degree of dst nodes ----------
__global__ __launch_bounds__(256) void k_deg(const int* __restrict__ edge,
                                             int* __restrict__ deg) {
  int e = blockIdx.x * 256 + threadIdx.x;
  if (e < NE) atomicAdd(&deg[edge[NE + e]], 1);
}

// ---------- parallel scan, phase 1: per-block inclusive scan + block sums ----
__global__ __launch_bounds__(1024) void k_scan1(const int* __restrict__ deg,
                                                int* __restrict__ row_ptr,
                                                int* __restrict__ bsum) {
  __shared__ int wsum[16];
  const int t = threadIdx.x, lane = t & 63, w = t >> 6;
  const int i = blockIdx.x * 1024 + t;
  int x = (i < NN) ? deg[i] : 0;
#pragma unroll
  for (int off = 1; off < 64; off <<= 1) {
    int y = __shfl_up(x, off, 64);
    if (lane >= off) x += y;
  }
  if (lane == 63) wsum[w] = x;
  __syncthreads();
  if (w == 0 && lane < 16) {
    int s = wsum[lane];
#pragma unroll
    for (int off = 1; off < 16; off <<= 1) {
      int y = __shfl_up(s, off, 64);
      if (lane >= off) s += y;
    }
    wsum[lane] = s;
  }
  __syncthreads();
  int incl = x + ((w == 0) ? 0 : wsum[w - 1]);
  if (i < NN) row_ptr[i + 1] = incl;
  if (t == 1023) bsum[blockIdx.x] = incl;
}

// ---------- phase 2: single-wave exclusive scan of block sums ----------
__global__ __launch_bounds__(64) void k_scan2(int* __restrict__ bsum) {
  const int t = threadIdx.x;
  int x = (t < SCAN_NBLK) ? bsum[t] : 0;
#pragma unroll
  for (int off = 1; off < 64; off <<= 1) {
    int y = __shfl_up(x, off, 64);
    if (t >= off) x += y;
  }
  int ex = __shfl_up(x, 1, 64);
  if (t == 0) ex = 0;
  if (t < SCAN_NBLK) bsum[t] = ex;
}

// ---------- phase 3: add block offsets ----------
__global__ __launch_bounds__(256) void k_scan3(const int* __restrict__ bsum,
                                               int* __restrict__ row_ptr) {
  const int i = blockIdx.x * 256 + threadIdx.x;
  if (i == 0) row_ptr[0] = 0;
  if (i < NN) row_ptr[i + 1] += bsum[i >> 10];
}

// ---------- fill CSR payload: dst-sorted src + f16 e_attr ----------
__global__ __launch_bounds__(256) void k_fill(
    const int* __restrict__ edge, const float* __restrict__ eattr,
    const int* __restrict__ row_ptr, int* __restrict__ cursor,
    int* __restrict__ ssrc, _Float16* __restrict__ sea8) {
  int e = blockIdx.x * 256 + threadIdx.x;
  if (e >= NE) return;
  int s = edge[e], d = edge[NE + e];
  int idx = row_ptr[d] + atomicAdd(&cursor[d], 1);
  ssrc[idx] = s;
  half8 v;
#pragma unroll
  for (int j = 0; j < EA; ++j) v[j] = (_Float16)eattr[(size_t)e * EA + j];
  v[6] = (_Float16)0.f; v[7] = (_Float16)0.f;
  *(half8*)(sea8 + (size_t)idx * 8) = v;
}

// ---------- segment starts from sorted bbox_idx ----------
__global__ __launch_bounds__(256) void k_segstart(const int* __restrict__ bbox,
                                                  int* __restrict__ seg) {
  int i = blockIdx.x * 256 + threadIdx.x;
  if (i >= NN) return;
  int bc = bbox[i];
  int bp = (i == 0) ? -1 : bbox[i - 1];
  for (int j = bp + 1; j <= bc; ++j) seg[j] = i;
  if (i == NN - 1)
    for (int j = bc + 1; j <= NB; ++j) seg[j] = NN;
}

// ---------- head node transform (K=8): scalar path -> interleaved f16 ----------
__global__ __launch_bounds__(256) void k_node_pq(
    const float* __restrict__ X, int ldx, int K,
    const float* __restrict__ W, const float* __restrict__ bias,
    _Float16* __restrict__ PQi, _Float16* __restrict__ Qi, int sel) {
  const int t = threadIdx.x, lane = t & 63, wv = t >> 6;
  const int nbase = blockIdx.x * 32 + wv * 8;
  const int c = lane * 2;
  const float2 bv = *(const float2*)(bias + c);
  float2 pacc[8], qacc[8];
#pragma unroll
  for (int u = 0; u < 8; ++u) { pacc[u] = bv; qacc[u] = make_float2(0.f, 0.f); }
  const int xrow = min(nbase + (lane >> 3), NN - 1);
  const int xk = lane & 7;
  for (int k0 = 0; k0 < K; k0 += 8) {
    const float xv = X[(size_t)xrow * ldx + k0 + xk];
#pragma unroll
    for (int j = 0; j < 8; ++j) {
      const float2 w1 = *(const float2*)(W + (size_t)(k0 + j) * CH + c);
      const float2 w2 = *(const float2*)(W + (size_t)(K + k0 + j) * CH + c);
      const float2 wd = {w1.x - w2.x, w1.y - w2.y};
#pragma unroll
      for (int u = 0; u < 8; ++u) {
        const float xs = __shfl(xv, u * 8 + j, 64);
        pacc[u].x += xs * wd.x; pacc[u].y += xs * wd.y;
        qacc[u].x += xs * w2.x; qacc[u].y += xs * w2.y;
      }
    }
  }
#pragma unroll
  for (int u = 0; u < 8; ++u) {
    const int node = nbase + u;
    if (node < NN) {
      const size_t o = ((size_t)node * 64 + lane) * 4 + sel * 2;
      *(h2*)(PQi + o) = (h2){(_Float16)pacc[u].x, (_Float16)pacc[u].y};
      *(h2*)(Qi + o)  = (h2){(_Float16)qacc[u].x, (_Float16)qacc[u].y};
    }
  }
}

// ---------- pack [W1-W2 | W2] (K=128 x N=256) into f16 B-fragments ----------
__global__ __launch_bounds__(64) void k_cvtWnpq(
    const float* __restrict__ WN, const float* __restrict__ WS,
    _Float16* __restrict__ whN, _Float16* __restrict__ whS) {
  const float* W = blockIdx.y ? WS : WN;
  _Float16* wh   = blockIdx.y ? whS : whN;
  const int c = blockIdx.x >> 4, tile = blockIdx.x & 15;
  const int L = threadIdx.x;
  const int n = tile * 16 + (L & 15);
  const int k0 = c * 32 + (L >> 4) * 8;
  half8 v;
#pragma unroll
  for (int j = 0; j < 8; ++j) {
    const int k = k0 + j;
    float val;
    if (n < CH) val = W[(size_t)k * CH + n] - W[(size_t)(CH + k) * CH + n];
    else        val = W[(size_t)(CH + k) * CH + (n - CH)];
    v[j] = (_Float16)val;
  }
  *(half8*)(wh + (((size_t)(c * 16 + tile)) * 64 + L) * 8) = v;
}

// ---------- residual node transform on matrix cores (both streams) ----------
__global__ __launch_bounds__(256) void k_npq_mfma(
    const float* __restrict__ Xn, const float* __restrict__ Xs, int ldx,
    const _Float16* __restrict__ whN, const _Float16* __restrict__ whS,
    const float* __restrict__ biasN, const float* __restrict__ biasS,
    _Float16* __restrict__ PQi, _Float16* __restrict__ Qi) {
  const int sel = blockIdx.y;
  const float* X = sel ? Xs : Xn;
  const _Float16* wh = sel ? whS : whN;
  const float* bias = sel ? biasS : biasN;
  const int t = threadIdx.x, lane = t & 63, wv = t >> 6;
  const int nbase = blockIdx.x * 64;
  const int m = lane & 15, quad = lane >> 4;
  f32x4 acc[4][4];
#pragma unroll
  for (int i = 0; i < 4; ++i)
#pragma unroll
    for (int nt = 0; nt < 4; ++nt) acc[i][nt] = (f32x4){0.f, 0.f, 0.f, 0.f};
#pragma unroll
  for (int ks = 0; ks < 4; ++ks) {
    half8 b[4];
#pragma unroll
    for (int nt = 0; nt < 4; ++nt)
      b[nt] = *(const half8*)(wh + (((size_t)(ks * 16 + wv * 4 + nt)) * 64 + lane) * 8);
#pragma unroll
    for (int i = 0; i < 4; ++i) {
      const int row = min(nbase + i * 16 + m, NN - 1);
      const float* src = X + (size_t)row * ldx + ks * 32 + quad * 8;
      const float4 f0 = *(const float4*)src;
      const float4 f1 = *(const float4*)(src + 4);
      half8 a;
      a[0] = (_Float16)f0.x; a[1] = (_Float16)f0.y;
      a[2] = (_Float16)f0.z; a[3] = (_Float16)f0.w;
      a[4] = (_Float16)f1.x; a[5] = (_Float16)f1.y;
      a[6] = (_Float16)f1.z; a[7] = (_Float16)f1.w;
#pragma unroll
      for (int nt = 0; nt < 4; ++nt)
        acc[i][nt] = __builtin_amdgcn_mfma_f32_16x16x32_f16(a, b[nt], acc[i][nt],
                                                            0, 0, 0);
    }
  }
#pragma unroll
  for (int i = 0; i < 4; ++i)
#pragma unroll
    for (int nt = 0; nt < 4; ++nt) {
      const int col = wv * 64 + nt * 16 + m;
      const float bv = (col < CH) ? bias[col] : 0.f;
#pragma unroll
      for (int r = 0; r < 4; ++r) {
        const int row = nbase + i * 16 + quad * 4 + r;
        if (row < NN) {
          const float v = acc[i][nt][r] + bv;
          if (col < CH)
            PQi[((size_t)row * 64 + (col >> 1)) * 4 + sel * 2 + (col & 1)] =
                (_Float16)v;
          else {
            const int qc = col - CH;
            Qi[((size_t)row * 64 + (qc >> 1)) * 4 + sel * 2 + (qc & 1)] =
                (_Float16)v;
          }
        }
      }
    }
}

// ---------- fused dual-stream CSR conv: interleaved PQ (1 gather/edge) ----------
__global__ __launch_bounds__(256) void k_conv2(
    const int* __restrict__ row_ptr, const int* __restrict__ ssrc,
    const _Float16* __restrict__ sea8,
    const _Float16* __restrict__ PQi, const _Float16* __restrict__ Qi,
    const float* __restrict__ Cn, const float* __restrict__ Cs,
    float* __restrict__ feats, float* __restrict__ sfeats,
    int cur, int prev) {
  const int t = threadIdx.x;
  const int lane = t & 63;
  const int node = blockIdx.x * 4 + (t >> 6);
  const int c = lane * 2;
  float2 cwn[EA], cws[EA];
#pragma unroll
  for (int j = 0; j < EA; ++j) {
    cwn[j] = *(const float2*)(Cn + j * CH + c);
    cws[j] = *(const float2*)(Cs + j * CH + c);
  }
  int i0 = __builtin_amdgcn_readfirstlane(row_ptr[node]);
  int i1 = __builtin_amdgcn_readfirstlane(row_ptr[node + 1]);
  const uint2 qv = *(const uint2*)(Qi + ((size_t)node * 64 + lane) * 4);
  const h2 qnh = *(const h2*)&qv.x;
  const h2 qsh = *(const h2*)&qv.y;
  const float2 qn = {(float)qnh[0], (float)qnh[1]};
  const float2 qs = {(float)qsh[0], (float)qsh[1]};
  float an0 = 0.f, an1 = 0.f, as0 = 0.f, as1 = 0.f;
  for (int base = i0; base < i1; base += 64) {
    const int cnt = min(64, i1 - base);
    int s_l = 0;
    uint4 ea_l = {0u, 0u, 0u, 0u};
    if (lane < cnt) {
      s_l = ssrc[base + lane];
      ea_l = *(const uint4*)(sea8 + (size_t)(base + lane) * 8);
    }
#define EDGE_BODY(J)                                                       \
    {                                                                      \
      int s = __shfl(s_l, (J), 64);                                        \
      unsigned w0 = __shfl((int)ea_l.x, (J), 64);                          \
      unsigned w1 = __shfl((int)ea_l.y, (J), 64);                          \
      unsigned w2 = __shfl((int)ea_l.z, (J), 64);                          \
      const h2 ha = *(const h2*)&w0;                                       \
      const h2 hb = *(const h2*)&w1;                                       \
      const h2 hc = *(const h2*)&w2;                                       \
      const float e0 = (float)ha[0], e1 = (float)ha[1];                    \
      const float e2 = (float)hb[0], e3 = (float)hb[1];                    \
      const float e4 = (float)hc[0], e5 = (float)hc[1];                    \
      const uint2 pv = *(const uint2*)(PQi + ((size_t)s * 64 + lane) * 4); \
      const h2 pnv = *(const h2*)&pv.x;                                    \
      const h2 psv = *(const h2*)&pv.y;                                    \
      float vn0 = (float)pnv[0] + qn.x, vn1 = (float)pnv[1] + qn.y;        \
      float vs0 = (float)psv[0] + qs.x, vs1 = (float)psv[1] + qs.y;        \
      vn0 += e0 * cwn[0].x; vn1 += e0 * cwn[0].y;                          \
      vs0 += e0 * cws[0].x; vs1 += e0 * cws[0].y;                          \
      vn0 += e1 * cwn[1].x; vn1 += e1 * cwn[1].y;                          \
      vs0 += e1 * cws[1].x; vs1 += e1 * cws[1].y;                          \
      vn0 += e2 * cwn[2].x; vn1 += e2 * cwn[2].y;                          \
      vs0 += e2 * cws[2].x; vs1 += e2 * cws[2].y;                          \
      vn0 += e3 * cwn[3].x; vn1 += e3 * cwn[3].y;                          \
      vs0 += e3 * cws[3].x; vs1 += e3 * cws[3].y;                          \
      vn0 += e4 * cwn[4].x; vn1 += e4 * cwn[4].y;                          \
      vs0 += e4 * cws[4].x; vs1 += e4 * cws[4].y;                          \
      vn0 += e5 * cwn[5].x; vn1 += e5 * cwn[5].y;                          \
      vs0 += e5 * cws[5].x; vs1 += e5 * cws[5].y;                          \
      an0 = fmaxf(an0, vn0); an1 = fmaxf(an1, vn1);                        \
      as0 += fmaxf(vs0, 0.f); as1 += fmaxf(vs1, 0.f);                      \
    }
    int j = 0;
    for (; j + 4 <= cnt; j += 4) {
      EDGE_BODY(j) EDGE_BODY(j + 1) EDGE_BODY(j + 2) EDGE_BODY(j + 3)
    }
    for (; j < cnt; ++j) EDGE_BODY(j)
#undef EDGE_BODY
  }
  const float inv = 1.f / fmaxf((float)(i1 - i0), 1.f);
  as0 *= inv; as1 *= inv;
  const size_t o = (size_t)node * FUS + (size_t)cur * CH + c;
  if (prev >= 0) {
    const size_t op = (size_t)node * FUS + (size_t)prev * CH + c;
    const float2 prn = *(const float2*)(feats + op);
    const float2 prs = *(const float2*)(sfeats + op);
    an0 += prn.x; an1 += prn.y;
    as0 += prs.x; as1 += prs.y;
  }
  float2 on = {an0, an1}, os = {as0, as1};
  *(float2*)(feats + o) = on;
  *(float2*)(sfeats + o) = os;
}

// ---------- pack feats -> f16 A-fragments: [rb][ks][i][lane][8] ----------
__global__ __launch_bounds__(64) void k_cvtApack(const float* __restrict__ feats,
                                                 _Float16* __restrict__ ap) {
  const int rb = blockIdx.x / 12, ks = blockIdx.x % 12;
  const int L = threadIdx.x, m = L & 15, quad = L >> 4;
#pragma unroll
  for (int i = 0; i < 4; ++i) {
    const int row = rb * 64 + i * 16 + m;
    const int rowc = min(row, NN - 1);
    const float* src = feats + (size_t)rowc * FUS + ks * 32 + quad * 8;
    half8 v;
    if (row < NN) {
      const float4 f0 = *(const float4*)src;
      const float4 f1 = *(const float4*)(src + 4);
      v[0] = (_Float16)f0.x; v[1] = (_Float16)f0.y;
      v[2] = (_Float16)f0.z; v[3] = (_Float16)f0.w;
      v[4] = (_Float16)f1.x; v[5] = (_Float16)f1.y;
      v[6] = (_Float16)f1.z; v[7] = (_Float16)f1.w;
    } else {
#pragma unroll
      for (int j = 0; j < 8; ++j) v[j] = (_Float16)0.f;
    }
    *(half8*)(ap + (((size_t)(rb * 12 + ks) * 4 + i) * 64 + L) * 8) = v;
  }
}

// ---------- convert + pack W (KxN f32) into f16 B-fragment order ----------
template <int N, int NT>
__global__ __launch_bounds__(64) void k_cvtB(const float* __restrict__ W,
                                             _Float16* __restrict__ wh) {
  const int c = blockIdx.x / NT;
  const int tile = blockIdx.x % NT;
  const int L = threadIdx.x;
  const int n = tile * 16 + (L & 15);
  const int k0 = c * 32 + (L >> 4) * 8;
  half8 v;
#pragma unroll
  for (int j = 0; j < 8; ++j) v[j] = (_Float16)W[(size_t)(k0 + j) * N + n];
  *(half8*)(wh + (((size_t)(c * NT + tile)) * 64 + L) * 8) = v;
}

// ---------- fusion GEMM + segment max ----
// cg fastest-varying within XCD (R0: FETCH 123MB->22MB). R1: the kernel is
// latency-bound at 40% occupancy (LDS 33.8KB -> 4 blk/CU). Halve LDS by
// doing the pooling epilogue in two 32-row phases, cache the block's bbox
// window in LDS once (kills 32 serialized L2 loads/thread), and pin
// 8 waves/EU (VGPR<=64) so 8 blocks/CU co-reside to hide L2 latency.
__global__ __launch_bounds__(256, 8) void k_pool_mfma(
    const _Float16* __restrict__ aP, const _Float16* __restrict__ wh,
    const int* __restrict__ bbox, const float* __restrict__ bf,
    float* __restrict__ pooled) {
  __shared__ float cl[32 * 132];
  __shared__ int s_bb[64];
  const int t = threadIdx.x, lane = t & 63, wv = t >> 6;
  const int fid = blockIdx.x;
  const int xcd = fid & 7, slot = fid >> 3;
  const int cg = slot & 7;
  const int rb = xcd * 98 + (slot >> 3);
  const int nbase = rb * 64;
  const int m = lane & 15, quad = lane >> 4;
  if (t < 64) s_bb[t] = bbox[min(nbase + t, NN - 1)];
  f32x4 acc[4][2];
#pragma unroll
  for (int i = 0; i < 4; ++i)
#pragma unroll
    for (int nt = 0; nt < 2; ++nt) acc[i][nt] = (f32x4){0.f, 0.f, 0.f, 0.f};
  const _Float16* apb = aP + (size_t)rb * 12 * 2048 + (size_t)lane * 8;
  const _Float16* bp = wh + ((size_t)(cg * 8 + wv * 2) * 64 + lane) * 8;
#pragma unroll
  for (int ks = 0; ks < 12; ++ks) {
    const half8 b0 = *(const half8*)(bp + (size_t)ks * 32768);
    const half8 b1 = *(const half8*)(bp + (size_t)ks * 32768 + 512);
#pragma unroll
    for (int i = 0; i < 4; ++i) {
      const half8 a = *(const half8*)(apb + ((size_t)ks * 4 + i) * 512);
      acc[i][0] = __builtin_amdgcn_mfma_f32_16x16x32_f16(a, b0, acc[i][0], 0, 0, 0);
      acc[i][1] = __builtin_amdgcn_mfma_f32_16x16x32_f16(a, b1, acc[i][1], 0, 0, 0);
    }
  }
  const int col = t & 127, rh = t >> 7;
  const int gcol = cg * 128 + col;
  const float bias = bf[gcol];
#pragma unroll
  for (int p = 0; p < 2; ++p) {
    __syncthreads();  // p=0: orders s_bb; p=1: phase-0 readers done with cl
#pragma unroll
    for (int ii = 0; ii < 2; ++ii)
#pragma unroll
      for (int nt = 0; nt < 2; ++nt) {
        const int scol = wv * 32 + nt * 16 + m;
#pragma unroll
        for (int r = 0; r < 4; ++r)
          cl[(ii * 16 + quad * 4 + r) * 132 + scol] = acc[p * 2 + ii][nt][r];
      }
    __syncthreads();
    int curb = -1;
    float mx = 0.f;
    for (int rr = 0; rr < 16; ++rr) {
      const int rl = rh * 16 + rr;
      const int node = nbase + p * 32 + rl;
      if (node >= NN) break;
      const int bid = s_bb[p * 32 + rl];
      const float v = fmaxf(cl[rl * 132 + col] + bias, 0.f);
      if (bid != curb) {
        if (curb >= 0)
          atomicMax((unsigned*)(pooled + (size_t)curb * 1408 + gcol),
                    __float_as_uint(mx));
        curb = bid;
        mx = v;
      } else {
        mx = fmaxf(mx, v);
      }
    }
    if (curb >= 0)
      atomicMax((unsigned*)(pooled + (size_t)curb * 1408 + gcol),
                __float_as_uint(mx));
  }
}

// ---------- raw-feats bbox max + sfeats bbox mean ----------
__global__ __launch_bounds__(256) void k_poolraw(
    const float* __restrict__ feats, const float* __restrict__ sfeats,
    const int* __restrict__ seg, float* __restrict__ pooled,
    float* __restrict__ sb) {
  const int b = blockIdx.x, t = threadIdx.x;
  if (t >= 192) return;
  const int c2 = t * 2;
  const int n0 = __builtin_amdgcn_readfirstlane(seg[b]);
  const int n1 = __builtin_amdgcn_readfirstlane(seg[b + 1]);
  float2 fmx = {0.f, 0.f}, ss = {0.f, 0.f};
  for (int n = n0; n < n1; ++n) {
    const float2 f2 = *(const float2*)(feats + (size_t)n * FUS + c2);
    fmx.x = fmaxf(fmx.x, f2.x); fmx.y = fmaxf(fmx.y, f2.y);
    const float2 s2 = *(const float2*)(sfeats + (size_t)n * FUS + c2);
    ss.x += s2.x; ss.y += s2.y;
  }
  *(float2*)(pooled + (size_t)b * 1408 + 1024 + c2) = fmx;
  const float inv = 1.f / fmaxf((float)(n1 - n0), 1.f);
  float2 o = {ss.x * inv, ss.y * inv};
  *(float2*)(sb + (size_t)b * FUS + c2) = o;
}

// ---------- fusion_super = relu(sb @ Wfs + bfs), lane-distributed x ----------
__global__ __launch_bounds__(256) void k_fusion_super(
    const float* __restrict__ sb, const float* __restrict__ Wfs,
    const float* __restrict__ bfs, float* __restrict__ fs) {
  const int t = threadIdx.x, lane = t & 63, wv = t >> 6;
  const int r0 = blockIdx.x * 4;
  const int c = (blockIdx.y * 4 + wv) * 128 + lane * 2;
  float2 acc[4];
#pragma unroll
  for (int u = 0; u < 4; ++u) acc[u] = make_float2(0.f, 0.f);
  const int xr = r0 + (lane >> 4), xk = lane & 15;
  for (int k0 = 0; k0 < FUS; k0 += 16) {
    const float xv = sb[(size_t)xr * FUS + k0 + xk];
#pragma unroll
    for (int j = 0; j < 16; ++j) {
      const float2 w = *(const float2*)(Wfs + (size_t)(k0 + j) * 1024 + c);
#pragma unroll
      for (int u = 0; u < 4; ++u) {
        const float xs = __shfl(xv, u * 16 + j, 64);
        acc[u].x += xs * w.x; acc[u].y += xs * w.y;
      }
    }
  }
  const float2 b = *(const float2*)(bfs + c);
#pragma unroll
  for (int u = 0; u < 4; ++u) {
    float2 o = {fmaxf(acc[u].x + b.x, 0.f), fmaxf(acc[u].y + b.y, 0.f)};
    *(float2*)(fs + (size_t)(r0 + u) * 1024 + c) = o;
  }
}

// ---------- concat [pooled | fsup | sb] -> f16 bbH[NB_PAD][K1], zero-padded ----
__global__ __launch_bounds__(256) void k_cvt_cat(
    const float* __restrict__ pooled, const float* __restrict__ fsup,
    const float* __restrict__ sb, _Float16* __restrict__ bbH) {
  const size_t off = ((size_t)blockIdx.x * 256 + threadIdx.x) * 8;
  const int row = (int)(off / K1);
  const int col = (int)(off - (size_t)row * K1);
  half8 v;
  if (row < NB) {
    const float* src;
    if (col < 1408)      src = pooled + (size_t)row * 1408 + col;
    else if (col < 2432) src = fsup + (size_t)row * 1024 + (col - 1408);
    else                 src = sb + (size_t)row * FUS + (col - 2432);
    const float4 f0 = *(const float4*)src;
    const float4 f1 = *(const float4*)(src + 4);
    v[0] = (_Float16)f0.x; v[1] = (_Float16)f0.y;
    v[2] = (_Float16)f0.z; v[3] = (_Float16)f0.w;
    v[4] = (_Float16)f1.x; v[5] = (_Float16)f1.y;
    v[6] = (_Float16)f1.z; v[7] = (_Float16)f1.w;
  } else {
#pragma unroll
    for (int j = 0; j < 8; ++j) v[j] = (_Float16)0.f;
  }
  *(half8*)(bbH + off) = v;
}

// ---------- h1 = relu(bbH @ W1 + b1) on matrix cores ----------
__global__ __launch_bounds__(256) void k_mlp1_mfma(
    const _Float16* __restrict__ bbH, const _Float16* __restrict__ wh,
    const float* __restrict__ b1, float* __restrict__ h1) {
  const int t = threadIdx.x, lane = t & 63, wv = t >> 6;
  const int nbase = blockIdx.x * 64;
  const int cg = blockIdx.y;
  const int m = lane & 15, quad = lane >> 4;
  f32x4 acc[4][2];
#pragma unroll
  for (int i = 0; i < 4; ++i)
#pragma unroll
    for (int nt = 0; nt < 2; ++nt) acc[i][nt] = (f32x4){0.f, 0.f, 0.f, 0.f};
  const _Float16* ap = bbH + (size_t)(nbase + m) * K1 + quad * 8;
  const _Float16* bp = wh + ((size_t)(cg * 8 + wv * 2) * 64 + lane) * 8;
#pragma unroll 4
  for (int ks = 0; ks < 88; ++ks) {
    const half8 b0 = *(const half8*)(bp + (size_t)ks * 16384);
    const half8 b1v = *(const half8*)(bp + (size_t)ks * 16384 + 512);
#pragma unroll
    for (int i = 0; i < 4; ++i) {
      const half8 a = *(const half8*)(ap + (size_t)(i * 16) * K1 + ks * 32);
      acc[i][0] = __builtin_amdgcn_mfma_f32_16x16x32_f16(a, b0, acc[i][0], 0, 0, 0);
      acc[i][1] = __builtin_amdgcn_mfma_f32_16x16x32_f16(a, b1v, acc[i][1], 0, 0, 0);
    }
  }
#pragma unroll
  for (int i = 0; i < 4; ++i)
#pragma unroll
    for (int nt = 0; nt < 2; ++nt) {
      const int gcol = cg * 128 + wv * 32 + nt * 16 + m;
      const float bias = b1[gcol];
#pragma unroll
      for (int r = 0; r < 4; ++r) {
        const int row = nbase + i * 16 + quad * 4 + r;
        if (row < NB)
          h1[(size_t)row * 512 + gcol] = fmaxf(acc[i][nt][r] + bias, 0.f);
      }
    }
}

// ---------- h2 = relu(h1 @ W2 + b2) ----------
__global__ __launch_bounds__(256) void k_mlp2(
    const float* __restrict__ h1, const float* __restrict__ W2,
    const float* __restrict__ b2, float* __restrict__ h2o) {
  const int r0 = blockIdx.x * 8, t = threadIdx.x;
  float acc[8];
#pragma unroll
  for (int u = 0; u < 8; ++u) acc[u] = 0.f;
  for (int k = 0; k < 512; ++k) {
    float w = W2[(size_t)k * 256 + t];
#pragma unroll
    for (int u = 0; u < 8; ++u) acc[u] += h1[(size_t)(r0 + u) * 512 + k] * w;
  }
  float bv = b2[t];
#pragma unroll
  for (int u = 0; u < 8; ++u)
    h2o[(size_t)(r0 + u) * 256 + t] = fmaxf(acc[u] + bv, 0.f);
}

// ---------- logits = h2 @ W3 + b3 ----------
__global__ __launch_bounds__(256) void k_mlp3(
    const float* __restrict__ h2i, const float* __restrict__ W3,
    const float* __restrict__ b3, float* __restrict__ out) {
  const int r0 = blockIdx.x * 8, t = threadIdx.x;
  const int u = t >> 5, oc = t & 31;
  const float* x = h2i + (size_t)(r0 + u) * 256;
  float acc = 0.f;
  for (int k = 0; k < 256; ++k) acc += x[k] * W3[(size_t)k * 32 + oc];
  out[(size_t)(r0 + u) * 32 + oc] = acc + b3[oc];
}

extern "C" void kernel_launch(void* const* d_in, const int* in_sizes, int n_in,
                              void* d_out, int out_size, void* d_ws, size_t ws_size,
                              hipStream_t stream) {
  const float* x     = (const float*)d_in[0];
  const float* eattr = (const float*)d_in[1];
  const float* W_h   = (const float*)d_in[2];
  const float* b_h   = (const float*)d_in[3];
  const float* Ws_h  = (const float*)d_in[4];
  const float* bs_h  = (const float*)d_in[5];
  const float* Wb    = (const float*)d_in[6];
  const float* bb    = (const float*)d_in[7];
  const float* Wbs   = (const float*)d_in[8];
  const float* bbs   = (const float*)d_in[9];
  const float* W_f   = (const float*)d_in[10];
  const float* b_f   = (const float*)d_in[11];
  const float* W_fs  = (const float*)d_in[12];
  const float* b_fs  = (const float*)d_in[13];
  const float* W1    = (const float*)d_in[14];
  const float* b1    = (const float*)d_in[15];
  const float* W2    = (const float*)d_in[16];
  const float* b2    = (const float*)d_in[17];
  const float* W3    = (const float*)d_in[18];
  const float* b3    = (const float*)d_in[19];
  const int*   edge  = (const int*)d_in[20];
  const int*   bbox  = (const int*)d_in[21];
  float* out = (float*)d_out;

  // ---- workspace layout (~221.5 MB; known-good budget >= 233 MB) ----
  float* p = (float*)d_ws;
  float* feats  = p; p += (size_t)NN * FUS;
  float* sfeats = p; p += (size_t)NN * FUS;
  float* PQ     = p; p += (size_t)2 * NN * CH;    // 12.8M floats
  _Float16* PQi = (_Float16*)PQ;
  _Float16* Qi  = PQi + (size_t)NN * 256;
  // overlays inside PQ (live only AFTER the last k_conv2):
  _Float16* aPack = (_Float16*)PQ;
  _Float16* WfH   = aPack + (size_t)784 * 12 * 2048;
  float* pooled   = (float*)(WfH + (size_t)FUS * 1024);
  float* sb   = PQ;
  float* fsup = sb + (size_t)NB * FUS;
  float* h1   = fsup + (size_t)NB * 1024;
  float* h2b  = h1 + (size_t)NB * 512;
  _Float16* bbH = (_Float16*)(h2b + (size_t)NB * 256);
  _Float16* W1H = bbH + (size_t)NB_PAD * K1;
  // CSR payload + misc after PQ region:
  _Float16* sea8 = (_Float16*)p;
  int* ssrc    = (int*)(sea8 + (size_t)NE * 8);
  int* row_ptr = ssrc + NE;
  int* deg     = row_ptr + NN + 1;
  int* cursor  = deg + NN;
  int* seg     = cursor + NN;
  _Float16* WcatN = (_Float16*)(seg + NB + 1);
  _Float16* WcatS = WcatN + (size_t)128 * 256;
  int* bsum = (int*)(WcatS + (size_t)128 * 256);

  hipMemsetAsync(deg, 0, 2 * NN * sizeof(int), stream);  // deg + cursor

  // ---- CSR build (dst-sorted payload, parallel scan) + bbox segments ----
  k_deg<<<(NE + 255) / 256, 256, 0, stream>>>(edge, deg);
  k_scan1<<<SCAN_NBLK, 1024, 0, stream>>>(deg, row_ptr, bsum);
  k_scan2<<<1, 64, 0, stream>>>(bsum);
  k_scan3<<<(NN + 255) / 256, 256, 0, stream>>>(bsum, row_ptr);
  k_fill<<<(NE + 255) / 256, 256, 0, stream>>>(edge, eattr, row_ptr, cursor,
                                               ssrc, sea8);
  k_segstart<<<(NN + 255) / 256, 256, 0, stream>>>(bbox, seg);

  const int npq_grid = (NN + 31) / 32;

  // ---- conv 0 (head): both streams read x (K=8), scalar node transform ----
  k_node_pq<<<npq_grid, 256, 0, stream>>>(x, INCH, INCH, W_h, b_h, PQi, Qi, 0);
  k_node_pq<<<npq_grid, 256, 0, stream>>>(x, INCH, INCH, Ws_h, bs_h, PQi, Qi, 1);
  k_conv2<<<NN / 4, 256, 0, stream>>>(row_ptr, ssrc, sea8, PQi, Qi,
                                      W_h + 2 * INCH * CH, Ws_h + 2 * INCH * CH,
                                      feats, sfeats, 0, -1);

  // ---- residual blocks (K=128): MFMA node transform, both streams ----
  for (int i = 0; i < 2; ++i) {
    const float* Wi  = Wb  + (size_t)i * 262 * CH;
    const float* bi  = bb  + (size_t)i * CH;
    const float* Wsi = Wbs + (size_t)i * 262 * CH;
    const float* bsi = bbs + (size_t)i * CH;
    k_cvtWnpq<<<dim3(64, 2), 64, 0, stream>>>(Wi, Wsi, WcatN, WcatS);
    k_npq_mfma<<<dim3((NN + 63) / 64, 2), 256, 0, stream>>>(
        feats + i * CH, sfeats + i * CH, FUS, WcatN, WcatS, bi, bsi, PQi, Qi);
    k_conv2<<<NN / 4, 256, 0, stream>>>(row_ptr, ssrc, sea8, PQi, Qi,
                                        Wi + 2 * CH * CH, Wsi + 2 * CH * CH,
                                        feats, sfeats, i + 1, i);
  }

  // ---- pooling: packed-A f16 convert + MFMA GEMM + atomicMax ----
  k_cvtApack<<<784 * 12, 64, 0, stream>>>(feats, aPack);
  k_cvtB<1024, 64><<<12 * 64, 64, 0, stream>>>(W_f, WfH);
  hipMemsetAsync(pooled, 0, (size_t)NB * 1408 * sizeof(float), stream);
  k_pool_mfma<<<784 * 8, 256, 0, stream>>>(aPack, WfH, bbox, b_f, pooled);
  k_poolraw<<<NB, 256, 0, stream>>>(feats, sfeats, seg, pooled, sb);
  k_fusion_super<<<dim3(NB / 4, 2), 256, 0, stream>>>(sb, W_fs, b_fs, fsup);

  // ---- head MLP: concat->f16, W1->f16 frag, MFMA GEMM, then small MLPs ----
  k_cvt_cat<<<(int)(((size_t)NB_PAD * K1 / 8) / 256), 256, 0, stream>>>(
      pooled, fsup, sb, bbH);
  k_cvtB<512, 32><<<88 * 32, 64, 0, stream>>>(W1, W1H);
  k_mlp1_mfma<<<dim3(NB_PAD / 64, 4), 256, 0, stream>>>(bbH, W1H, b1, h1);
  k_mlp2<<<NB / 8, 256, 0, stream>>>(h1, W2, b2, h2b);
  k_mlp3<<<NB / 8, 256, 0, stream>>>(h2b, W3, b3, out);
}

// Round 3
// 939.106 us; speedup vs baseline: 1.1554x; 1.0738x over previous
//
#include <hip/hip_runtime.h>

#define NN      50000
#define NE      800000
#define INCH    8
#define CH      128
#define EA      6
#define NB      2000
#define NB_PAD  2048
#define NCLS    32
#define FUS     384
#define K1      2816   // 1408 + 1024 + 384
#define SCAN_NBLK 49   // (NN + 1023) / 1024

typedef _Float16 half8 __attribute__((ext_vector_type(8)));
typedef _Float16 h2 __attribute__((ext_vector_type(2)));
typedef float f32x4 __attribute__((ext_vector_type(4)));

// ---------- degree of dst nodes ----------
__global__ __launch_bounds__(256) void k_deg(const int* __restrict__ edge,
                                             int* __restrict__ deg) {
  int e = blockIdx.x * 256 + threadIdx.x;
  if (e < NE) atomicAdd(&deg[edge[NE + e]], 1);
}

// ---------- parallel scan, phase 1: per-block inclusive scan + block sums ----
__global__ __launch_bounds__(1024) void k_scan1(const int* __restrict__ deg,
                                                int* __restrict__ row_ptr,
                                                int* __restrict__ bsum) {
  __shared__ int wsum[16];
  const int t = threadIdx.x, lane = t & 63, w = t >> 6;
  const int i = blockIdx.x * 1024 + t;
  int x = (i < NN) ? deg[i] : 0;
#pragma unroll
  for (int off = 1; off < 64; off <<= 1) {
    int y = __shfl_up(x, off, 64);
    if (lane >= off) x += y;
  }
  if (lane == 63) wsum[w] = x;
  __syncthreads();
  if (w == 0 && lane < 16) {
    int s = wsum[lane];
#pragma unroll
    for (int off = 1; off < 16; off <<= 1) {
      int y = __shfl_up(s, off, 64);
      if (lane >= off) s += y;
    }
    wsum[lane] = s;
  }
  __syncthreads();
  int incl = x + ((w == 0) ? 0 : wsum[w - 1]);
  if (i < NN) row_ptr[i + 1] = incl;
  if (t == 1023) bsum[blockIdx.x] = incl;
}

// ---------- phase 2: single-wave exclusive scan of block sums ----------
__global__ __launch_bounds__(64) void k_scan2(int* __restrict__ bsum) {
  const int t = threadIdx.x;
  int x = (t < SCAN_NBLK) ? bsum[t] : 0;
#pragma unroll
  for (int off = 1; off < 64; off <<= 1) {
    int y = __shfl_up(x, off, 64);
    if (t >= off) x += y;
  }
  int ex = __shfl_up(x, 1, 64);
  if (t == 0) ex = 0;
  if (t < SCAN_NBLK) bsum[t] = ex;
}

// ---------- phase 3: add block offsets ----------
__global__ __launch_bounds__(256) void k_scan3(const int* __restrict__ bsum,
                                               int* __restrict__ row_ptr) {
  const int i = blockIdx.x * 256 + threadIdx.x;
  if (i == 0) row_ptr[0] = 0;
  if (i < NN) row_ptr[i + 1] += bsum[i >> 10];
}

// ---------- fill CSR payload: dst-sorted src + f16 e_attr ----------
__global__ __launch_bounds__(256) void k_fill(
    const int* __restrict__ edge, const float* __restrict__ eattr,
    const int* __restrict__ row_ptr, int* __restrict__ cursor,
    int* __restrict__ ssrc, _Float16* __restrict__ sea8) {
  int e = blockIdx.x * 256 + threadIdx.x;
  if (e >= NE) return;
  int s = edge[e], d = edge[NE + e];
  int idx = row_ptr[d] + atomicAdd(&cursor[d], 1);
  ssrc[idx] = s;
  half8 v;
#pragma unroll
  for (int j = 0; j < EA; ++j) v[j] = (_Float16)eattr[(size_t)e * EA + j];
  v[6] = (_Float16)0.f; v[7] = (_Float16)0.f;
  *(half8*)(sea8 + (size_t)idx * 8) = v;
}

// ---------- segment starts from sorted bbox_idx ----------
__global__ __launch_bounds__(256) void k_segstart(const int* __restrict__ bbox,
                                                  int* __restrict__ seg) {
  int i = blockIdx.x * 256 + threadIdx.x;
  if (i >= NN) return;
  int bc = bbox[i];
  int bp = (i == 0) ? -1 : bbox[i - 1];
  for (int j = bp + 1; j <= bc; ++j) seg[j] = i;
  if (i == NN - 1)
    for (int j = bc + 1; j <= NB; ++j) seg[j] = NN;
}

// ---------- head node transform (K=8): scalar path -> interleaved f16 ----------
__global__ __launch_bounds__(256) void k_node_pq(
    const float* __restrict__ X, int ldx, int K,
    const float* __restrict__ W, const float* __restrict__ bias,
    _Float16* __restrict__ PQi, _Float16* __restrict__ Qi, int sel) {
  const int t = threadIdx.x, lane = t & 63, wv = t >> 6;
  const int nbase = blockIdx.x * 32 + wv * 8;
  const int c = lane * 2;
  const float2 bv = *(const float2*)(bias + c);
  float2 pacc[8], qacc[8];
#pragma unroll
  for (int u = 0; u < 8; ++u) { pacc[u] = bv; qacc[u] = make_float2(0.f, 0.f); }
  const int xrow = min(nbase + (lane >> 3), NN - 1);
  const int xk = lane & 7;
  for (int k0 = 0; k0 < K; k0 += 8) {
    const float xv = X[(size_t)xrow * ldx + k0 + xk];
#pragma unroll
    for (int j = 0; j < 8; ++j) {
      const float2 w1 = *(const float2*)(W + (size_t)(k0 + j) * CH + c);
      const float2 w2 = *(const float2*)(W + (size_t)(K + k0 + j) * CH + c);
      const float2 wd = {w1.x - w2.x, w1.y - w2.y};
#pragma unroll
      for (int u = 0; u < 8; ++u) {
        const float xs = __shfl(xv, u * 8 + j, 64);
        pacc[u].x += xs * wd.x; pacc[u].y += xs * wd.y;
        qacc[u].x += xs * w2.x; qacc[u].y += xs * w2.y;
      }
    }
  }
#pragma unroll
  for (int u = 0; u < 8; ++u) {
    const int node = nbase + u;
    if (node < NN) {
      const size_t o = ((size_t)node * 64 + lane) * 4 + sel * 2;
      *(h2*)(PQi + o) = (h2){(_Float16)pacc[u].x, (_Float16)pacc[u].y};
      *(h2*)(Qi + o)  = (h2){(_Float16)qacc[u].x, (_Float16)qacc[u].y};
    }
  }
}

// ---------- pack [W1-W2 | W2] (K=128 x N=256) into f16 B-fragments ----------
__global__ __launch_bounds__(64) void k_cvtWnpq(
    const float* __restrict__ WN, const float* __restrict__ WS,
    _Float16* __restrict__ whN, _Float16* __restrict__ whS) {
  const float* W = blockIdx.y ? WS : WN;
  _Float16* wh   = blockIdx.y ? whS : whN;
  const int c = blockIdx.x >> 4, tile = blockIdx.x & 15;
  const int L = threadIdx.x;
  const int n = tile * 16 + (L & 15);
  const int k0 = c * 32 + (L >> 4) * 8;
  half8 v;
#pragma unroll
  for (int j = 0; j < 8; ++j) {
    const int k = k0 + j;
    float val;
    if (n < CH) val = W[(size_t)k * CH + n] - W[(size_t)(CH + k) * CH + n];
    else        val = W[(size_t)(CH + k) * CH + (n - CH)];
    v[j] = (_Float16)val;
  }
  *(half8*)(wh + (((size_t)(c * 16 + tile)) * 64 + L) * 8) = v;
}

// ---------- residual node transform on matrix cores (both streams) ----------
__global__ __launch_bounds__(256) void k_npq_mfma(
    const float* __restrict__ Xn, const float* __restrict__ Xs, int ldx,
    const _Float16* __restrict__ whN, const _Float16* __restrict__ whS,
    const float* __restrict__ biasN, const float* __restrict__ biasS,
    _Float16* __restrict__ PQi, _Float16* __restrict__ Qi) {
  const int sel = blockIdx.y;
  const float* X = sel ? Xs : Xn;
  const _Float16* wh = sel ? whS : whN;
  const float* bias = sel ? biasS : biasN;
  const int t = threadIdx.x, lane = t & 63, wv = t >> 6;
  const int nbase = blockIdx.x * 64;
  const int m = lane & 15, quad = lane >> 4;
  f32x4 acc[4][4];
#pragma unroll
  for (int i = 0; i < 4; ++i)
#pragma unroll
    for (int nt = 0; nt < 4; ++nt) acc[i][nt] = (f32x4){0.f, 0.f, 0.f, 0.f};
#pragma unroll
  for (int ks = 0; ks < 4; ++ks) {
    half8 b[4];
#pragma unroll
    for (int nt = 0; nt < 4; ++nt)
      b[nt] = *(const half8*)(wh + (((size_t)(ks * 16 + wv * 4 + nt)) * 64 + lane) * 8);
#pragma unroll
    for (int i = 0; i < 4; ++i) {
      const int row = min(nbase + i * 16 + m, NN - 1);
      const float* src = X + (size_t)row * ldx + ks * 32 + quad * 8;
      const float4 f0 = *(const float4*)src;
      const float4 f1 = *(const float4*)(src + 4);
      half8 a;
      a[0] = (_Float16)f0.x; a[1] = (_Float16)f0.y;
      a[2] = (_Float16)f0.z; a[3] = (_Float16)f0.w;
      a[4] = (_Float16)f1.x; a[5] = (_Float16)f1.y;
      a[6] = (_Float16)f1.z; a[7] = (_Float16)f1.w;
#pragma unroll
      for (int nt = 0; nt < 4; ++nt)
        acc[i][nt] = __builtin_amdgcn_mfma_f32_16x16x32_f16(a, b[nt], acc[i][nt],
                                                            0, 0, 0);
    }
  }
#pragma unroll
  for (int i = 0; i < 4; ++i)
#pragma unroll
    for (int nt = 0; nt < 4; ++nt) {
      const int col = wv * 64 + nt * 16 + m;
      const float bv = (col < CH) ? bias[col] : 0.f;
#pragma unroll
      for (int r = 0; r < 4; ++r) {
        const int row = nbase + i * 16 + quad * 4 + r;
        if (row < NN) {
          const float v = acc[i][nt][r] + bv;
          if (col < CH)
            PQi[((size_t)row * 64 + (col >> 1)) * 4 + sel * 2 + (col & 1)] =
                (_Float16)v;
          else {
            const int qc = col - CH;
            Qi[((size_t)row * 64 + (qc >> 1)) * 4 + sel * 2 + (qc & 1)] =
                (_Float16)v;
          }
        }
      }
    }
}

// ---------- fused dual-stream CSR conv ----------
// R2: packed-f16 edge math (v_pk_add/fma/max_f16): P,Q,e,C are all f16
// already; removes 15 cvts + halves FMA count (~51 -> ~26 VALU/edge).
// Gathers for 4 edges issued BEFORE any compute (independent loads in
// flight to cover L2/L3 latency - the kernel is latency-bound, not
// VALU-bound: per-SIMD VALU saturation was only ~30%).
// Max-stream reduced in f16 (exact); mean-stream accumulated in f32.
__global__ __launch_bounds__(256) void k_conv2(
    const int* __restrict__ row_ptr, const int* __restrict__ ssrc,
    const _Float16* __restrict__ sea8,
    const _Float16* __restrict__ PQi, const _Float16* __restrict__ Qi,
    const float* __restrict__ Cn, const float* __restrict__ Cs,
    float* __restrict__ feats, float* __restrict__ sfeats,
    int cur, int prev) {
  const int t = threadIdx.x;
  const int lane = t & 63;
  const int node = blockIdx.x * 4 + (t >> 6);
  const int c = lane * 2;
  h2 cwnh[EA], cwsh[EA];
#pragma unroll
  for (int j = 0; j < EA; ++j) {
    const float2 a = *(const float2*)(Cn + j * CH + c);
    const float2 b = *(const float2*)(Cs + j * CH + c);
    cwnh[j] = (h2){(_Float16)a.x, (_Float16)a.y};
    cwsh[j] = (h2){(_Float16)b.x, (_Float16)b.y};
  }
  int i0 = __builtin_amdgcn_readfirstlane(row_ptr[node]);
  int i1 = __builtin_amdgcn_readfirstlane(row_ptr[node + 1]);
  const uint2 qv = *(const uint2*)(Qi + ((size_t)node * 64 + lane) * 4);
  const h2 qnh = *(const h2*)&qv.x;
  const h2 qsh = *(const h2*)&qv.y;
  const _Float16* pqL = PQi + (size_t)lane * 4;  // + s*256 per edge
  h2 anh = (h2){(_Float16)0.f, (_Float16)0.f};
  float as0 = 0.f, as1 = 0.f;
  const h2 zero = (h2){(_Float16)0.f, (_Float16)0.f};
#define COMP(PV, J)                                                        \
  {                                                                        \
    unsigned w0 = __shfl((int)ea_l.x, (J), 64);                            \
    unsigned w1 = __shfl((int)ea_l.y, (J), 64);                            \
    unsigned w2 = __shfl((int)ea_l.z, (J), 64);                            \
    const h2 ea01 = *(const h2*)&w0;                                       \
    const h2 ea23 = *(const h2*)&w1;                                       \
    const h2 ea45 = *(const h2*)&w2;                                       \
    h2 vn = *(const h2*)&PV.x + qnh;                                       \
    h2 vs = *(const h2*)&PV.y + qsh;                                       \
    h2 b;                                                                  \
    b = (h2){ea01[0], ea01[0]}; vn += b * cwnh[0]; vs += b * cwsh[0];      \
    b = (h2){ea01[1], ea01[1]}; vn += b * cwnh[1]; vs += b * cwsh[1];      \
    b = (h2){ea23[0], ea23[0]}; vn += b * cwnh[2]; vs += b * cwsh[2];      \
    b = (h2){ea23[1], ea23[1]}; vn += b * cwnh[3]; vs += b * cwsh[3];      \
    b = (h2){ea45[0], ea45[0]}; vn += b * cwnh[4]; vs += b * cwsh[4];      \
    b = (h2){ea45[1], ea45[1]}; vn += b * cwnh[5]; vs += b * cwsh[5];      \
    anh = __builtin_elementwise_max(anh, vn);                              \
    const h2 vsr = __builtin_elementwise_max(vs, zero);                    \
    as0 += (float)vsr[0]; as1 += (float)vsr[1];                            \
  }
  for (int base = i0; base < i1; base += 64) {
    const int cnt = min(64, i1 - base);
    int s_l = 0;
    uint4 ea_l = {0u, 0u, 0u, 0u};
    if (lane < cnt) {
      s_l = ssrc[base + lane];
      ea_l = *(const uint4*)(sea8 + (size_t)(base + lane) * 8);
    }
    int j = 0;
    for (; j + 4 <= cnt; j += 4) {
      // phase 1: broadcast src indices, issue 4 independent row gathers
      const int sa = __shfl(s_l, j, 64);
      const int sb = __shfl(s_l, j + 1, 64);
      const int sc = __shfl(s_l, j + 2, 64);
      const int sd = __shfl(s_l, j + 3, 64);
      const uint2 pva = *(const uint2*)(pqL + (size_t)sa * 256);
      const uint2 pvb = *(const uint2*)(pqL + (size_t)sb * 256);
      const uint2 pvc = *(const uint2*)(pqL + (size_t)sc * 256);
      const uint2 pvd = *(const uint2*)(pqL + (size_t)sd * 256);
      // phase 2: packed-f16 compute per edge
      COMP(pva, j) COMP(pvb, j + 1) COMP(pvc, j + 2) COMP(pvd, j + 3)
    }
    for (; j < cnt; ++j) {
      const int sa = __shfl(s_l, j, 64);
      const uint2 pva = *(const uint2*)(pqL + (size_t)sa * 256);
      COMP(pva, j)
    }
  }
#undef COMP
  float an0 = (float)anh[0], an1 = (float)anh[1];
  const float inv = 1.f / fmaxf((float)(i1 - i0), 1.f);
  as0 *= inv; as1 *= inv;
  const size_t o = (size_t)node * FUS + (size_t)cur * CH + c;
  if (prev >= 0) {
    const size_t op = (size_t)node * FUS + (size_t)prev * CH + c;
    const float2 prn = *(const float2*)(feats + op);
    const float2 prs = *(const float2*)(sfeats + op);
    an0 += prn.x; an1 += prn.y;
    as0 += prs.x; as1 += prs.y;
  }
  float2 on = {an0, an1}, os = {as0, as1};
  *(float2*)(feats + o) = on;
  *(float2*)(sfeats + o) = os;
}

// ---------- pack feats -> f16 A-fragments: [rb][ks][i][lane][8] ----------
__global__ __launch_bounds__(64) void k_cvtApack(const float* __restrict__ feats,
                                                 _Float16* __restrict__ ap) {
  const int rb = blockIdx.x / 12, ks = blockIdx.x % 12;
  const int L = threadIdx.x, m = L & 15, quad = L >> 4;
#pragma unroll
  for (int i = 0; i < 4; ++i) {
    const int row = rb * 64 + i * 16 + m;
    const int rowc = min(row, NN - 1);
    const float* src = feats + (size_t)rowc * FUS + ks * 32 + quad * 8;
    half8 v;
    if (row < NN) {
      const float4 f0 = *(const float4*)src;
      const float4 f1 = *(const float4*)(src + 4);
      v[0] = (_Float16)f0.x; v[1] = (_Float16)f0.y;
      v[2] = (_Float16)f0.z; v[3] = (_Float16)f0.w;
      v[4] = (_Float16)f1.x; v[5] = (_Float16)f1.y;
      v[6] = (_Float16)f1.z; v[7] = (_Float16)f1.w;
    } else {
#pragma unroll
      for (int j = 0; j < 8; ++j) v[j] = (_Float16)0.f;
    }
    *(half8*)(ap + (((size_t)(rb * 12 + ks) * 4 + i) * 64 + L) * 8) = v;
  }
}

// ---------- convert + pack W (KxN f32) into f16 B-fragment order ----------
template <int N, int NT>
__global__ __launch_bounds__(64) void k_cvtB(const float* __restrict__ W,
                                             _Float16* __restrict__ wh) {
  const int c = blockIdx.x / NT;
  const int tile = blockIdx.x % NT;
  const int L = threadIdx.x;
  const int n = tile * 16 + (L & 15);
  const int k0 = c * 32 + (L >> 4) * 8;
  half8 v;
#pragma unroll
  for (int j = 0; j < 8; ++j) v[j] = (_Float16)W[(size_t)(k0 + j) * N + n];
  *(half8*)(wh + (((size_t)(c * NT + tile)) * 64 + L) * 8) = v;
}

// ---------- fusion GEMM + segment max ----
// cg fastest-varying within XCD (R0: FETCH 123MB->22MB). R1: two-phase
// epilogue halves LDS (16.9KB) + s_bb cache + 8 waves/EU pin -> dropped
// out of top-5.
__global__ __launch_bounds__(256, 8) void k_pool_mfma(
    const _Float16* __restrict__ aP, const _Float16* __restrict__ wh,
    const int* __restrict__ bbox, const float* __restrict__ bf,
    float* __restrict__ pooled) {
  __shared__ float cl[32 * 132];
  __shared__ int s_bb[64];
  const int t = threadIdx.x, lane = t & 63, wv = t >> 6;
  const int fid = blockIdx.x;
  const int xcd = fid & 7, slot = fid >> 3;
  const int cg = slot & 7;
  const int rb = xcd * 98 + (slot >> 3);
  const int nbase = rb * 64;
  const int m = lane & 15, quad = lane >> 4;
  if (t < 64) s_bb[t] = bbox[min(nbase + t, NN - 1)];
  f32x4 acc[4][2];
#pragma unroll
  for (int i = 0; i < 4; ++i)
#pragma unroll
    for (int nt = 0; nt < 2; ++nt) acc[i][nt] = (f32x4){0.f, 0.f, 0.f, 0.f};
  const _Float16* apb = aP + (size_t)rb * 12 * 2048 + (size_t)lane * 8;
  const _Float16* bp = wh + ((size_t)(cg * 8 + wv * 2) * 64 + lane) * 8;
#pragma unroll
  for (int ks = 0; ks < 12; ++ks) {
    const half8 b0 = *(const half8*)(bp + (size_t)ks * 32768);
    const half8 b1 = *(const half8*)(bp + (size_t)ks * 32768 + 512);
#pragma unroll
    for (int i = 0; i < 4; ++i) {
      const half8 a = *(const half8*)(apb + ((size_t)ks * 4 + i) * 512);
      acc[i][0] = __builtin_amdgcn_mfma_f32_16x16x32_f16(a, b0, acc[i][0], 0, 0, 0);
      acc[i][1] = __builtin_amdgcn_mfma_f32_16x16x32_f16(a, b1, acc[i][1], 0, 0, 0);
    }
  }
  const int col = t & 127, rh = t >> 7;
  const int gcol = cg * 128 + col;
  const float bias = bf[gcol];
#pragma unroll
  for (int p = 0; p < 2; ++p) {
    __syncthreads();  // p=0: orders s_bb; p=1: phase-0 readers done with cl
#pragma unroll
    for (int ii = 0; ii < 2; ++ii)
#pragma unroll
      for (int nt = 0; nt < 2; ++nt) {
        const int scol = wv * 32 + nt * 16 + m;
#pragma unroll
        for (int r = 0; r < 4; ++r)
          cl[(ii * 16 + quad * 4 + r) * 132 + scol] = acc[p * 2 + ii][nt][r];
      }
    __syncthreads();
    int curb = -1;
    float mx = 0.f;
    for (int rr = 0; rr < 16; ++rr) {
      const int rl = rh * 16 + rr;
      const int node = nbase + p * 32 + rl;
      if (node >= NN) break;
      const int bid = s_bb[p * 32 + rl];
      const float v = fmaxf(cl[rl * 132 + col] + bias, 0.f);
      if (bid != curb) {
        if (curb >= 0)
          atomicMax((unsigned*)(pooled + (size_t)curb * 1408 + gcol),
                    __float_as_uint(mx));
        curb = bid;
        mx = v;
      } else {
        mx = fmaxf(mx, v);
      }
    }
    if (curb >= 0)
      atomicMax((unsigned*)(pooled + (size_t)curb * 1408 + gcol),
                __float_as_uint(mx));
  }
}

// ---------- raw-feats bbox max + sfeats bbox mean ----------
__global__ __launch_bounds__(256) void k_poolraw(
    const float* __restrict__ feats, const float* __restrict__ sfeats,
    const int* __restrict__ seg, float* __restrict__ pooled,
    float* __restrict__ sb) {
  const int b = blockIdx.x, t = threadIdx.x;
  if (t >= 192) return;
  const int c2 = t * 2;
  const int n0 = __builtin_amdgcn_readfirstlane(seg[b]);
  const int n1 = __builtin_amdgcn_readfirstlane(seg[b + 1]);
  float2 fmx = {0.f, 0.f}, ss = {0.f, 0.f};
  for (int n = n0; n < n1; ++n) {
    const float2 f2 = *(const float2*)(feats + (size_t)n * FUS + c2);
    fmx.x = fmaxf(fmx.x, f2.x); fmx.y = fmaxf(fmx.y, f2.y);
    const float2 s2 = *(const float2*)(sfeats + (size_t)n * FUS + c2);
    ss.x += s2.x; ss.y += s2.y;
  }
  *(float2*)(pooled + (size_t)b * 1408 + 1024 + c2) = fmx;
  const float inv = 1.f / fmaxf((float)(n1 - n0), 1.f);
  float2 o = {ss.x * inv, ss.y * inv};
  *(float2*)(sb + (size_t)b * FUS + c2) = o;
}

// ---------- fusion_super = relu(sb @ Wfs + bfs), lane-distributed x ----------
__global__ __launch_bounds__(256) void k_fusion_super(
    const float* __restrict__ sb, const float* __restrict__ Wfs,
    const float* __restrict__ bfs, float* __restrict__ fs) {
  const int t = threadIdx.x, lane = t & 63, wv = t >> 6;
  const int r0 = blockIdx.x * 4;
  const int c = (blockIdx.y * 4 + wv) * 128 + lane * 2;
  float2 acc[4];
#pragma unroll
  for (int u = 0; u < 4; ++u) acc[u] = make_float2(0.f, 0.f);
  const int xr = r0 + (lane >> 4), xk = lane & 15;
  for (int k0 = 0; k0 < FUS; k0 += 16) {
    const float xv = sb[(size_t)xr * FUS + k0 + xk];
#pragma unroll
    for (int j = 0; j < 16; ++j) {
      const float2 w = *(const float2*)(Wfs + (size_t)(k0 + j) * 1024 + c);
#pragma unroll
      for (int u = 0; u < 4; ++u) {
        const float xs = __shfl(xv, u * 16 + j, 64);
        acc[u].x += xs * w.x; acc[u].y += xs * w.y;
      }
    }
  }
  const float2 b = *(const float2*)(bfs + c);
#pragma unroll
  for (int u = 0; u < 4; ++u) {
    float2 o = {fmaxf(acc[u].x + b.x, 0.f), fmaxf(acc[u].y + b.y, 0.f)};
    *(float2*)(fs + (size_t)(r0 + u) * 1024 + c) = o;
  }
}

// ---------- concat [pooled | fsup | sb] -> f16 bbH[NB_PAD][K1], zero-padded ----
__global__ __launch_bounds__(256) void k_cvt_cat(
    const float* __restrict__ pooled, const float* __restrict__ fsup,
    const float* __restrict__ sb, _Float16* __restrict__ bbH) {
  const size_t off = ((size_t)blockIdx.x * 256 + threadIdx.x) * 8;
  const int row = (int)(off / K1);
  const int col = (int)(off - (size_t)row * K1);
  half8 v;
  if (row < NB) {
    const float* src;
    if (col < 1408)      src = pooled + (size_t)row * 1408 + col;
    else if (col < 2432) src = fsup + (size_t)row * 1024 + (col - 1408);
    else                 src = sb + (size_t)row * FUS + (col - 2432);
    const float4 f0 = *(const float4*)src;
    const float4 f1 = *(const float4*)(src + 4);
    v[0] = (_Float16)f0.x; v[1] = (_Float16)f0.y;
    v[2] = (_Float16)f0.z; v[3] = (_Float16)f0.w;
    v[4] = (_Float16)f1.x; v[5] = (_Float16)f1.y;
    v[6] = (_Float16)f1.z; v[7] = (_Float16)f1.w;
  } else {
#pragma unroll
    for (int j = 0; j < 8; ++j) v[j] = (_Float16)0.f;
  }
  *(half8*)(bbH + off) = v;
}

// ---------- h1 = relu(bbH @ W1 + b1) on matrix cores ----------
__global__ __launch_bounds__(256) void k_mlp1_mfma(
    const _Float16* __restrict__ bbH, const _Float16* __restrict__ wh,
    const float* __restrict__ b1, float* __restrict__ h1) {
  const int t = threadIdx.x, lane = t & 63, wv = t >> 6;
  const int nbase = blockIdx.x * 64;
  const int cg = blockIdx.y;
  const int m = lane & 15, quad = lane >> 4;
  f32x4 acc[4][2];
#pragma unroll
  for (int i = 0; i < 4; ++i)
#pragma unroll
    for (int nt = 0; nt < 2; ++nt) acc[i][nt] = (f32x4){0.f, 0.f, 0.f, 0.f};
  const _Float16* ap = bbH + (size_t)(nbase + m) * K1 + quad * 8;
  const _Float16* bp = wh + ((size_t)(cg * 8 + wv * 2) * 64 + lane) * 8;
#pragma unroll 4
  for (int ks = 0; ks < 88; ++ks) {
    const half8 b0 = *(const half8*)(bp + (size_t)ks * 16384);
    const half8 b1v = *(const half8*)(bp + (size_t)ks * 16384 + 512);
#pragma unroll
    for (int i = 0; i < 4; ++i) {
      const half8 a = *(const half8*)(ap + (size_t)(i * 16) * K1 + ks * 32);
      acc[i][0] = __builtin_amdgcn_mfma_f32_16x16x32_f16(a, b0, acc[i][0], 0, 0, 0);
      acc[i][1] = __builtin_amdgcn_mfma_f32_16x16x32_f16(a, b1v, acc[i][1], 0, 0, 0);
    }
  }
#pragma unroll
  for (int i = 0; i < 4; ++i)
#pragma unroll
    for (int nt = 0; nt < 2; ++nt) {
      const int gcol = cg * 128 + wv * 32 + nt * 16 + m;
      const float bias = b1[gcol];
#pragma unroll
      for (int r = 0; r < 4; ++r) {
        const int row = nbase + i * 16 + quad * 4 + r;
        if (row < NB)
          h1[(size_t)row * 512 + gcol] = fmaxf(acc[i][nt][r] + bias, 0.f);
      }
    }
}

// ---------- h2 = relu(h1 @ W2 + b2) ----------
__global__ __launch_bounds__(256) void k_mlp2(
    const float* __restrict__ h1, const float* __restrict__ W2,
    const float* __restrict__ b2, float* __restrict__ h2o) {
  const int r0 = blockIdx.x * 8, t = threadIdx.x;
  float acc[8];
#pragma unroll
  for (int u = 0; u < 8; ++u) acc[u] = 0.f;
  for (int k = 0; k < 512; ++k) {
    float w = W2[(size_t)k * 256 + t];
#pragma unroll
    for (int u = 0; u < 8; ++u) acc[u] += h1[(size_t)(r0 + u) * 512 + k] * w;
  }
  float bv = b2[t];
#pragma unroll
  for (int u = 0; u < 8; ++u)
    h2o[(size_t)(r0 + u) * 256 + t] = fmaxf(acc[u] + bv, 0.f);
}

// ---------- logits = h2 @ W3 + b3 ----------
__global__ __launch_bounds__(256) void k_mlp3(
    const float* __restrict__ h2i, const float* __restrict__ W3,
    const float* __restrict__ b3, float* __restrict__ out) {
  const int r0 = blockIdx.x * 8, t = threadIdx.x;
  const int u = t >> 5, oc = t & 31;
  const float* x = h2i + (size_t)(r0 + u) * 256;
  float acc = 0.f;
  for (int k = 0; k < 256; ++k) acc += x[k] * W3[(size_t)k * 32 + oc];
  out[(size_t)(r0 + u) * 32 + oc] = acc + b3[oc];
}

extern "C" void kernel_launch(void* const* d_in, const int* in_sizes, int n_in,
                              void* d_out, int out_size, void* d_ws, size_t ws_size,
                              hipStream_t stream) {
  const float* x     = (const float*)d_in[0];
  const float* eattr = (const float*)d_in[1];
  const float* W_h   = (const float*)d_in[2];
  const float* b_h   = (const float*)d_in[3];
  const float* Ws_h  = (const float*)d_in[4];
  const float* bs_h  = (const float*)d_in[5];
  const float* Wb    = (const float*)d_in[6];
  const float* bb    = (const float*)d_in[7];
  const float* Wbs   = (const float*)d_in[8];
  const float* bbs   = (const float*)d_in[9];
  const float* W_f   = (const float*)d_in[10];
  const float* b_f   = (const float*)d_in[11];
  const float* W_fs  = (const float*)d_in[12];
  const float* b_fs  = (const float*)d_in[13];
  const float* W1    = (const float*)d_in[14];
  const float* b1    = (const float*)d_in[15];
  const float* W2    = (const float*)d_in[16];
  const float* b2    = (const float*)d_in[17];
  const float* W3    = (const float*)d_in[18];
  const float* b3    = (const float*)d_in[19];
  const int*   edge  = (const int*)d_in[20];
  const int*   bbox  = (const int*)d_in[21];
  float* out = (float*)d_out;

  // ---- workspace layout (~221.5 MB; known-good budget >= 233 MB) ----
  float* p = (float*)d_ws;
  float* feats  = p; p += (size_t)NN * FUS;
  float* sfeats = p; p += (size_t)NN * FUS;
  float* PQ     = p; p += (size_t)2 * NN * CH;    // 12.8M floats
  _Float16* PQi = (_Float16*)PQ;
  _Float16* Qi  = PQi + (size_t)NN * 256;
  // overlays inside PQ (live only AFTER the last k_conv2):
  _Float16* aPack = (_Float16*)PQ;
  _Float16* WfH   = aPack + (size_t)784 * 12 * 2048;
  float* pooled   = (float*)(WfH + (size_t)FUS * 1024);
  float* sb   = PQ;
  float* fsup = sb + (size_t)NB * FUS;
  float* h1   = fsup + (size_t)NB * 1024;
  float* h2b  = h1 + (size_t)NB * 512;
  _Float16* bbH = (_Float16*)(h2b + (size_t)NB * 256);
  _Float16* W1H = bbH + (size_t)NB_PAD * K1;
  // CSR payload + misc after PQ region:
  _Float16* sea8 = (_Float16*)p;
  int* ssrc    = (int*)(sea8 + (size_t)NE * 8);
  int* row_ptr = ssrc + NE;
  int* deg     = row_ptr + NN + 1;
  int* cursor  = deg + NN;
  int* seg     = cursor + NN;
  _Float16* WcatN = (_Float16*)(seg + NB + 1);
  _Float16* WcatS = WcatN + (size_t)128 * 256;
  int* bsum = (int*)(WcatS + (size_t)128 * 256);

  hipMemsetAsync(deg, 0, 2 * NN * sizeof(int), stream);  // deg + cursor

  // ---- CSR build (dst-sorted payload, parallel scan) + bbox segments ----
  k_deg<<<(NE + 255) / 256, 256, 0, stream>>>(edge, deg);
  k_scan1<<<SCAN_NBLK, 1024, 0, stream>>>(deg, row_ptr, bsum);
  k_scan2<<<1, 64, 0, stream>>>(bsum);
  k_scan3<<<(NN + 255) / 256, 256, 0, stream>>>(bsum, row_ptr);
  k_fill<<<(NE + 255) / 256, 256, 0, stream>>>(edge, eattr, row_ptr, cursor,
                                               ssrc, sea8);
  k_segstart<<<(NN + 255) / 256, 256, 0, stream>>>(bbox, seg);

  const int npq_grid = (NN + 31) / 32;

  // ---- conv 0 (head): both streams read x (K=8), scalar node transform ----
  k_node_pq<<<npq_grid, 256, 0, stream>>>(x, INCH, INCH, W_h, b_h, PQi, Qi, 0);
  k_node_pq<<<npq_grid, 256, 0, stream>>>(x, INCH, INCH, Ws_h, bs_h, PQi, Qi, 1);
  k_conv2<<<NN / 4, 256, 0, stream>>>(row_ptr, ssrc, sea8, PQi, Qi,
                                      W_h + 2 * INCH * CH, Ws_h + 2 * INCH * CH,
                                      feats, sfeats, 0, -1);

  // ---- residual blocks (K=128): MFMA node transform, both streams ----
  for (int i = 0; i < 2; ++i) {
    const float* Wi  = Wb  + (size_t)i * 262 * CH;
    const float* bi  = bb  + (size_t)i * CH;
    const float* Wsi = Wbs + (size_t)i * 262 * CH;
    const float* bsi = bbs + (size_t)i * CH;
    k_cvtWnpq<<<dim3(64, 2), 64, 0, stream>>>(Wi, Wsi, WcatN, WcatS);
    k_npq_mfma<<<dim3((NN + 63) / 64, 2), 256, 0, stream>>>(
        feats + i * CH, sfeats + i * CH, FUS, WcatN, WcatS, bi, bsi, PQi, Qi);
    k_conv2<<<NN / 4, 256, 0, stream>>>(row_ptr, ssrc, sea8, PQi, Qi,
                                        Wi + 2 * CH * CH, Wsi + 2 * CH * CH,
                                        feats, sfeats, i + 1, i);
  }

  // ---- pooling: packed-A f16 convert + MFMA GEMM + atomicMax ----
  k_cvtApack<<<784 * 12, 64, 0, stream>>>(feats, aPack);
  k_cvtB<1024, 64><<<12 * 64, 64, 0, stream>>>(W_f, WfH);
  hipMemsetAsync(pooled, 0, (size_t)NB * 1408 * sizeof(float), stream);
  k_pool_mfma<<<784 * 8, 256, 0, stream>>>(aPack, WfH, bbox, b_f, pooled);
  k_poolraw<<<NB, 256, 0, stream>>>(feats, sfeats, seg, pooled, sb);
  k_fusion_super<<<dim3(NB / 4, 2), 256, 0, stream>>>(sb, W_fs, b_fs, fsup);

  // ---- head MLP: concat->f16, W1->f16 frag, MFMA GEMM, then small MLPs ----
  k_cvt_cat<<<(int)(((size_t)NB_PAD * K1 / 8) / 256), 256, 0, stream>>>(
      pooled, fsup, sb, bbH);
  k_cvtB<512, 32><<<88 * 32, 64, 0, stream>>>(W1, W1H);
  k_mlp1_mfma<<<dim3(NB_PAD / 64, 4), 256, 0, stream>>>(bbH, W1H, b1, h1);
  k_mlp2<<<NB / 8, 256, 0, stream>>>(h1, W2, b2, h2b);
  k_mlp3<<<NB / 8, 256, 0, stream>>>(h2b, W3, b3, out);
}

// Round 4
// 930.979 us; speedup vs baseline: 1.1655x; 1.0087x over previous
//
#include <hip/hip_runtime.h>

#define NN      50000
#define NE      800000
#define INCH    8
#define CH      128
#define EA      6
#define NB      2000
#define NB_PAD  2048
#define NCLS    32
#define FUS     384
#define K1      2816   // 1408 + 1024 + 384
#define SCAN_NBLK 49   // (NN + 1023) / 1024

typedef _Float16 half8 __attribute__((ext_vector_type(8)));
typedef _Float16 h2 __attribute__((ext_vector_type(2)));
typedef float f32x4 __attribute__((ext_vector_type(4)));

// ---------- degree of dst nodes ----------
__global__ __launch_bounds__(256) void k_deg(const int* __restrict__ edge,
                                             int* __restrict__ deg) {
  int e = blockIdx.x * 256 + threadIdx.x;
  if (e < NE) atomicAdd(&deg[edge[NE + e]], 1);
}

// ---------- parallel scan, phase 1: per-block inclusive scan + block sums ----
__global__ __launch_bounds__(1024) void k_scan1(const int* __restrict__ deg,
                                                int* __restrict__ row_ptr,
                                                int* __restrict__ bsum) {
  __shared__ int wsum[16];
  const int t = threadIdx.x, lane = t & 63, w = t >> 6;
  const int i = blockIdx.x * 1024 + t;
  int x = (i < NN) ? deg[i] : 0;
#pragma unroll
  for (int off = 1; off < 64; off <<= 1) {
    int y = __shfl_up(x, off, 64);
    if (lane >= off) x += y;
  }
  if (lane == 63) wsum[w] = x;
  __syncthreads();
  if (w == 0 && lane < 16) {
    int s = wsum[lane];
#pragma unroll
    for (int off = 1; off < 16; off <<= 1) {
      int y = __shfl_up(s, off, 64);
      if (lane >= off) s += y;
    }
    wsum[lane] = s;
  }
  __syncthreads();
  int incl = x + ((w == 0) ? 0 : wsum[w - 1]);
  if (i < NN) row_ptr[i + 1] = incl;
  if (t == 1023) bsum[blockIdx.x] = incl;
}

// ---------- phase 2: single-wave exclusive scan of block sums ----------
__global__ __launch_bounds__(64) void k_scan2(int* __restrict__ bsum) {
  const int t = threadIdx.x;
  int x = (t < SCAN_NBLK) ? bsum[t] : 0;
#pragma unroll
  for (int off = 1; off < 64; off <<= 1) {
    int y = __shfl_up(x, off, 64);
    if (t >= off) x += y;
  }
  int ex = __shfl_up(x, 1, 64);
  if (t == 0) ex = 0;
  if (t < SCAN_NBLK) bsum[t] = ex;
}

// ---------- phase 3: add block offsets ----------
__global__ __launch_bounds__(256) void k_scan3(const int* __restrict__ bsum,
                                               int* __restrict__ row_ptr) {
  const int i = blockIdx.x * 256 + threadIdx.x;
  if (i == 0) row_ptr[0] = 0;
  if (i < NN) row_ptr[i + 1] += bsum[i >> 10];
}

// ---------- fill CSR payload: dst-sorted src + f16 e_attr ----------
__global__ __launch_bounds__(256) void k_fill(
    const int* __restrict__ edge, const float* __restrict__ eattr,
    const int* __restrict__ row_ptr, int* __restrict__ cursor,
    int* __restrict__ ssrc, _Float16* __restrict__ sea8) {
  int e = blockIdx.x * 256 + threadIdx.x;
  if (e >= NE) return;
  int s = edge[e], d = edge[NE + e];
  int idx = row_ptr[d] + atomicAdd(&cursor[d], 1);
  ssrc[idx] = s;
  half8 v;
#pragma unroll
  for (int j = 0; j < EA; ++j) v[j] = (_Float16)eattr[(size_t)e * EA + j];
  v[6] = (_Float16)0.f; v[7] = (_Float16)0.f;
  *(half8*)(sea8 + (size_t)idx * 8) = v;
}

// ---------- segment starts from sorted bbox_idx ----------
__global__ __launch_bounds__(256) void k_segstart(const int* __restrict__ bbox,
                                                  int* __restrict__ seg) {
  int i = blockIdx.x * 256 + threadIdx.x;
  if (i >= NN) return;
  int bc = bbox[i];
  int bp = (i == 0) ? -1 : bbox[i - 1];
  for (int j = bp + 1; j <= bc; ++j) seg[j] = i;
  if (i == NN - 1)
    for (int j = bc + 1; j <= NB; ++j) seg[j] = NN;
}

// ---------- head node transform (K=8): scalar path -> interleaved f16 ----------
__global__ __launch_bounds__(256) void k_node_pq(
    const float* __restrict__ X, int ldx, int K,
    const float* __restrict__ W, const float* __restrict__ bias,
    _Float16* __restrict__ PQi, _Float16* __restrict__ Qi, int sel) {
  const int t = threadIdx.x, lane = t & 63, wv = t >> 6;
  const int nbase = blockIdx.x * 32 + wv * 8;
  const int c = lane * 2;
  const float2 bv = *(const float2*)(bias + c);
  float2 pacc[8], qacc[8];
#pragma unroll
  for (int u = 0; u < 8; ++u) { pacc[u] = bv; qacc[u] = make_float2(0.f, 0.f); }
  const int xrow = min(nbase + (lane >> 3), NN - 1);
  const int xk = lane & 7;
  for (int k0 = 0; k0 < K; k0 += 8) {
    const float xv = X[(size_t)xrow * ldx + k0 + xk];
#pragma unroll
    for (int j = 0; j < 8; ++j) {
      const float2 w1 = *(const float2*)(W + (size_t)(k0 + j) * CH + c);
      const float2 w2 = *(const float2*)(W + (size_t)(K + k0 + j) * CH + c);
      const float2 wd = {w1.x - w2.x, w1.y - w2.y};
#pragma unroll
      for (int u = 0; u < 8; ++u) {
        const float xs = __shfl(xv, u * 8 + j, 64);
        pacc[u].x += xs * wd.x; pacc[u].y += xs * wd.y;
        qacc[u].x += xs * w2.x; qacc[u].y += xs * w2.y;
      }
    }
  }
#pragma unroll
  for (int u = 0; u < 8; ++u) {
    const int node = nbase + u;
    if (node < NN) {
      const size_t o = ((size_t)node * 64 + lane) * 4 + sel * 2;
      *(h2*)(PQi + o) = (h2){(_Float16)pacc[u].x, (_Float16)pacc[u].y};
      *(h2*)(Qi + o)  = (h2){(_Float16)qacc[u].x, (_Float16)qacc[u].y};
    }
  }
}

// ---------- pack [W1-W2 | W2] (K=128 x N=256) into f16 B-fragments ----------
__global__ __launch_bounds__(64) void k_cvtWnpq(
    const float* __restrict__ WN, const float* __restrict__ WS,
    _Float16* __restrict__ whN, _Float16* __restrict__ whS) {
  const float* W = blockIdx.y ? WS : WN;
  _Float16* wh   = blockIdx.y ? whS : whN;
  const int c = blockIdx.x >> 4, tile = blockIdx.x & 15;
  const int L = threadIdx.x;
  const int n = tile * 16 + (L & 15);
  const int k0 = c * 32 + (L >> 4) * 8;
  half8 v;
#pragma unroll
  for (int j = 0; j < 8; ++j) {
    const int k = k0 + j;
    float val;
    if (n < CH) val = W[(size_t)k * CH + n] - W[(size_t)(CH + k) * CH + n];
    else        val = W[(size_t)(CH + k) * CH + (n - CH)];
    v[j] = (_Float16)val;
  }
  *(half8*)(wh + (((size_t)(c * 16 + tile)) * 64 + L) * 8) = v;
}

// ---------- residual node transform on matrix cores (both streams) ----------
__global__ __launch_bounds__(256) void k_npq_mfma(
    const float* __restrict__ Xn, const float* __restrict__ Xs, int ldx,
    const _Float16* __restrict__ whN, const _Float16* __restrict__ whS,
    const float* __restrict__ biasN, const float* __restrict__ biasS,
    _Float16* __restrict__ PQi, _Float16* __restrict__ Qi) {
  const int sel = blockIdx.y;
  const float* X = sel ? Xs : Xn;
  const _Float16* wh = sel ? whS : whN;
  const float* bias = sel ? biasS : biasN;
  const int t = threadIdx.x, lane = t & 63, wv = t >> 6;
  const int nbase = blockIdx.x * 64;
  const int m = lane & 15, quad = lane >> 4;
  f32x4 acc[4][4];
#pragma unroll
  for (int i = 0; i < 4; ++i)
#pragma unroll
    for (int nt = 0; nt < 4; ++nt) acc[i][nt] = (f32x4){0.f, 0.f, 0.f, 0.f};
#pragma unroll
  for (int ks = 0; ks < 4; ++ks) {
    half8 b[4];
#pragma unroll
    for (int nt = 0; nt < 4; ++nt)
      b[nt] = *(const half8*)(wh + (((size_t)(ks * 16 + wv * 4 + nt)) * 64 + lane) * 8);
#pragma unroll
    for (int i = 0; i < 4; ++i) {
      const int row = min(nbase + i * 16 + m, NN - 1);
      const float* src = X + (size_t)row * ldx + ks * 32 + quad * 8;
      const float4 f0 = *(const float4*)src;
      const float4 f1 = *(const float4*)(src + 4);
      half8 a;
      a[0] = (_Float16)f0.x; a[1] = (_Float16)f0.y;
      a[2] = (_Float16)f0.z; a[3] = (_Float16)f0.w;
      a[4] = (_Float16)f1.x; a[5] = (_Float16)f1.y;
      a[6] = (_Float16)f1.z; a[7] = (_Float16)f1.w;
#pragma unroll
      for (int nt = 0; nt < 4; ++nt)
        acc[i][nt] = __builtin_amdgcn_mfma_f32_16x16x32_f16(a, b[nt], acc[i][nt],
                                                            0, 0, 0);
    }
  }
#pragma unroll
  for (int i = 0; i < 4; ++i)
#pragma unroll
    for (int nt = 0; nt < 4; ++nt) {
      const int col = wv * 64 + nt * 16 + m;
      const float bv = (col < CH) ? bias[col] : 0.f;
#pragma unroll
      for (int r = 0; r < 4; ++r) {
        const int row = nbase + i * 16 + quad * 4 + r;
        if (row < NN) {
          const float v = acc[i][nt][r] + bv;
          if (col < CH)
            PQi[((size_t)row * 64 + (col >> 1)) * 4 + sel * 2 + (col & 1)] =
                (_Float16)v;
          else {
            const int qc = col - CH;
            Qi[((size_t)row * 64 + (qc >> 1)) * 4 + sel * 2 + (qc & 1)] =
                (_Float16)v;
          }
        }
      }
    }
}

// ---------- fused dual-stream CSR conv ----------
// R2: packed-f16 edge math + 4-deep gather prefetch (110 -> <88 us).
__global__ __launch_bounds__(256) void k_conv2(
    const int* __restrict__ row_ptr, const int* __restrict__ ssrc,
    const _Float16* __restrict__ sea8,
    const _Float16* __restrict__ PQi, const _Float16* __restrict__ Qi,
    const float* __restrict__ Cn, const float* __restrict__ Cs,
    float* __restrict__ feats, float* __restrict__ sfeats,
    int cur, int prev) {
  const int t = threadIdx.x;
  const int lane = t & 63;
  const int node = blockIdx.x * 4 + (t >> 6);
  const int c = lane * 2;
  h2 cwnh[EA], cwsh[EA];
#pragma unroll
  for (int j = 0; j < EA; ++j) {
    const float2 a = *(const float2*)(Cn + j * CH + c);
    const float2 b = *(const float2*)(Cs + j * CH + c);
    cwnh[j] = (h2){(_Float16)a.x, (_Float16)a.y};
    cwsh[j] = (h2){(_Float16)b.x, (_Float16)b.y};
  }
  int i0 = __builtin_amdgcn_readfirstlane(row_ptr[node]);
  int i1 = __builtin_amdgcn_readfirstlane(row_ptr[node + 1]);
  const uint2 qv = *(const uint2*)(Qi + ((size_t)node * 64 + lane) * 4);
  const h2 qnh = *(const h2*)&qv.x;
  const h2 qsh = *(const h2*)&qv.y;
  const _Float16* pqL = PQi + (size_t)lane * 4;  // + s*256 per edge
  h2 anh = (h2){(_Float16)0.f, (_Float16)0.f};
  float as0 = 0.f, as1 = 0.f;
  const h2 zero = (h2){(_Float16)0.f, (_Float16)0.f};
#define COMP(PV, J)                                                        \
  {                                                                        \
    unsigned w0 = __shfl((int)ea_l.x, (J), 64);                            \
    unsigned w1 = __shfl((int)ea_l.y, (J), 64);                            \
    unsigned w2 = __shfl((int)ea_l.z, (J), 64);                            \
    const h2 ea01 = *(const h2*)&w0;                                       \
    const h2 ea23 = *(const h2*)&w1;                                       \
    const h2 ea45 = *(const h2*)&w2;                                       \
    h2 vn = *(const h2*)&PV.x + qnh;                                       \
    h2 vs = *(const h2*)&PV.y + qsh;                                       \
    h2 b;                                                                  \
    b = (h2){ea01[0], ea01[0]}; vn += b * cwnh[0]; vs += b * cwsh[0];      \
    b = (h2){ea01[1], ea01[1]}; vn += b * cwnh[1]; vs += b * cwsh[1];      \
    b = (h2){ea23[0], ea23[0]}; vn += b * cwnh[2]; vs += b * cwsh[2];      \
    b = (h2){ea23[1], ea23[1]}; vn += b * cwnh[3]; vs += b * cwsh[3];      \
    b = (h2){ea45[0], ea45[0]}; vn += b * cwnh[4]; vs += b * cwsh[4];      \
    b = (h2){ea45[1], ea45[1]}; vn += b * cwnh[5]; vs += b * cwsh[5];      \
    anh = __builtin_elementwise_max(anh, vn);                              \
    const h2 vsr = __builtin_elementwise_max(vs, zero);                    \
    as0 += (float)vsr[0]; as1 += (float)vsr[1];                            \
  }
  for (int base = i0; base < i1; base += 64) {
    const int cnt = min(64, i1 - base);
    int s_l = 0;
    uint4 ea_l = {0u, 0u, 0u, 0u};
    if (lane < cnt) {
      s_l = ssrc[base + lane];
      ea_l = *(const uint4*)(sea8 + (size_t)(base + lane) * 8);
    }
    int j = 0;
    for (; j + 4 <= cnt; j += 4) {
      // phase 1: broadcast src indices, issue 4 independent row gathers
      const int sa = __shfl(s_l, j, 64);
      const int sb = __shfl(s_l, j + 1, 64);
      const int sc = __shfl(s_l, j + 2, 64);
      const int sd = __shfl(s_l, j + 3, 64);
      const uint2 pva = *(const uint2*)(pqL + (size_t)sa * 256);
      const uint2 pvb = *(const uint2*)(pqL + (size_t)sb * 256);
      const uint2 pvc = *(const uint2*)(pqL + (size_t)sc * 256);
      const uint2 pvd = *(const uint2*)(pqL + (size_t)sd * 256);
      // phase 2: packed-f16 compute per edge
      COMP(pva, j) COMP(pvb, j + 1) COMP(pvc, j + 2) COMP(pvd, j + 3)
    }
    for (; j < cnt; ++j) {
      const int sa = __shfl(s_l, j, 64);
      const uint2 pva = *(const uint2*)(pqL + (size_t)sa * 256);
      COMP(pva, j)
    }
  }
#undef COMP
  float an0 = (float)anh[0], an1 = (float)anh[1];
  const float inv = 1.f / fmaxf((float)(i1 - i0), 1.f);
  as0 *= inv; as1 *= inv;
  const size_t o = (size_t)node * FUS + (size_t)cur * CH + c;
  if (prev >= 0) {
    const size_t op = (size_t)node * FUS + (size_t)prev * CH + c;
    const float2 prn = *(const float2*)(feats + op);
    const float2 prs = *(const float2*)(sfeats + op);
    an0 += prn.x; an1 += prn.y;
    as0 += prs.x; as1 += prs.y;
  }
  float2 on = {an0, an1}, os = {as0, as1};
  *(float2*)(feats + o) = on;
  *(float2*)(sfeats + o) = os;
}

// ---------- pack feats -> f16 A-fragments: [rb][ks][i][lane][8] ----------
__global__ __launch_bounds__(64) void k_cvtApack(const float* __restrict__ feats,
                                                 _Float16* __restrict__ ap) {
  const int rb = blockIdx.x / 12, ks = blockIdx.x % 12;
  const int L = threadIdx.x, m = L & 15, quad = L >> 4;
#pragma unroll
  for (int i = 0; i < 4; ++i) {
    const int row = rb * 64 + i * 16 + m;
    const int rowc = min(row, NN - 1);
    const float* src = feats + (size_t)rowc * FUS + ks * 32 + quad * 8;
    half8 v;
    if (row < NN) {
      const float4 f0 = *(const float4*)src;
      const float4 f1 = *(const float4*)(src + 4);
      v[0] = (_Float16)f0.x; v[1] = (_Float16)f0.y;
      v[2] = (_Float16)f0.z; v[3] = (_Float16)f0.w;
      v[4] = (_Float16)f1.x; v[5] = (_Float16)f1.y;
      v[6] = (_Float16)f1.z; v[7] = (_Float16)f1.w;
    } else {
#pragma unroll
      for (int j = 0; j < 8; ++j) v[j] = (_Float16)0.f;
    }
    *(half8*)(ap + (((size_t)(rb * 12 + ks) * 4 + i) * 64 + L) * 8) = v;
  }
}

// ---------- convert + pack W (KxN f32) into f16 B-fragment order ----------
template <int N, int NT>
__global__ __launch_bounds__(64) void k_cvtB(const float* __restrict__ W,
                                             _Float16* __restrict__ wh) {
  const int c = blockIdx.x / NT;
  const int tile = blockIdx.x % NT;
  const int L = threadIdx.x;
  const int n = tile * 16 + (L & 15);
  const int k0 = c * 32 + (L >> 4) * 8;
  half8 v;
#pragma unroll
  for (int j = 0; j < 8; ++j) v[j] = (_Float16)W[(size_t)(k0 + j) * N + n];
  *(half8*)(wh + (((size_t)(c * NT + tile)) * 64 + L) * 8) = v;
}

// ---------- fusion GEMM + segment max ----
// R0: cg fastest within XCD (FETCH 123->22MB). R1: two-phase epilogue,
// 17KB LDS, s_bb cache. R3: the (256,8) pin capped the unified RF at 64
// regs/wave (32 VGPR + 32 AGPR acc) -> zero load pipelining, MfmaUtil 18%.
// Relax to 6 waves/EU (~85 regs) + explicit 2-stage prefetch: B(ks+1) and
// next A-fragment load during current MFMAs (all indices compile-time).
__global__ __launch_bounds__(256, 6) void k_pool_mfma(
    const _Float16* __restrict__ aP, const _Float16* __restrict__ wh,
    const int* __restrict__ bbox, const float* __restrict__ bf,
    float* __restrict__ pooled) {
  __shared__ float cl[32 * 132];
  __shared__ int s_bb[64];
  const int t = threadIdx.x, lane = t & 63, wv = t >> 6;
  const int fid = blockIdx.x;
  const int xcd = fid & 7, slot = fid >> 3;
  const int cg = slot & 7;
  const int rb = xcd * 98 + (slot >> 3);
  const int nbase = rb * 64;
  const int m = lane & 15, quad = lane >> 4;
  if (t < 64) s_bb[t] = bbox[min(nbase + t, NN - 1)];
  f32x4 acc[4][2];
#pragma unroll
  for (int i = 0; i < 4; ++i)
#pragma unroll
    for (int nt = 0; nt < 2; ++nt) acc[i][nt] = (f32x4){0.f, 0.f, 0.f, 0.f};
  const _Float16* apb = aP + (size_t)rb * 12 * 2048 + (size_t)lane * 8;
  const _Float16* bp = wh + ((size_t)(cg * 8 + wv * 2) * 64 + lane) * 8;
  half8 b0 = *(const half8*)(bp);
  half8 b1 = *(const half8*)(bp + 512);
  half8 an = *(const half8*)(apb);  // (ks=0, i=0)
#pragma unroll
  for (int ks = 0; ks < 12; ++ks) {
    const half8 b0c = b0, b1c = b1;
    if (ks < 11) {
      b0 = *(const half8*)(bp + (size_t)(ks + 1) * 32768);
      b1 = *(const half8*)(bp + (size_t)(ks + 1) * 32768 + 512);
    }
#pragma unroll
    for (int i = 0; i < 4; ++i) {
      const half8 ac = an;
      if (!(ks == 11 && i == 3)) {
        const int nks = (i == 3) ? ks + 1 : ks;
        const int ni = (i == 3) ? 0 : i + 1;
        an = *(const half8*)(apb + ((size_t)nks * 4 + ni) * 512);
      }
      acc[i][0] = __builtin_amdgcn_mfma_f32_16x16x32_f16(ac, b0c, acc[i][0], 0, 0, 0);
      acc[i][1] = __builtin_amdgcn_mfma_f32_16x16x32_f16(ac, b1c, acc[i][1], 0, 0, 0);
    }
  }
  const int col = t & 127, rh = t >> 7;
  const int gcol = cg * 128 + col;
  const float bias = bf[gcol];
#pragma unroll
  for (int p = 0; p < 2; ++p) {
    __syncthreads();  // p=0: orders s_bb; p=1: phase-0 readers done with cl
#pragma unroll
    for (int ii = 0; ii < 2; ++ii)
#pragma unroll
      for (int nt = 0; nt < 2; ++nt) {
        const int scol = wv * 32 + nt * 16 + m;
#pragma unroll
        for (int r = 0; r < 4; ++r)
          cl[(ii * 16 + quad * 4 + r) * 132 + scol] = acc[p * 2 + ii][nt][r];
      }
    __syncthreads();
    int curb = -1;
    float mx = 0.f;
    for (int rr = 0; rr < 16; ++rr) {
      const int rl = rh * 16 + rr;
      const int node = nbase + p * 32 + rl;
      if (node >= NN) break;
      const int bid = s_bb[p * 32 + rl];
      const float v = fmaxf(cl[rl * 132 + col] + bias, 0.f);
      if (bid != curb) {
        if (curb >= 0)
          atomicMax((unsigned*)(pooled + (size_t)curb * 1408 + gcol),
                    __float_as_uint(mx));
        curb = bid;
        mx = v;
      } else {
        mx = fmaxf(mx, v);
      }
    }
    if (curb >= 0)
      atomicMax((unsigned*)(pooled + (size_t)curb * 1408 + gcol),
                __float_as_uint(mx));
  }
}

// ---------- raw-feats bbox max + sfeats bbox mean ----------
__global__ __launch_bounds__(256) void k_poolraw(
    const float* __restrict__ feats, const float* __restrict__ sfeats,
    const int* __restrict__ seg, float* __restrict__ pooled,
    float* __restrict__ sb) {
  const int b = blockIdx.x, t = threadIdx.x;
  if (t >= 192) return;
  const int c2 = t * 2;
  const int n0 = __builtin_amdgcn_readfirstlane(seg[b]);
  const int n1 = __builtin_amdgcn_readfirstlane(seg[b + 1]);
  float2 fmx = {0.f, 0.f}, ss = {0.f, 0.f};
  for (int n = n0; n < n1; ++n) {
    const float2 f2 = *(const float2*)(feats + (size_t)n * FUS + c2);
    fmx.x = fmaxf(fmx.x, f2.x); fmx.y = fmaxf(fmx.y, f2.y);
    const float2 s2 = *(const float2*)(sfeats + (size_t)n * FUS + c2);
    ss.x += s2.x; ss.y += s2.y;
  }
  *(float2*)(pooled + (size_t)b * 1408 + 1024 + c2) = fmx;
  const float inv = 1.f / fmaxf((float)(n1 - n0), 1.f);
  float2 o = {ss.x * inv, ss.y * inv};
  *(float2*)(sb + (size_t)b * FUS + c2) = o;
}

// ---------- fusion_super = relu(sb @ Wfs + bfs), lane-distributed x ----------
__global__ __launch_bounds__(256) void k_fusion_super(
    const float* __restrict__ sb, const float* __restrict__ Wfs,
    const float* __restrict__ bfs, float* __restrict__ fs) {
  const int t = threadIdx.x, lane = t & 63, wv = t >> 6;
  const int r0 = blockIdx.x * 4;
  const int c = (blockIdx.y * 4 + wv) * 128 + lane * 2;
  float2 acc[4];
#pragma unroll
  for (int u = 0; u < 4; ++u) acc[u] = make_float2(0.f, 0.f);
  const int xr = r0 + (lane >> 4), xk = lane & 15;
  for (int k0 = 0; k0 < FUS; k0 += 16) {
    const float xv = sb[(size_t)xr * FUS + k0 + xk];
#pragma unroll
    for (int j = 0; j < 16; ++j) {
      const float2 w = *(const float2*)(Wfs + (size_t)(k0 + j) * 1024 + c);
#pragma unroll
      for (int u = 0; u < 4; ++u) {
        const float xs = __shfl(xv, u * 16 + j, 64);
        acc[u].x += xs * w.x; acc[u].y += xs * w.y;
      }
    }
  }
  const float2 b = *(const float2*)(bfs + c);
#pragma unroll
  for (int u = 0; u < 4; ++u) {
    float2 o = {fmaxf(acc[u].x + b.x, 0.f), fmaxf(acc[u].y + b.y, 0.f)};
    *(float2*)(fs + (size_t)(r0 + u) * 1024 + c) = o;
  }
}

// ---------- concat [pooled | fsup | sb] -> f16 bbH[NB_PAD][K1], zero-padded ----
__global__ __launch_bounds__(256) void k_cvt_cat(
    const float* __restrict__ pooled, const float* __restrict__ fsup,
    const float* __restrict__ sb, _Float16* __restrict__ bbH) {
  const size_t off = ((size_t)blockIdx.x * 256 + threadIdx.x) * 8;
  const int row = (int)(off / K1);
  const int col = (int)(off - (size_t)row * K1);
  half8 v;
  if (row < NB) {
    const float* src;
    if (col < 1408)      src = pooled + (size_t)row * 1408 + col;
    else if (col < 2432) src = fsup + (size_t)row * 1024 + (col - 1408);
    else                 src = sb + (size_t)row * FUS + (col - 2432);
    const float4 f0 = *(const float4*)src;
    const float4 f1 = *(const float4*)(src + 4);
    v[0] = (_Float16)f0.x; v[1] = (_Float16)f0.y;
    v[2] = (_Float16)f0.z; v[3] = (_Float16)f0.w;
    v[4] = (_Float16)f1.x; v[5] = (_Float16)f1.y;
    v[6] = (_Float16)f1.z; v[7] = (_Float16)f1.w;
  } else {
#pragma unroll
    for (int j = 0; j < 8; ++j) v[j] = (_Float16)0.f;
  }
  *(half8*)(bbH + off) = v;
}

// ---------- h1 = relu(bbH @ W1 + b1) on matrix cores ----------
__global__ __launch_bounds__(256) void k_mlp1_mfma(
    const _Float16* __restrict__ bbH, const _Float16* __restrict__ wh,
    const float* __restrict__ b1, float* __restrict__ h1) {
  const int t = threadIdx.x, lane = t & 63, wv = t >> 6;
  const int nbase = blockIdx.x * 64;
  const int cg = blockIdx.y;
  const int m = lane & 15, quad = lane >> 4;
  f32x4 acc[4][2];
#pragma unroll
  for (int i = 0; i < 4; ++i)
#pragma unroll
    for (int nt = 0; nt < 2; ++nt) acc[i][nt] = (f32x4){0.f, 0.f, 0.f, 0.f};
  const _Float16* ap = bbH + (size_t)(nbase + m) * K1 + quad * 8;
  const _Float16* bp = wh + ((size_t)(cg * 8 + wv * 2) * 64 + lane) * 8;
#pragma unroll 4
  for (int ks = 0; ks < 88; ++ks) {
    const half8 b0 = *(const half8*)(bp + (size_t)ks * 16384);
    const half8 b1v = *(const half8*)(bp + (size_t)ks * 16384 + 512);
#pragma unroll
    for (int i = 0; i < 4; ++i) {
      const half8 a = *(const half8*)(ap + (size_t)(i * 16) * K1 + ks * 32);
      acc[i][0] = __builtin_amdgcn_mfma_f32_16x16x32_f16(a, b0, acc[i][0], 0, 0, 0);
      acc[i][1] = __builtin_amdgcn_mfma_f32_16x16x32_f16(a, b1v, acc[i][1], 0, 0, 0);
    }
  }
#pragma unroll
  for (int i = 0; i < 4; ++i)
#pragma unroll
    for (int nt = 0; nt < 2; ++nt) {
      const int gcol = cg * 128 + wv * 32 + nt * 16 + m;
      const float bias = b1[gcol];
#pragma unroll
      for (int r = 0; r < 4; ++r) {
        const int row = nbase + i * 16 + quad * 4 + r;
        if (row < NB)
          h1[(size_t)row * 512 + gcol] = fmaxf(acc[i][nt][r] + bias, 0.f);
      }
    }
}

// ---------- h2 = relu(h1 @ W2 + b2) ----------
__global__ __launch_bounds__(256) void k_mlp2(
    const float* __restrict__ h1, const float* __restrict__ W2,
    const float* __restrict__ b2, float* __restrict__ h2o) {
  const int r0 = blockIdx.x * 8, t = threadIdx.x;
  float acc[8];
#pragma unroll
  for (int u = 0; u < 8; ++u) acc[u] = 0.f;
  for (int k = 0; k < 512; ++k) {
    float w = W2[(size_t)k * 256 + t];
#pragma unroll
    for (int u = 0; u < 8; ++u) acc[u] += h1[(size_t)(r0 + u) * 512 + k] * w;
  }
  float bv = b2[t];
#pragma unroll
  for (int u = 0; u < 8; ++u)
    h2o[(size_t)(r0 + u) * 256 + t] = fmaxf(acc[u] + bv, 0.f);
}

// ---------- logits = h2 @ W3 + b3 ----------
__global__ __launch_bounds__(256) void k_mlp3(
    const float* __restrict__ h2i, const float* __restrict__ W3,
    const float* __restrict__ b3, float* __restrict__ out) {
  const int r0 = blockIdx.x * 8, t = threadIdx.x;
  const int u = t >> 5, oc = t & 31;
  const float* x = h2i + (size_t)(r0 + u) * 256;
  float acc = 0.f;
  for (int k = 0; k < 256; ++k) acc += x[k] * W3[(size_t)k * 32 + oc];
  out[(size_t)(r0 + u) * 32 + oc] = acc + b3[oc];
}

extern "C" void kernel_launch(void* const* d_in, const int* in_sizes, int n_in,
                              void* d_out, int out_size, void* d_ws, size_t ws_size,
                              hipStream_t stream) {
  const float* x     = (const float*)d_in[0];
  const float* eattr = (const float*)d_in[1];
  const float* W_h   = (const float*)d_in[2];
  const float* b_h   = (const float*)d_in[3];
  const float* Ws_h  = (const float*)d_in[4];
  const float* bs_h  = (const float*)d_in[5];
  const float* Wb    = (const float*)d_in[6];
  const float* bb    = (const float*)d_in[7];
  const float* Wbs   = (const float*)d_in[8];
  const float* bbs   = (const float*)d_in[9];
  const float* W_f   = (const float*)d_in[10];
  const float* b_f   = (const float*)d_in[11];
  const float* W_fs  = (const float*)d_in[12];
  const float* b_fs  = (const float*)d_in[13];
  const float* W1    = (const float*)d_in[14];
  const float* b1    = (const float*)d_in[15];
  const float* W2    = (const float*)d_in[16];
  const float* b2    = (const float*)d_in[17];
  const float* W3    = (const float*)d_in[18];
  const float* b3    = (const float*)d_in[19];
  const int*   edge  = (const int*)d_in[20];
  const int*   bbox  = (const int*)d_in[21];
  float* out = (float*)d_out;

  // ---- workspace layout (~221.5 MB; known-good budget >= 233 MB) ----
  float* p = (float*)d_ws;
  float* feats  = p; p += (size_t)NN * FUS;
  float* sfeats = p; p += (size_t)NN * FUS;
  float* PQ     = p; p += (size_t)2 * NN * CH;    // 12.8M floats
  _Float16* PQi = (_Float16*)PQ;
  _Float16* Qi  = PQi + (size_t)NN * 256;
  // overlays inside PQ (live only AFTER the last k_conv2):
  _Float16* aPack = (_Float16*)PQ;
  _Float16* WfH   = aPack + (size_t)784 * 12 * 2048;
  float* pooled   = (float*)(WfH + (size_t)FUS * 1024);
  float* sb   = PQ;
  float* fsup = sb + (size_t)NB * FUS;
  float* h1   = fsup + (size_t)NB * 1024;
  float* h2b  = h1 + (size_t)NB * 512;
  _Float16* bbH = (_Float16*)(h2b + (size_t)NB * 256);
  _Float16* W1H = bbH + (size_t)NB_PAD * K1;
  // CSR payload + misc after PQ region:
  _Float16* sea8 = (_Float16*)p;
  int* ssrc    = (int*)(sea8 + (size_t)NE * 8);
  int* row_ptr = ssrc + NE;
  int* deg     = row_ptr + NN + 1;
  int* cursor  = deg + NN;
  int* seg     = cursor + NN;
  _Float16* WcatN = (_Float16*)(seg + NB + 1);
  _Float16* WcatS = WcatN + (size_t)128 * 256;
  int* bsum = (int*)(WcatS + (size_t)128 * 256);

  hipMemsetAsync(deg, 0, 2 * NN * sizeof(int), stream);  // deg + cursor

  // ---- CSR build (dst-sorted payload, parallel scan) + bbox segments ----
  k_deg<<<(NE + 255) / 256, 256, 0, stream>>>(edge, deg);
  k_scan1<<<SCAN_NBLK, 1024, 0, stream>>>(deg, row_ptr, bsum);
  k_scan2<<<1, 64, 0, stream>>>(bsum);
  k_scan3<<<(NN + 255) / 256, 256, 0, stream>>>(bsum, row_ptr);
  k_fill<<<(NE + 255) / 256, 256, 0, stream>>>(edge, eattr, row_ptr, cursor,
                                               ssrc, sea8);
  k_segstart<<<(NN + 255) / 256, 256, 0, stream>>>(bbox, seg);

  const int npq_grid = (NN + 31) / 32;

  // ---- conv 0 (head): both streams read x (K=8), scalar node transform ----
  k_node_pq<<<npq_grid, 256, 0, stream>>>(x, INCH, INCH, W_h, b_h, PQi, Qi, 0);
  k_node_pq<<<npq_grid, 256, 0, stream>>>(x, INCH, INCH, Ws_h, bs_h, PQi, Qi, 1);
  k_conv2<<<NN / 4, 256, 0, stream>>>(row_ptr, ssrc, sea8, PQi, Qi,
                                      W_h + 2 * INCH * CH, Ws_h + 2 * INCH * CH,
                                      feats, sfeats, 0, -1);

  // ---- residual blocks (K=128): MFMA node transform, both streams ----
  for (int i = 0; i < 2; ++i) {
    const float* Wi  = Wb  + (size_t)i * 262 * CH;
    const float* bi  = bb  + (size_t)i * CH;
    const float* Wsi = Wbs + (size_t)i * 262 * CH;
    const float* bsi = bbs + (size_t)i * CH;
    k_cvtWnpq<<<dim3(64, 2), 64, 0, stream>>>(Wi, Wsi, WcatN, WcatS);
    k_npq_mfma<<<dim3((NN + 63) / 64, 2), 256, 0, stream>>>(
        feats + i * CH, sfeats + i * CH, FUS, WcatN, WcatS, bi, bsi, PQi, Qi);
    k_conv2<<<NN / 4, 256, 0, stream>>>(row_ptr, ssrc, sea8, PQi, Qi,
                                        Wi + 2 * CH * CH, Wsi + 2 * CH * CH,
                                        feats, sfeats, i + 1, i);
  }

  // ---- pooling: packed-A f16 convert + MFMA GEMM + atomicMax ----
  k_cvtApack<<<784 * 12, 64, 0, stream>>>(feats, aPack);
  k_cvtB<1024, 64><<<12 * 64, 64, 0, stream>>>(W_f, WfH);
  hipMemsetAsync(pooled, 0, (size_t)NB * 1408 * sizeof(float), stream);
  k_pool_mfma<<<784 * 8, 256, 0, stream>>>(aPack, WfH, bbox, b_f, pooled);
  k_poolraw<<<NB, 256, 0, stream>>>(feats, sfeats, seg, pooled, sb);
  k_fusion_super<<<dim3(NB / 4, 2), 256, 0, stream>>>(sb, W_fs, b_fs, fsup);

  // ---- head MLP: concat->f16, W1->f16 frag, MFMA GEMM, then small MLPs ----
  k_cvt_cat<<<(int)(((size_t)NB_PAD * K1 / 8) / 256), 256, 0, stream>>>(
      pooled, fsup, sb, bbH);
  k_cvtB<512, 32><<<88 * 32, 64, 0, stream>>>(W1, W1H);
  k_mlp1_mfma<<<dim3(NB_PAD / 64, 4), 256, 0, stream>>>(bbH, W1H, b1, h1);
  k_mlp2<<<NB / 8, 256, 0, stream>>>(h1, W2, b2, h2b);
  k_mlp3<<<NB / 8, 256, 0, stream>>>(h2b, W3, b3, out);
}

// Round 5
// 901.578 us; speedup vs baseline: 1.2035x; 1.0326x over previous
//
#include <hip/hip_runtime.h>

#define NN      50000
#define NE      800000
#define INCH    8
#define CH      128
#define EA      6
#define NB      2000
#define NB_PAD  2048
#define NCLS    32
#define FUS     384
#define K1      2816   // 1408 + 1024 + 384
#define SCAN_NBLK 49   // (NN + 1023) / 1024

typedef _Float16 half8 __attribute__((ext_vector_type(8)));
typedef _Float16 h2 __attribute__((ext_vector_type(2)));
typedef float f32x4 __attribute__((ext_vector_type(4)));

// ---------- degree of dst nodes ----------
__global__ __launch_bounds__(256) void k_deg(const int* __restrict__ edge,
                                             int* __restrict__ deg) {
  int e = blockIdx.x * 256 + threadIdx.x;
  if (e < NE) atomicAdd(&deg[edge[NE + e]], 1);
}

// ---------- parallel scan, phase 1: per-block inclusive scan + block sums ----
__global__ __launch_bounds__(1024) void k_scan1(const int* __restrict__ deg,
                                                int* __restrict__ row_ptr,
                                                int* __restrict__ bsum) {
  __shared__ int wsum[16];
  const int t = threadIdx.x, lane = t & 63, w = t >> 6;
  const int i = blockIdx.x * 1024 + t;
  int x = (i < NN) ? deg[i] : 0;
#pragma unroll
  for (int off = 1; off < 64; off <<= 1) {
    int y = __shfl_up(x, off, 64);
    if (lane >= off) x += y;
  }
  if (lane == 63) wsum[w] = x;
  __syncthreads();
  if (w == 0 && lane < 16) {
    int s = wsum[lane];
#pragma unroll
    for (int off = 1; off < 16; off <<= 1) {
      int y = __shfl_up(s, off, 64);
      if (lane >= off) s += y;
    }
    wsum[lane] = s;
  }
  __syncthreads();
  int incl = x + ((w == 0) ? 0 : wsum[w - 1]);
  if (i < NN) row_ptr[i + 1] = incl;
  if (t == 1023) bsum[blockIdx.x] = incl;
}

// ---------- phase 2: single-wave exclusive scan of block sums ----------
__global__ __launch_bounds__(64) void k_scan2(int* __restrict__ bsum) {
  const int t = threadIdx.x;
  int x = (t < SCAN_NBLK) ? bsum[t] : 0;
#pragma unroll
  for (int off = 1; off < 64; off <<= 1) {
    int y = __shfl_up(x, off, 64);
    if (t >= off) x += y;
  }
  int ex = __shfl_up(x, 1, 64);
  if (t == 0) ex = 0;
  if (t < SCAN_NBLK) bsum[t] = ex;
}

// ---------- phase 3: add block offsets ----------
__global__ __launch_bounds__(256) void k_scan3(const int* __restrict__ bsum,
                                               int* __restrict__ row_ptr) {
  const int i = blockIdx.x * 256 + threadIdx.x;
  if (i == 0) row_ptr[0] = 0;
  if (i < NN) row_ptr[i + 1] += bsum[i >> 10];
}

// ---------- fill CSR payload: dst-sorted src + f16 e_attr ----------
__global__ __launch_bounds__(256) void k_fill(
    const int* __restrict__ edge, const float* __restrict__ eattr,
    const int* __restrict__ row_ptr, int* __restrict__ cursor,
    int* __restrict__ ssrc, _Float16* __restrict__ sea8) {
  int e = blockIdx.x * 256 + threadIdx.x;
  if (e >= NE) return;
  int s = edge[e], d = edge[NE + e];
  int idx = row_ptr[d] + atomicAdd(&cursor[d], 1);
  ssrc[idx] = s;
  half8 v;
#pragma unroll
  for (int j = 0; j < EA; ++j) v[j] = (_Float16)eattr[(size_t)e * EA + j];
  v[6] = (_Float16)0.f; v[7] = (_Float16)0.f;
  *(half8*)(sea8 + (size_t)idx * 8) = v;
}

// ---------- segment starts from sorted bbox_idx ----------
__global__ __launch_bounds__(256) void k_segstart(const int* __restrict__ bbox,
                                                  int* __restrict__ seg) {
  int i = blockIdx.x * 256 + threadIdx.x;
  if (i >= NN) return;
  int bc = bbox[i];
  int bp = (i == 0) ? -1 : bbox[i - 1];
  for (int j = bp + 1; j <= bc; ++j) seg[j] = i;
  if (i == NN - 1)
    for (int j = bc + 1; j <= NB; ++j) seg[j] = NN;
}

// ---------- head node transform (K=8), both streams via blockIdx.y ----------
__global__ __launch_bounds__(256) void k_node_pq(
    const float* __restrict__ X, int ldx, int K,
    const float* __restrict__ WN, const float* __restrict__ bN,
    const float* __restrict__ WS, const float* __restrict__ bS,
    _Float16* __restrict__ PQi, _Float16* __restrict__ Qi) {
  const int sel = blockIdx.y;
  const float* W = sel ? WS : WN;
  const float* bias = sel ? bS : bN;
  const int t = threadIdx.x, lane = t & 63, wv = t >> 6;
  const int nbase = blockIdx.x * 32 + wv * 8;
  const int c = lane * 2;
  const float2 bv = *(const float2*)(bias + c);
  float2 pacc[8], qacc[8];
#pragma unroll
  for (int u = 0; u < 8; ++u) { pacc[u] = bv; qacc[u] = make_float2(0.f, 0.f); }
  const int xrow = min(nbase + (lane >> 3), NN - 1);
  const int xk = lane & 7;
  for (int k0 = 0; k0 < K; k0 += 8) {
    const float xv = X[(size_t)xrow * ldx + k0 + xk];
#pragma unroll
    for (int j = 0; j < 8; ++j) {
      const float2 w1 = *(const float2*)(W + (size_t)(k0 + j) * CH + c);
      const float2 w2 = *(const float2*)(W + (size_t)(K + k0 + j) * CH + c);
      const float2 wd = {w1.x - w2.x, w1.y - w2.y};
#pragma unroll
      for (int u = 0; u < 8; ++u) {
        const float xs = __shfl(xv, u * 8 + j, 64);
        pacc[u].x += xs * wd.x; pacc[u].y += xs * wd.y;
        qacc[u].x += xs * w2.x; qacc[u].y += xs * w2.y;
      }
    }
  }
#pragma unroll
  for (int u = 0; u < 8; ++u) {
    const int node = nbase + u;
    if (node < NN) {
      const size_t o = ((size_t)node * 64 + lane) * 4 + sel * 2;
      *(h2*)(PQi + o) = (h2){(_Float16)pacc[u].x, (_Float16)pacc[u].y};
      *(h2*)(Qi + o)  = (h2){(_Float16)qacc[u].x, (_Float16)qacc[u].y};
    }
  }
}

// ---------- pack [W1-W2 | W2] into f16 B-frags, both res-blocks (z) ----------
__global__ __launch_bounds__(64) void k_cvtWnpq(
    const float* __restrict__ WbAll, const float* __restrict__ WbsAll,
    _Float16* __restrict__ whN, _Float16* __restrict__ whS) {
  const int blk = blockIdx.z;
  const float* W = (blockIdx.y ? WbsAll : WbAll) + (size_t)blk * 262 * CH;
  _Float16* wh   = (blockIdx.y ? whS : whN) + (size_t)blk * 32768;
  const int c = blockIdx.x >> 4, tile = blockIdx.x & 15;
  const int L = threadIdx.x;
  const int n = tile * 16 + (L & 15);
  const int k0 = c * 32 + (L >> 4) * 8;
  half8 v;
#pragma unroll
  for (int j = 0; j < 8; ++j) {
    const int k = k0 + j;
    float val;
    if (n < CH) val = W[(size_t)k * CH + n] - W[(size_t)(CH + k) * CH + n];
    else        val = W[(size_t)(CH + k) * CH + (n - CH)];
    v[j] = (_Float16)val;
  }
  *(half8*)(wh + (((size_t)(c * 16 + tile)) * 64 + L) * 8) = v;
}

// ---------- residual node transform on matrix cores (both streams) ----------
__global__ __launch_bounds__(256) void k_npq_mfma(
    const float* __restrict__ Xn, const float* __restrict__ Xs, int ldx,
    const _Float16* __restrict__ whN, const _Float16* __restrict__ whS,
    const float* __restrict__ biasN, const float* __restrict__ biasS,
    _Float16* __restrict__ PQi, _Float16* __restrict__ Qi) {
  const int sel = blockIdx.y;
  const float* X = sel ? Xs : Xn;
  const _Float16* wh = sel ? whS : whN;
  const float* bias = sel ? biasS : biasN;
  const int t = threadIdx.x, lane = t & 63, wv = t >> 6;
  const int nbase = blockIdx.x * 64;
  const int m = lane & 15, quad = lane >> 4;
  f32x4 acc[4][4];
#pragma unroll
  for (int i = 0; i < 4; ++i)
#pragma unroll
    for (int nt = 0; nt < 4; ++nt) acc[i][nt] = (f32x4){0.f, 0.f, 0.f, 0.f};
#pragma unroll
  for (int ks = 0; ks < 4; ++ks) {
    half8 b[4];
#pragma unroll
    for (int nt = 0; nt < 4; ++nt)
      b[nt] = *(const half8*)(wh + (((size_t)(ks * 16 + wv * 4 + nt)) * 64 + lane) * 8);
#pragma unroll
    for (int i = 0; i < 4; ++i) {
      const int row = min(nbase + i * 16 + m, NN - 1);
      const float* src = X + (size_t)row * ldx + ks * 32 + quad * 8;
      const float4 f0 = *(const float4*)src;
      const float4 f1 = *(const float4*)(src + 4);
      half8 a;
      a[0] = (_Float16)f0.x; a[1] = (_Float16)f0.y;
      a[2] = (_Float16)f0.z; a[3] = (_Float16)f0.w;
      a[4] = (_Float16)f1.x; a[5] = (_Float16)f1.y;
      a[6] = (_Float16)f1.z; a[7] = (_Float16)f1.w;
#pragma unroll
      for (int nt = 0; nt < 4; ++nt)
        acc[i][nt] = __builtin_amdgcn_mfma_f32_16x16x32_f16(a, b[nt], acc[i][nt],
                                                            0, 0, 0);
    }
  }
#pragma unroll
  for (int i = 0; i < 4; ++i)
#pragma unroll
    for (int nt = 0; nt < 4; ++nt) {
      const int col = wv * 64 + nt * 16 + m;
      const float bv = (col < CH) ? bias[col] : 0.f;
#pragma unroll
      for (int r = 0; r < 4; ++r) {
        const int row = nbase + i * 16 + quad * 4 + r;
        if (row < NN) {
          const float v = acc[i][nt][r] + bv;
          if (col < CH)
            PQi[((size_t)row * 64 + (col >> 1)) * 4 + sel * 2 + (col & 1)] =
                (_Float16)v;
          else {
            const int qc = col - CH;
            Qi[((size_t)row * 64 + (qc >> 1)) * 4 + sel * 2 + (qc & 1)] =
                (_Float16)v;
          }
        }
      }
    }
}

// ---------- fused dual-stream CSR conv ----------
// R2: packed-f16 edge math + 4-deep gather prefetch (110 -> <88 us).
__global__ __launch_bounds__(256) void k_conv2(
    const int* __restrict__ row_ptr, const int* __restrict__ ssrc,
    const _Float16* __restrict__ sea8,
    const _Float16* __restrict__ PQi, const _Float16* __restrict__ Qi,
    const float* __restrict__ Cn, const float* __restrict__ Cs,
    float* __restrict__ feats, float* __restrict__ sfeats,
    int cur, int prev) {
  const int t = threadIdx.x;
  const int lane = t & 63;
  const int node = blockIdx.x * 4 + (t >> 6);
  const int c = lane * 2;
  h2 cwnh[EA], cwsh[EA];
#pragma unroll
  for (int j = 0; j < EA; ++j) {
    const float2 a = *(const float2*)(Cn + j * CH + c);
    const float2 b = *(const float2*)(Cs + j * CH + c);
    cwnh[j] = (h2){(_Float16)a.x, (_Float16)a.y};
    cwsh[j] = (h2){(_Float16)b.x, (_Float16)b.y};
  }
  int i0 = __builtin_amdgcn_readfirstlane(row_ptr[node]);
  int i1 = __builtin_amdgcn_readfirstlane(row_ptr[node + 1]);
  const uint2 qv = *(const uint2*)(Qi + ((size_t)node * 64 + lane) * 4);
  const h2 qnh = *(const h2*)&qv.x;
  const h2 qsh = *(const h2*)&qv.y;
  const _Float16* pqL = PQi + (size_t)lane * 4;  // + s*256 per edge
  h2 anh = (h2){(_Float16)0.f, (_Float16)0.f};
  float as0 = 0.f, as1 = 0.f;
  const h2 zero = (h2){(_Float16)0.f, (_Float16)0.f};
#define COMP(PV, J)                                                        \
  {                                                                        \
    unsigned w0 = __shfl((int)ea_l.x, (J), 64);                            \
    unsigned w1 = __shfl((int)ea_l.y, (J), 64);                            \
    unsigned w2 = __shfl((int)ea_l.z, (J), 64);                            \
    const h2 ea01 = *(const h2*)&w0;                                       \
    const h2 ea23 = *(const h2*)&w1;                                       \
    const h2 ea45 = *(const h2*)&w2;                                       \
    h2 vn = *(const h2*)&PV.x + qnh;                                       \
    h2 vs = *(const h2*)&PV.y + qsh;                                       \
    h2 b;                                                                  \
    b = (h2){ea01[0], ea01[0]}; vn += b * cwnh[0]; vs += b * cwsh[0];      \
    b = (h2){ea01[1], ea01[1]}; vn += b * cwnh[1]; vs += b * cwsh[1];      \
    b = (h2){ea23[0], ea23[0]}; vn += b * cwnh[2]; vs += b * cwsh[2];      \
    b = (h2){ea23[1], ea23[1]}; vn += b * cwnh[3]; vs += b * cwsh[3];      \
    b = (h2){ea45[0], ea45[0]}; vn += b * cwnh[4]; vs += b * cwsh[4];      \
    b = (h2){ea45[1], ea45[1]}; vn += b * cwnh[5]; vs += b * cwsh[5];      \
    anh = __builtin_elementwise_max(anh, vn);                              \
    const h2 vsr = __builtin_elementwise_max(vs, zero);                    \
    as0 += (float)vsr[0]; as1 += (float)vsr[1];                            \
  }
  for (int base = i0; base < i1; base += 64) {
    const int cnt = min(64, i1 - base);
    int s_l = 0;
    uint4 ea_l = {0u, 0u, 0u, 0u};
    if (lane < cnt) {
      s_l = ssrc[base + lane];
      ea_l = *(const uint4*)(sea8 + (size_t)(base + lane) * 8);
    }
    int j = 0;
    for (; j + 4 <= cnt; j += 4) {
      // phase 1: broadcast src indices, issue 4 independent row gathers
      const int sa = __shfl(s_l, j, 64);
      const int sb = __shfl(s_l, j + 1, 64);
      const int sc = __shfl(s_l, j + 2, 64);
      const int sd = __shfl(s_l, j + 3, 64);
      const uint2 pva = *(const uint2*)(pqL + (size_t)sa * 256);
      const uint2 pvb = *(const uint2*)(pqL + (size_t)sb * 256);
      const uint2 pvc = *(const uint2*)(pqL + (size_t)sc * 256);
      const uint2 pvd = *(const uint2*)(pqL + (size_t)sd * 256);
      // phase 2: packed-f16 compute per edge
      COMP(pva, j) COMP(pvb, j + 1) COMP(pvc, j + 2) COMP(pvd, j + 3)
    }
    for (; j < cnt; ++j) {
      const int sa = __shfl(s_l, j, 64);
      const uint2 pva = *(const uint2*)(pqL + (size_t)sa * 256);
      COMP(pva, j)
    }
  }
#undef COMP
  float an0 = (float)anh[0], an1 = (float)anh[1];
  const float inv = 1.f / fmaxf((float)(i1 - i0), 1.f);
  as0 *= inv; as1 *= inv;
  const size_t o = (size_t)node * FUS + (size_t)cur * CH + c;
  if (prev >= 0) {
    const size_t op = (size_t)node * FUS + (size_t)prev * CH + c;
    const float2 prn = *(const float2*)(feats + op);
    const float2 prs = *(const float2*)(sfeats + op);
    an0 += prn.x; an1 += prn.y;
    as0 += prs.x; as1 += prs.y;
  }
  float2 on = {an0, an1}, os = {as0, as1};
  *(float2*)(feats + o) = on;
  *(float2*)(sfeats + o) = os;
}

// ---------- pack feats -> f16 A-fragments: [rb][ks][i][lane][8] ----------
__global__ __launch_bounds__(64) void k_cvtApack(const float* __restrict__ feats,
                                                 _Float16* __restrict__ ap) {
  const int rb = blockIdx.x / 12, ks = blockIdx.x % 12;
  const int L = threadIdx.x, m = L & 15, quad = L >> 4;
#pragma unroll
  for (int i = 0; i < 4; ++i) {
    const int row = rb * 64 + i * 16 + m;
    const int rowc = min(row, NN - 1);
    const float* src = feats + (size_t)rowc * FUS + ks * 32 + quad * 8;
    half8 v;
    if (row < NN) {
      const float4 f0 = *(const float4*)src;
      const float4 f1 = *(const float4*)(src + 4);
      v[0] = (_Float16)f0.x; v[1] = (_Float16)f0.y;
      v[2] = (_Float16)f0.z; v[3] = (_Float16)f0.w;
      v[4] = (_Float16)f1.x; v[5] = (_Float16)f1.y;
      v[6] = (_Float16)f1.z; v[7] = (_Float16)f1.w;
    } else {
#pragma unroll
      for (int j = 0; j < 8; ++j) v[j] = (_Float16)0.f;
    }
    *(half8*)(ap + (((size_t)(rb * 12 + ks) * 4 + i) * 64 + L) * 8) = v;
  }
}

// ---------- convert + pack W (KxN f32) into f16 B-fragment order ----------
template <int N, int NT>
__global__ __launch_bounds__(64) void k_cvtB(const float* __restrict__ W,
                                             _Float16* __restrict__ wh) {
  const int c = blockIdx.x / NT;
  const int tile = blockIdx.x % NT;
  const int L = threadIdx.x;
  const int n = tile * 16 + (L & 15);
  const int k0 = c * 32 + (L >> 4) * 8;
  half8 v;
#pragma unroll
  for (int j = 0; j < 8; ++j) v[j] = (_Float16)W[(size_t)(k0 + j) * N + n];
  *(half8*)(wh + (((size_t)(c * NT + tile)) * 64 + L) * 8) = v;
}

// ---------- fusion GEMM + segment max ----
// R0: cg fastest within XCD (FETCH 123->22MB). R1: two-phase epilogue.
// R4: each wave previously streamed the FULL 48KB A-tile from L2 (4x
// redundancy, 288KB L2-reads/block -> ~L2-BW-bound at ~60% of 34.5TB/s
// = the measured 85us; MfmaUtil stuck at 18% with ILP AND occupancy
// changes both neutral). Now: per-ks 4KB A-chunk staged to LDS once
// (wave wv reg-loads frag i==wv, ds_write, all waves ds_read), double-
// buffered with 2-deep global prefetch, one barrier per ks. A-dbuf (8KB)
// aliases the epilogue cl array -> LDS stays 17.4KB. L2 traffic halves.
__global__ __launch_bounds__(256, 6) void k_pool_mfma(
    const _Float16* __restrict__ aP, const _Float16* __restrict__ wh,
    const int* __restrict__ bbox, const float* __restrict__ bf,
    float* __restrict__ pooled) {
  __shared__ float cl[32 * 132];
  __shared__ int s_bb[64];
  _Float16* abuf = (_Float16*)cl;  // 2 x 2048 halves (8KB), K-loop life only
  const int t = threadIdx.x, lane = t & 63, wv = t >> 6;
  const int fid = blockIdx.x;
  const int xcd = fid & 7, slot = fid >> 3;
  const int cg = slot & 7;
  const int rb = xcd * 98 + (slot >> 3);
  const int nbase = rb * 64;
  const int m = lane & 15, quad = lane >> 4;
  if (t < 64) s_bb[t] = bbox[min(nbase + t, NN - 1)];
  f32x4 acc[4][2];
#pragma unroll
  for (int i = 0; i < 4; ++i)
#pragma unroll
    for (int nt = 0; nt < 2; ++nt) acc[i][nt] = (f32x4){0.f, 0.f, 0.f, 0.f};
  // wave wv stages fragment i==wv (512 halves) of each 2048-half chunk
  const _Float16* apc = aP + (size_t)rb * 12 * 2048 + (size_t)wv * 512 +
                        (size_t)lane * 8;
  const _Float16* bp = wh + ((size_t)(cg * 8 + wv * 2) * 64 + lane) * 8;
  _Float16* wslot = abuf + wv * 512 + lane * 8;
  const _Float16* rbase = abuf + lane * 8;
  half8 b0 = *(const half8*)(bp);
  half8 b1 = *(const half8*)(bp + 512);
  half8 rA = *(const half8*)(apc);             // chunk 0 quarter
  *(half8*)(wslot) = rA;                       // -> buf0
  half8 rN = *(const half8*)(apc + 2048);      // chunk 1 quarter
  __syncthreads();                             // buf0 ready (+ s_bb ordered)
#pragma unroll
  for (int ks = 0; ks < 12; ++ks) {
    const int cur = ks & 1;
    half8 nb0, nb1;
    if (ks < 11) {
      nb0 = *(const half8*)(bp + (size_t)(ks + 1) * 32768);
      nb1 = *(const half8*)(bp + (size_t)(ks + 1) * 32768 + 512);
    }
#pragma unroll
    for (int i = 0; i < 4; ++i) {
      const half8 a = *(const half8*)(rbase + cur * 2048 + i * 512);
      acc[i][0] = __builtin_amdgcn_mfma_f32_16x16x32_f16(a, b0, acc[i][0], 0, 0, 0);
      acc[i][1] = __builtin_amdgcn_mfma_f32_16x16x32_f16(a, b1, acc[i][1], 0, 0, 0);
    }
    if (ks < 11) {
      *(half8*)(wslot + (cur ^ 1) * 2048) = rN;   // stage chunk ks+1
      b0 = nb0; b1 = nb1;
    }
    if (ks < 10) rN = *(const half8*)(apc + (size_t)(ks + 2) * 2048);
    __syncthreads();   // buf[cur^1] ready; all reads of buf[cur] done
  }
  const int col = t & 127, rh = t >> 7;
  const int gcol = cg * 128 + col;
  const float bias = bf[gcol];
#pragma unroll
  for (int p = 0; p < 2; ++p) {
    __syncthreads();  // p=1: phase-0 readers done with cl
#pragma unroll
    for (int ii = 0; ii < 2; ++ii)
#pragma unroll
      for (int nt = 0; nt < 2; ++nt) {
        const int scol = wv * 32 + nt * 16 + m;
#pragma unroll
        for (int r = 0; r < 4; ++r)
          cl[(ii * 16 + quad * 4 + r) * 132 + scol] = acc[p * 2 + ii][nt][r];
      }
    __syncthreads();
    int curb = -1;
    float mx = 0.f;
    for (int rr = 0; rr < 16; ++rr) {
      const int rl = rh * 16 + rr;
      const int node = nbase + p * 32 + rl;
      if (node >= NN) break;
      const int bid = s_bb[p * 32 + rl];
      const float v = fmaxf(cl[rl * 132 + col] + bias, 0.f);
      if (bid != curb) {
        if (curb >= 0)
          atomicMax((unsigned*)(pooled + (size_t)curb * 1408 + gcol),
                    __float_as_uint(mx));
        curb = bid;
        mx = v;
      } else {
        mx = fmaxf(mx, v);
      }
    }
    if (curb >= 0)
      atomicMax((unsigned*)(pooled + (size_t)curb * 1408 + gcol),
                __float_as_uint(mx));
  }
}

// ---------- raw-feats bbox max + sfeats bbox mean ----------
__global__ __launch_bounds__(256) void k_poolraw(
    const float* __restrict__ feats, const float* __restrict__ sfeats,
    const int* __restrict__ seg, float* __restrict__ pooled,
    float* __restrict__ sb) {
  const int b = blockIdx.x, t = threadIdx.x;
  if (t >= 192) return;
  const int c2 = t * 2;
  const int n0 = __builtin_amdgcn_readfirstlane(seg[b]);
  const int n1 = __builtin_amdgcn_readfirstlane(seg[b + 1]);
  float2 fmx = {0.f, 0.f}, ss = {0.f, 0.f};
  for (int n = n0; n < n1; ++n) {
    const float2 f2 = *(const float2*)(feats + (size_t)n * FUS + c2);
    fmx.x = fmaxf(fmx.x, f2.x); fmx.y = fmaxf(fmx.y, f2.y);
    const float2 s2 = *(const float2*)(sfeats + (size_t)n * FUS + c2);
    ss.x += s2.x; ss.y += s2.y;
  }
  *(float2*)(pooled + (size_t)b * 1408 + 1024 + c2) = fmx;
  const float inv = 1.f / fmaxf((float)(n1 - n0), 1.f);
  float2 o = {ss.x * inv, ss.y * inv};
  *(float2*)(sb + (size_t)b * FUS + c2) = o;
}

// ---------- fusion_super = relu(sb @ Wfs + bfs), lane-distributed x ----------
__global__ __launch_bounds__(256) void k_fusion_super(
    const float* __restrict__ sb, const float* __restrict__ Wfs,
    const float* __restrict__ bfs, float* __restrict__ fs) {
  const int t = threadIdx.x, lane = t & 63, wv = t >> 6;
  const int r0 = blockIdx.x * 4;
  const int c = (blockIdx.y * 4 + wv) * 128 + lane * 2;
  float2 acc[4];
#pragma unroll
  for (int u = 0; u < 4; ++u) acc[u] = make_float2(0.f, 0.f);
  const int xr = r0 + (lane >> 4), xk = lane & 15;
  for (int k0 = 0; k0 < FUS; k0 += 16) {
    const float xv = sb[(size_t)xr * FUS + k0 + xk];
#pragma unroll
    for (int j = 0; j < 16; ++j) {
      const float2 w = *(const float2*)(Wfs + (size_t)(k0 + j) * 1024 + c);
#pragma unroll
      for (int u = 0; u < 4; ++u) {
        const float xs = __shfl(xv, u * 16 + j, 64);
        acc[u].x += xs * w.x; acc[u].y += xs * w.y;
      }
    }
  }
  const float2 b = *(const float2*)(bfs + c);
#pragma unroll
  for (int u = 0; u < 4; ++u) {
    float2 o = {fmaxf(acc[u].x + b.x, 0.f), fmaxf(acc[u].y + b.y, 0.f)};
    *(float2*)(fs + (size_t)(r0 + u) * 1024 + c) = o;
  }
}

// ---------- concat [pooled | fsup | sb] -> f16 bbH[NB_PAD][K1], zero-padded ----
__global__ __launch_bounds__(256) void k_cvt_cat(
    const float* __restrict__ pooled, const float* __restrict__ fsup,
    const float* __restrict__ sb, _Float16* __restrict__ bbH) {
  const size_t off = ((size_t)blockIdx.x * 256 + threadIdx.x) * 8;
  const int row = (int)(off / K1);
  const int col = (int)(off - (size_t)row * K1);
  half8 v;
  if (row < NB) {
    const float* src;
    if (col < 1408)      src = pooled + (size_t)row * 1408 + col;
    else if (col < 2432) src = fsup + (size_t)row * 1024 + (col - 1408);
    else                 src = sb + (size_t)row * FUS + (col - 2432);
    const float4 f0 = *(const float4*)src;
    const float4 f1 = *(const float4*)(src + 4);
    v[0] = (_Float16)f0.x; v[1] = (_Float16)f0.y;
    v[2] = (_Float16)f0.z; v[3] = (_Float16)f0.w;
    v[4] = (_Float16)f1.x; v[5] = (_Float16)f1.y;
    v[6] = (_Float16)f1.z; v[7] = (_Float16)f1.w;
  } else {
#pragma unroll
    for (int j = 0; j < 8; ++j) v[j] = (_Float16)0.f;
  }
  *(half8*)(bbH + off) = v;
}

// ---------- h1 = relu(bbH @ W1 + b1) on matrix cores ----------
__global__ __launch_bounds__(256) void k_mlp1_mfma(
    const _Float16* __restrict__ bbH, const _Float16* __restrict__ wh,
    const float* __restrict__ b1, float* __restrict__ h1) {
  const int t = threadIdx.x, lane = t & 63, wv = t >> 6;
  const int nbase = blockIdx.x * 64;
  const int cg = blockIdx.y;
  const int m = lane & 15, quad = lane >> 4;
  f32x4 acc[4][2];
#pragma unroll
  for (int i = 0; i < 4; ++i)
#pragma unroll
    for (int nt = 0; nt < 2; ++nt) acc[i][nt] = (f32x4){0.f, 0.f, 0.f, 0.f};
  const _Float16* ap = bbH + (size_t)(nbase + m) * K1 + quad * 8;
  const _Float16* bp = wh + ((size_t)(cg * 8 + wv * 2) * 64 + lane) * 8;
#pragma unroll 4
  for (int ks = 0; ks < 88; ++ks) {
    const half8 b0 = *(const half8*)(bp + (size_t)ks * 16384);
    const half8 b1v = *(const half8*)(bp + (size_t)ks * 16384 + 512);
#pragma unroll
    for (int i = 0; i < 4; ++i) {
      const half8 a = *(const half8*)(ap + (size_t)(i * 16) * K1 + ks * 32);
      acc[i][0] = __builtin_amdgcn_mfma_f32_16x16x32_f16(a, b0, acc[i][0], 0, 0, 0);
      acc[i][1] = __builtin_amdgcn_mfma_f32_16x16x32_f16(a, b1v, acc[i][1], 0, 0, 0);
    }
  }
#pragma unroll
  for (int i = 0; i < 4; ++i)
#pragma unroll
    for (int nt = 0; nt < 2; ++nt) {
      const int gcol = cg * 128 + wv * 32 + nt * 16 + m;
      const float bias = b1[gcol];
#pragma unroll
      for (int r = 0; r < 4; ++r) {
        const int row = nbase + i * 16 + quad * 4 + r;
        if (row < NB)
          h1[(size_t)row * 512 + gcol] = fmaxf(acc[i][nt][r] + bias, 0.f);
      }
    }
}

// ---------- h2 = relu(h1 @ W2 + b2) ----------
__global__ __launch_bounds__(256) void k_mlp2(
    const float* __restrict__ h1, const float* __restrict__ W2,
    const float* __restrict__ b2, float* __restrict__ h2o) {
  const int r0 = blockIdx.x * 8, t = threadIdx.x;
  float acc[8];
#pragma unroll
  for (int u = 0; u < 8; ++u) acc[u] = 0.f;
  for (int k = 0; k < 512; ++k) {
    float w = W2[(size_t)k * 256 + t];
#pragma unroll
    for (int u = 0; u < 8; ++u) acc[u] += h1[(size_t)(r0 + u) * 512 + k] * w;
  }
  float bv = b2[t];
#pragma unroll
  for (int u = 0; u < 8; ++u)
    h2o[(size_t)(r0 + u) * 256 + t] = fmaxf(acc[u] + bv, 0.f);
}

// ---------- logits = h2 @ W3 + b3 ----------
__global__ __launch_bounds__(256) void k_mlp3(
    const float* __restrict__ h2i, const float* __restrict__ W3,
    const float* __restrict__ b3, float* __restrict__ out) {
  const int r0 = blockIdx.x * 8, t = threadIdx.x;
  const int u = t >> 5, oc = t & 31;
  const float* x = h2i + (size_t)(r0 + u) * 256;
  float acc = 0.f;
  for (int k = 0; k < 256; ++k) acc += x[k] * W3[(size_t)k * 32 + oc];
  out[(size_t)(r0 + u) * 32 + oc] = acc + b3[oc];
}

extern "C" void kernel_launch(void* const* d_in, const int* in_sizes, int n_in,
                              void* d_out, int out_size, void* d_ws, size_t ws_size,
                              hipStream_t stream) {
  const float* x     = (const float*)d_in[0];
  const float* eattr = (const float*)d_in[1];
  const float* W_h   = (const float*)d_in[2];
  const float* b_h   = (const float*)d_in[3];
  const float* Ws_h  = (const float*)d_in[4];
  const float* bs_h  = (const float*)d_in[5];
  const float* Wb    = (const float*)d_in[6];
  const float* bb    = (const float*)d_in[7];
  const float* Wbs   = (const float*)d_in[8];
  const float* bbs   = (const float*)d_in[9];
  const float* W_f   = (const float*)d_in[10];
  const float* b_f   = (const float*)d_in[11];
  const float* W_fs  = (const float*)d_in[12];
  const float* b_fs  = (const float*)d_in[13];
  const float* W1    = (const float*)d_in[14];
  const float* b1    = (const float*)d_in[15];
  const float* W2    = (const float*)d_in[16];
  const float* b2    = (const float*)d_in[17];
  const float* W3    = (const float*)d_in[18];
  const float* b3    = (const float*)d_in[19];
  const int*   edge  = (const int*)d_in[20];
  const int*   bbox  = (const int*)d_in[21];
  float* out = (float*)d_out;

  // ---- workspace layout (~221.6 MB; known-good budget >= 233 MB) ----
  float* p = (float*)d_ws;
  float* feats  = p; p += (size_t)NN * FUS;
  float* sfeats = p; p += (size_t)NN * FUS;
  float* PQ     = p; p += (size_t)2 * NN * CH;    // 12.8M floats
  _Float16* PQi = (_Float16*)PQ;
  _Float16* Qi  = PQi + (size_t)NN * 256;
  // overlays inside PQ (live only AFTER the last k_conv2):
  _Float16* aPack = (_Float16*)PQ;
  _Float16* WfH   = aPack + (size_t)784 * 12 * 2048;
  float* pooled   = (float*)(WfH + (size_t)FUS * 1024);
  float* sb   = PQ;
  float* fsup = sb + (size_t)NB * FUS;
  float* h1   = fsup + (size_t)NB * 1024;
  float* h2b  = h1 + (size_t)NB * 512;
  _Float16* bbH = (_Float16*)(h2b + (size_t)NB * 256);
  _Float16* W1H = bbH + (size_t)NB_PAD * K1;
  // CSR payload + misc after PQ region:
  _Float16* sea8 = (_Float16*)p;
  int* ssrc    = (int*)(sea8 + (size_t)NE * 8);
  int* row_ptr = ssrc + NE;
  int* deg     = row_ptr + NN + 1;
  int* cursor  = deg + NN;
  int* seg     = cursor + NN;
  _Float16* WcatN = (_Float16*)(seg + NB + 1);      // 2 blocks x 128x256
  _Float16* WcatS = WcatN + (size_t)2 * 128 * 256;
  int* bsum = (int*)(WcatS + (size_t)2 * 128 * 256);

  hipMemsetAsync(deg, 0, 2 * NN * sizeof(int), stream);  // deg + cursor

  // ---- CSR build (dst-sorted payload, parallel scan) + bbox segments ----
  k_deg<<<(NE + 255) / 256, 256, 0, stream>>>(edge, deg);
  k_scan1<<<SCAN_NBLK, 1024, 0, stream>>>(deg, row_ptr, bsum);
  k_scan2<<<1, 64, 0, stream>>>(bsum);
  k_scan3<<<(NN + 255) / 256, 256, 0, stream>>>(bsum, row_ptr);
  k_fill<<<(NE + 255) / 256, 256, 0, stream>>>(edge, eattr, row_ptr, cursor,
                                               ssrc, sea8);
  k_segstart<<<(NN + 255) / 256, 256, 0, stream>>>(bbox, seg);

  const int npq_grid = (NN + 31) / 32;

  // ---- conv 0 (head): both streams in one launch (blockIdx.y = sel) ----
  k_node_pq<<<dim3(npq_grid, 2), 256, 0, stream>>>(x, INCH, INCH, W_h, b_h,
                                                   Ws_h, bs_h, PQi, Qi);
  k_conv2<<<NN / 4, 256, 0, stream>>>(row_ptr, ssrc, sea8, PQi, Qi,
                                      W_h + 2 * INCH * CH, Ws_h + 2 * INCH * CH,
                                      feats, sfeats, 0, -1);

  // ---- residual blocks (K=128): weight prep hoisted, both blocks ----
  k_cvtWnpq<<<dim3(64, 2, 2), 64, 0, stream>>>(Wb, Wbs, WcatN, WcatS);
  for (int i = 0; i < 2; ++i) {
    const float* Wi  = Wb  + (size_t)i * 262 * CH;
    const float* bi  = bb  + (size_t)i * CH;
    const float* Wsi = Wbs + (size_t)i * 262 * CH;
    const float* bsi = bbs + (size_t)i * CH;
    k_npq_mfma<<<dim3((NN + 63) / 64, 2), 256, 0, stream>>>(
        feats + i * CH, sfeats + i * CH, FUS, WcatN + (size_t)i * 32768,
        WcatS + (size_t)i * 32768, bi, bsi, PQi, Qi);
    k_conv2<<<NN / 4, 256, 0, stream>>>(row_ptr, ssrc, sea8, PQi, Qi,
                                        Wi + 2 * CH * CH, Wsi + 2 * CH * CH,
                                        feats, sfeats, i + 1, i);
  }

  // ---- pooling: packed-A f16 convert + MFMA GEMM + atomicMax ----
  k_cvtApack<<<784 * 12, 64, 0, stream>>>(feats, aPack);
  k_cvtB<1024, 64><<<12 * 64, 64, 0, stream>>>(W_f, WfH);
  hipMemsetAsync(pooled, 0, (size_t)NB * 1408 * sizeof(float), stream);
  k_pool_mfma<<<784 * 8, 256, 0, stream>>>(aPack, WfH, bbox, b_f, pooled);
  k_poolraw<<<NB, 256, 0, stream>>>(feats, sfeats, seg, pooled, sb);
  k_fusion_super<<<dim3(NB / 4, 2), 256, 0, stream>>>(sb, W_fs, b_fs, fsup);

  // ---- head MLP: concat->f16, W1->f16 frag, MFMA GEMM, then small MLPs ----
  k_cvt_cat<<<(int)(((size_t)NB_PAD * K1 / 8) / 256), 256, 0, stream>>>(
      pooled, fsup, sb, bbH);
  k_cvtB<512, 32><<<88 * 32, 64, 0, stream>>>(W1, W1H);
  k_mlp1_mfma<<<dim3(NB_PAD / 64, 4), 256, 0, stream>>>(bbH, W1H, b1, h1);
  k_mlp2<<<NB / 8, 256, 0, stream>>>(h1, W2, b2, h2b);
  k_mlp3<<<NB / 8, 256, 0, stream>>>(h2b, W3, b3, out);
}

// Round 7
// 845.015 us; speedup vs baseline: 1.2841x; 1.0669x over previous
//
#include <hip/hip_runtime.h>
#include <stdint.h>

#define NN      50000
#define NE      800000
#define INCH    8
#define CH      128
#define EA      6
#define NB      2000
#define NB_PAD  2048
#define NCLS    32
#define FUS     384
#define K1      2816   // 1408 + 1024 + 384
#define SCAN_NBLK 49   // (NN + 1023) / 1024

typedef _Float16 half8 __attribute__((ext_vector_type(8)));
typedef _Float16 h2 __attribute__((ext_vector_type(2)));
typedef float f32x4 __attribute__((ext_vector_type(4)));

// ---------- degree of dst nodes ----------
__global__ __launch_bounds__(256) void k_deg(const int* __restrict__ edge,
                                             int* __restrict__ deg) {
  int e = blockIdx.x * 256 + threadIdx.x;
  if (e < NE) atomicAdd(&deg[edge[NE + e]], 1);
}

// ---------- parallel scan, phase 1: per-block inclusive scan + block sums ----
__global__ __launch_bounds__(1024) void k_scan1(const int* __restrict__ deg,
                                                int* __restrict__ row_ptr,
                                                int* __restrict__ bsum) {
  __shared__ int wsum[16];
  const int t = threadIdx.x, lane = t & 63, w = t >> 6;
  const int i = blockIdx.x * 1024 + t;
  int x = (i < NN) ? deg[i] : 0;
#pragma unroll
  for (int off = 1; off < 64; off <<= 1) {
    int y = __shfl_up(x, off, 64);
    if (lane >= off) x += y;
  }
  if (lane == 63) wsum[w] = x;
  __syncthreads();
  if (w == 0 && lane < 16) {
    int s = wsum[lane];
#pragma unroll
    for (int off = 1; off < 16; off <<= 1) {
      int y = __shfl_up(s, off, 64);
      if (lane >= off) s += y;
    }
    wsum[lane] = s;
  }
  __syncthreads();
  int incl = x + ((w == 0) ? 0 : wsum[w - 1]);
  if (i < NN) row_ptr[i + 1] = incl;
  if (t == 1023) bsum[blockIdx.x] = incl;
}

// ---------- phase 2: single-wave exclusive scan of block sums ----------
__global__ __launch_bounds__(64) void k_scan2(int* __restrict__ bsum) {
  const int t = threadIdx.x;
  int x = (t < SCAN_NBLK) ? bsum[t] : 0;
#pragma unroll
  for (int off = 1; off < 64; off <<= 1) {
    int y = __shfl_up(x, off, 64);
    if (t >= off) x += y;
  }
  int ex = __shfl_up(x, 1, 64);
  if (t == 0) ex = 0;
  if (t < SCAN_NBLK) bsum[t] = ex;
}

// ---------- phase 3: add block offsets ----------
__global__ __launch_bounds__(256) void k_scan3(const int* __restrict__ bsum,
                                               int* __restrict__ row_ptr) {
  const int i = blockIdx.x * 256 + threadIdx.x;
  if (i == 0) row_ptr[0] = 0;
  if (i < NN) row_ptr[i + 1] += bsum[i >> 10];
}

// ---------- fill CSR payload: dst-sorted src + f16 e_attr ----------
__global__ __launch_bounds__(256) void k_fill(
    const int* __restrict__ edge, const float* __restrict__ eattr,
    const int* __restrict__ row_ptr, int* __restrict__ cursor,
    int* __restrict__ ssrc, _Float16* __restrict__ sea8) {
  int e = blockIdx.x * 256 + threadIdx.x;
  if (e >= NE) return;
  int s = edge[e], d = edge[NE + e];
  int idx = row_ptr[d] + atomicAdd(&cursor[d], 1);
  ssrc[idx] = s;
  half8 v;
#pragma unroll
  for (int j = 0; j < EA; ++j) v[j] = (_Float16)eattr[(size_t)e * EA + j];
  v[6] = (_Float16)0.f; v[7] = (_Float16)0.f;
  *(half8*)(sea8 + (size_t)idx * 8) = v;
}

// ---------- segment starts from sorted bbox_idx ----------
__global__ __launch_bounds__(256) void k_segstart(const int* __restrict__ bbox,
                                                  int* __restrict__ seg) {
  int i = blockIdx.x * 256 + threadIdx.x;
  if (i >= NN) return;
  int bc = bbox[i];
  int bp = (i == 0) ? -1 : bbox[i - 1];
  for (int j = bp + 1; j <= bc; ++j) seg[j] = i;
  if (i == NN - 1)
    for (int j = bc + 1; j <= NB; ++j) seg[j] = NN;
}

// ---------- head node transform (K=8), both streams via blockIdx.y ----------
__global__ __launch_bounds__(256) void k_node_pq(
    const float* __restrict__ X, int ldx, int K,
    const float* __restrict__ WN, const float* __restrict__ bN,
    const float* __restrict__ WS, const float* __restrict__ bS,
    _Float16* __restrict__ PQi, _Float16* __restrict__ Qi) {
  const int sel = blockIdx.y;
  const float* W = sel ? WS : WN;
  const float* bias = sel ? bS : bN;
  const int t = threadIdx.x, lane = t & 63, wv = t >> 6;
  const int nbase = blockIdx.x * 32 + wv * 8;
  const int c = lane * 2;
  const float2 bv = *(const float2*)(bias + c);
  float2 pacc[8], qacc[8];
#pragma unroll
  for (int u = 0; u < 8; ++u) { pacc[u] = bv; qacc[u] = make_float2(0.f, 0.f); }
  const int xrow = min(nbase + (lane >> 3), NN - 1);
  const int xk = lane & 7;
  for (int k0 = 0; k0 < K; k0 += 8) {
    const float xv = X[(size_t)xrow * ldx + k0 + xk];
#pragma unroll
    for (int j = 0; j < 8; ++j) {
      const float2 w1 = *(const float2*)(W + (size_t)(k0 + j) * CH + c);
      const float2 w2 = *(const float2*)(W + (size_t)(K + k0 + j) * CH + c);
      const float2 wd = {w1.x - w2.x, w1.y - w2.y};
#pragma unroll
      for (int u = 0; u < 8; ++u) {
        const float xs = __shfl(xv, u * 8 + j, 64);
        pacc[u].x += xs * wd.x; pacc[u].y += xs * wd.y;
        qacc[u].x += xs * w2.x; qacc[u].y += xs * w2.y;
      }
    }
  }
#pragma unroll
  for (int u = 0; u < 8; ++u) {
    const int node = nbase + u;
    if (node < NN) {
      const size_t o = ((size_t)node * 64 + lane) * 4 + sel * 2;
      *(h2*)(PQi + o) = (h2){(_Float16)pacc[u].x, (_Float16)pacc[u].y};
      *(h2*)(Qi + o)  = (h2){(_Float16)qacc[u].x, (_Float16)qacc[u].y};
    }
  }
}

// ---------- pack [W1-W2 | W2] into f16 B-frags, both res-blocks (z) ----------
__global__ __launch_bounds__(64) void k_cvtWnpq(
    const float* __restrict__ WbAll, const float* __restrict__ WbsAll,
    _Float16* __restrict__ whN, _Float16* __restrict__ whS) {
  const int blk = blockIdx.z;
  const float* W = (blockIdx.y ? WbsAll : WbAll) + (size_t)blk * 262 * CH;
  _Float16* wh   = (blockIdx.y ? whS : whN) + (size_t)blk * 32768;
  const int c = blockIdx.x >> 4, tile = blockIdx.x & 15;
  const int L = threadIdx.x;
  const int n = tile * 16 + (L & 15);
  const int k0 = c * 32 + (L >> 4) * 8;
  half8 v;
#pragma unroll
  for (int j = 0; j < 8; ++j) {
    const int k = k0 + j;
    float val;
    if (n < CH) val = W[(size_t)k * CH + n] - W[(size_t)(CH + k) * CH + n];
    else        val = W[(size_t)(CH + k) * CH + (n - CH)];
    v[j] = (_Float16)val;
  }
  *(half8*)(wh + (((size_t)(c * 16 + tile)) * 64 + L) * 8) = v;
}

// ---------- residual node transform on matrix cores (both streams) ----------
__global__ __launch_bounds__(256) void k_npq_mfma(
    const float* __restrict__ Xn, const float* __restrict__ Xs, int ldx,
    const _Float16* __restrict__ whN, const _Float16* __restrict__ whS,
    const float* __restrict__ biasN, const float* __restrict__ biasS,
    _Float16* __restrict__ PQi, _Float16* __restrict__ Qi) {
  const int sel = blockIdx.y;
  const float* X = sel ? Xs : Xn;
  const _Float16* wh = sel ? whS : whN;
  const float* bias = sel ? biasS : biasN;
  const int t = threadIdx.x, lane = t & 63, wv = t >> 6;
  const int nbase = blockIdx.x * 64;
  const int m = lane & 15, quad = lane >> 4;
  f32x4 acc[4][4];
#pragma unroll
  for (int i = 0; i < 4; ++i)
#pragma unroll
    for (int nt = 0; nt < 4; ++nt) acc[i][nt] = (f32x4){0.f, 0.f, 0.f, 0.f};
#pragma unroll
  for (int ks = 0; ks < 4; ++ks) {
    half8 b[4];
#pragma unroll
    for (int nt = 0; nt < 4; ++nt)
      b[nt] = *(const half8*)(wh + (((size_t)(ks * 16 + wv * 4 + nt)) * 64 + lane) * 8);
#pragma unroll
    for (int i = 0; i < 4; ++i) {
      const int row = min(nbase + i * 16 + m, NN - 1);
      const float* src = X + (size_t)row * ldx + ks * 32 + quad * 8;
      const float4 f0 = *(const float4*)src;
      const float4 f1 = *(const float4*)(src + 4);
      half8 a;
      a[0] = (_Float16)f0.x; a[1] = (_Float16)f0.y;
      a[2] = (_Float16)f0.z; a[3] = (_Float16)f0.w;
      a[4] = (_Float16)f1.x; a[5] = (_Float16)f1.y;
      a[6] = (_Float16)f1.z; a[7] = (_Float16)f1.w;
#pragma unroll
      for (int nt = 0; nt < 4; ++nt)
        acc[i][nt] = __builtin_amdgcn_mfma_f32_16x16x32_f16(a, b[nt], acc[i][nt],
                                                            0, 0, 0);
    }
  }
#pragma unroll
  for (int i = 0; i < 4; ++i)
#pragma unroll
    for (int nt = 0; nt < 4; ++nt) {
      const int col = wv * 64 + nt * 16 + m;
      const float bv = (col < CH) ? bias[col] : 0.f;
#pragma unroll
      for (int r = 0; r < 4; ++r) {
        const int row = nbase + i * 16 + quad * 4 + r;
        if (row < NN) {
          const float v = acc[i][nt][r] + bv;
          if (col < CH)
            PQi[((size_t)row * 64 + (col >> 1)) * 4 + sel * 2 + (col & 1)] =
                (_Float16)v;
          else {
            const int qc = col - CH;
            Qi[((size_t)row * 64 + (qc >> 1)) * 4 + sel * 2 + (qc & 1)] =
                (_Float16)v;
          }
        }
      }
    }
}

// ---------- fused dual-stream CSR conv ----------
// R2: packed-f16 edge math + 4-deep gather prefetch (110 -> <88 us).
__global__ __launch_bounds__(256) void k_conv2(
    const int* __restrict__ row_ptr, const int* __restrict__ ssrc,
    const _Float16* __restrict__ sea8,
    const _Float16* __restrict__ PQi, const _Float16* __restrict__ Qi,
    const float* __restrict__ Cn, const float* __restrict__ Cs,
    float* __restrict__ feats, float* __restrict__ sfeats,
    int cur, int prev) {
  const int t = threadIdx.x;
  const int lane = t & 63;
  const int node = blockIdx.x * 4 + (t >> 6);
  const int c = lane * 2;
  h2 cwnh[EA], cwsh[EA];
#pragma unroll
  for (int j = 0; j < EA; ++j) {
    const float2 a = *(const float2*)(Cn + j * CH + c);
    const float2 b = *(const float2*)(Cs + j * CH + c);
    cwnh[j] = (h2){(_Float16)a.x, (_Float16)a.y};
    cwsh[j] = (h2){(_Float16)b.x, (_Float16)b.y};
  }
  int i0 = __builtin_amdgcn_readfirstlane(row_ptr[node]);
  int i1 = __builtin_amdgcn_readfirstlane(row_ptr[node + 1]);
  const uint2 qv = *(const uint2*)(Qi + ((size_t)node * 64 + lane) * 4);
  const h2 qnh = *(const h2*)&qv.x;
  const h2 qsh = *(const h2*)&qv.y;
  const _Float16* pqL = PQi + (size_t)lane * 4;  // + s*256 per edge
  h2 anh = (h2){(_Float16)0.f, (_Float16)0.f};
  float as0 = 0.f, as1 = 0.f;
  const h2 zero = (h2){(_Float16)0.f, (_Float16)0.f};
#define COMP(PV, J)                                                        \
  {                                                                        \
    unsigned w0 = __shfl((int)ea_l.x, (J), 64);                            \
    unsigned w1 = __shfl((int)ea_l.y, (J), 64);                            \
    unsigned w2 = __shfl((int)ea_l.z, (J), 64);                            \
    const h2 ea01 = *(const h2*)&w0;                                       \
    const h2 ea23 = *(const h2*)&w1;                                       \
    const h2 ea45 = *(const h2*)&w2;                                       \
    h2 vn = *(const h2*)&PV.x + qnh;                                       \
    h2 vs = *(const h2*)&PV.y + qsh;                                       \
    h2 b;                                                                  \
    b = (h2){ea01[0], ea01[0]}; vn += b * cwnh[0]; vs += b * cwsh[0];      \
    b = (h2){ea01[1], ea01[1]}; vn += b * cwnh[1]; vs += b * cwsh[1];      \
    b = (h2){ea23[0], ea23[0]}; vn += b * cwnh[2]; vs += b * cwsh[2];      \
    b = (h2){ea23[1], ea23[1]}; vn += b * cwnh[3]; vs += b * cwsh[3];      \
    b = (h2){ea45[0], ea45[0]}; vn += b * cwnh[4]; vs += b * cwsh[4];      \
    b = (h2){ea45[1], ea45[1]}; vn += b * cwnh[5]; vs += b * cwsh[5];      \
    anh = __builtin_elementwise_max(anh, vn);                              \
    const h2 vsr = __builtin_elementwise_max(vs, zero);                    \
    as0 += (float)vsr[0]; as1 += (float)vsr[1];                            \
  }
  for (int base = i0; base < i1; base += 64) {
    const int cnt = min(64, i1 - base);
    int s_l = 0;
    uint4 ea_l = {0u, 0u, 0u, 0u};
    if (lane < cnt) {
      s_l = ssrc[base + lane];
      ea_l = *(const uint4*)(sea8 + (size_t)(base + lane) * 8);
    }
    int j = 0;
    for (; j + 4 <= cnt; j += 4) {
      // phase 1: broadcast src indices, issue 4 independent row gathers
      const int sa = __shfl(s_l, j, 64);
      const int sb = __shfl(s_l, j + 1, 64);
      const int sc = __shfl(s_l, j + 2, 64);
      const int sd = __shfl(s_l, j + 3, 64);
      const uint2 pva = *(const uint2*)(pqL + (size_t)sa * 256);
      const uint2 pvb = *(const uint2*)(pqL + (size_t)sb * 256);
      const uint2 pvc = *(const uint2*)(pqL + (size_t)sc * 256);
      const uint2 pvd = *(const uint2*)(pqL + (size_t)sd * 256);
      // phase 2: packed-f16 compute per edge
      COMP(pva, j) COMP(pvb, j + 1) COMP(pvc, j + 2) COMP(pvd, j + 3)
    }
    for (; j < cnt; ++j) {
      const int sa = __shfl(s_l, j, 64);
      const uint2 pva = *(const uint2*)(pqL + (size_t)sa * 256);
      COMP(pva, j)
    }
  }
#undef COMP
  float an0 = (float)anh[0], an1 = (float)anh[1];
  const float inv = 1.f / fmaxf((float)(i1 - i0), 1.f);
  as0 *= inv; as1 *= inv;
  const size_t o = (size_t)node * FUS + (size_t)cur * CH + c;
  if (prev >= 0) {
    const size_t op = (size_t)node * FUS + (size_t)prev * CH + c;
    const float2 prn = *(const float2*)(feats + op);
    const float2 prs = *(const float2*)(sfeats + op);
    an0 += prn.x; an1 += prn.y;
    as0 += prs.x; as1 += prs.y;
  }
  float2 on = {an0, an1}, os = {as0, as1};
  *(float2*)(feats + o) = on;
  *(float2*)(sfeats + o) = os;
}

// ---------- pack feats -> f16 A-fragments: [rb][ks][i][lane][8] ----------
__global__ __launch_bounds__(64) void k_cvtApack(const float* __restrict__ feats,
                                                 _Float16* __restrict__ ap) {
  const int rb = blockIdx.x / 12, ks = blockIdx.x % 12;
  const int L = threadIdx.x, m = L & 15, quad = L >> 4;
#pragma unroll
  for (int i = 0; i < 4; ++i) {
    const int row = rb * 64 + i * 16 + m;
    const int rowc = min(row, NN - 1);
    const float* src = feats + (size_t)rowc * FUS + ks * 32 + quad * 8;
    half8 v;
    if (row < NN) {
      const float4 f0 = *(const float4*)src;
      const float4 f1 = *(const float4*)(src + 4);
      v[0] = (_Float16)f0.x; v[1] = (_Float16)f0.y;
      v[2] = (_Float16)f0.z; v[3] = (_Float16)f0.w;
      v[4] = (_Float16)f1.x; v[5] = (_Float16)f1.y;
      v[6] = (_Float16)f1.z; v[7] = (_Float16)f1.w;
    } else {
#pragma unroll
      for (int j = 0; j < 8; ++j) v[j] = (_Float16)0.f;
    }
    *(half8*)(ap + (((size_t)(rb * 12 + ks) * 4 + i) * 64 + L) * 8) = v;
  }
}

// ---------- convert + pack W (KxN f32) into f16 B-fragment order ----------
template <int N, int NT>
__global__ __launch_bounds__(64) void k_cvtB(const float* __restrict__ W,
                                             _Float16* __restrict__ wh) {
  const int c = blockIdx.x / NT;
  const int tile = blockIdx.x % NT;
  const int L = threadIdx.x;
  const int n = tile * 16 + (L & 15);
  const int k0 = c * 32 + (L >> 4) * 8;
  half8 v;
#pragma unroll
  for (int j = 0; j < 8; ++j) v[j] = (_Float16)W[(size_t)(k0 + j) * N + n];
  *(half8*)(wh + (((size_t)(c * NT + tile)) * 64 + L) * 8) = v;
}

// ---------- fusion GEMM + segment max ----
// R0: cg fastest within XCD (FETCH 123->22MB). R1: two-phase epilogue.
// R4: LDS-staged A (halves L2 traffic), dbuf + 2-deep prefetch -> <83us.
__global__ __launch_bounds__(256, 6) void k_pool_mfma(
    const _Float16* __restrict__ aP, const _Float16* __restrict__ wh,
    const int* __restrict__ bbox, const float* __restrict__ bf,
    float* __restrict__ pooled) {
  __shared__ float cl[32 * 132];
  __shared__ int s_bb[64];
  _Float16* abuf = (_Float16*)cl;  // 2 x 2048 halves (8KB), K-loop life only
  const int t = threadIdx.x, lane = t & 63, wv = t >> 6;
  const int fid = blockIdx.x;
  const int xcd = fid & 7, slot = fid >> 3;
  const int cg = slot & 7;
  const int rb = xcd * 98 + (slot >> 3);
  const int nbase = rb * 64;
  const int m = lane & 15, quad = lane >> 4;
  if (t < 64) s_bb[t] = bbox[min(nbase + t, NN - 1)];
  f32x4 acc[4][2];
#pragma unroll
  for (int i = 0; i < 4; ++i)
#pragma unroll
    for (int nt = 0; nt < 2; ++nt) acc[i][nt] = (f32x4){0.f, 0.f, 0.f, 0.f};
  // wave wv stages fragment i==wv (512 halves) of each 2048-half chunk
  const _Float16* apc = aP + (size_t)rb * 12 * 2048 + (size_t)wv * 512 +
                        (size_t)lane * 8;
  const _Float16* bp = wh + ((size_t)(cg * 8 + wv * 2) * 64 + lane) * 8;
  _Float16* wslot = abuf + wv * 512 + lane * 8;
  const _Float16* rbase = abuf + lane * 8;
  half8 b0 = *(const half8*)(bp);
  half8 b1 = *(const half8*)(bp + 512);
  half8 rA = *(const half8*)(apc);             // chunk 0 quarter
  *(half8*)(wslot) = rA;                       // -> buf0
  half8 rN = *(const half8*)(apc + 2048);      // chunk 1 quarter
  __syncthreads();                             // buf0 ready (+ s_bb ordered)
#pragma unroll
  for (int ks = 0; ks < 12; ++ks) {
    const int cur = ks & 1;
    half8 nb0, nb1;
    if (ks < 11) {
      nb0 = *(const half8*)(bp + (size_t)(ks + 1) * 32768);
      nb1 = *(const half8*)(bp + (size_t)(ks + 1) * 32768 + 512);
    }
#pragma unroll
    for (int i = 0; i < 4; ++i) {
      const half8 a = *(const half8*)(rbase + cur * 2048 + i * 512);
      acc[i][0] = __builtin_amdgcn_mfma_f32_16x16x32_f16(a, b0, acc[i][0], 0, 0, 0);
      acc[i][1] = __builtin_amdgcn_mfma_f32_16x16x32_f16(a, b1, acc[i][1], 0, 0, 0);
    }
    if (ks < 11) {
      *(half8*)(wslot + (cur ^ 1) * 2048) = rN;   // stage chunk ks+1
      b0 = nb0; b1 = nb1;
    }
    if (ks < 10) rN = *(const half8*)(apc + (size_t)(ks + 2) * 2048);
    __syncthreads();   // buf[cur^1] ready; all reads of buf[cur] done
  }
  const int col = t & 127, rh = t >> 7;
  const int gcol = cg * 128 + col;
  const float bias = bf[gcol];
#pragma unroll
  for (int p = 0; p < 2; ++p) {
    __syncthreads();  // p=1: phase-0 readers done with cl
#pragma unroll
    for (int ii = 0; ii < 2; ++ii)
#pragma unroll
      for (int nt = 0; nt < 2; ++nt) {
        const int scol = wv * 32 + nt * 16 + m;
#pragma unroll
        for (int r = 0; r < 4; ++r)
          cl[(ii * 16 + quad * 4 + r) * 132 + scol] = acc[p * 2 + ii][nt][r];
      }
    __syncthreads();
    int curb = -1;
    float mx = 0.f;
    for (int rr = 0; rr < 16; ++rr) {
      const int rl = rh * 16 + rr;
      const int node = nbase + p * 32 + rl;
      if (node >= NN) break;
      const int bid = s_bb[p * 32 + rl];
      const float v = fmaxf(cl[rl * 132 + col] + bias, 0.f);
      if (bid != curb) {
        if (curb >= 0)
          atomicMax((unsigned*)(pooled + (size_t)curb * 1408 + gcol),
                    __float_as_uint(mx));
        curb = bid;
        mx = v;
      } else {
        mx = fmaxf(mx, v);
      }
    }
    if (curb >= 0)
      atomicMax((unsigned*)(pooled + (size_t)curb * 1408 + gcol),
                __float_as_uint(mx));
  }
}

// ---------- raw-feats bbox max + sfeats bbox mean (+ f16 sb copy) ----------
__global__ __launch_bounds__(256) void k_poolraw(
    const float* __restrict__ feats, const float* __restrict__ sfeats,
    const int* __restrict__ seg, float* __restrict__ pooled,
    float* __restrict__ sb, _Float16* __restrict__ sbH) {
  const int b = blockIdx.x, t = threadIdx.x;
  if (t >= 192) return;
  const int c2 = t * 2;
  const int n0 = __builtin_amdgcn_readfirstlane(seg[b]);
  const int n1 = __builtin_amdgcn_readfirstlane(seg[b + 1]);
  float2 fmx = {0.f, 0.f}, ss = {0.f, 0.f};
  for (int n = n0; n < n1; ++n) {
    const float2 f2 = *(const float2*)(feats + (size_t)n * FUS + c2);
    fmx.x = fmaxf(fmx.x, f2.x); fmx.y = fmaxf(fmx.y, f2.y);
    const float2 s2 = *(const float2*)(sfeats + (size_t)n * FUS + c2);
    ss.x += s2.x; ss.y += s2.y;
  }
  *(float2*)(pooled + (size_t)b * 1408 + 1024 + c2) = fmx;
  const float inv = 1.f / fmaxf((float)(n1 - n0), 1.f);
  float2 o = {ss.x * inv, ss.y * inv};
  *(float2*)(sb + (size_t)b * FUS + c2) = o;
  *(h2*)(sbH + (size_t)b * FUS + c2) = (h2){(_Float16)o.x, (_Float16)o.y};
}

// ---------- fusion_super = relu(sbH @ WfsH + bfs) on matrix cores ----------
// R5/R6: replaces the scalar-VALU k_fusion_super (83us @ 19TF effective).
// Same geometry as k_mlp1_mfma: block = 64 rows x 128 cols, K=384.
// Rows >= NB read garbage A (discarded: MFMA output row r depends only
// on A row r; epilogue writes only row < NB).
__global__ __launch_bounds__(256) void k_fsup_mfma(
    const _Float16* __restrict__ sbH, const _Float16* __restrict__ wh,
    const float* __restrict__ bfs, float* __restrict__ fs) {
  const int t = threadIdx.x, lane = t & 63, wv = t >> 6;
  const int nbase = blockIdx.x * 64;
  const int cg = blockIdx.y;
  const int m = lane & 15, quad = lane >> 4;
  f32x4 acc[4][2];
#pragma unroll
  for (int i = 0; i < 4; ++i)
#pragma unroll
    for (int nt = 0; nt < 2; ++nt) acc[i][nt] = (f32x4){0.f, 0.f, 0.f, 0.f};
  const _Float16* ap = sbH + (size_t)(nbase + m) * FUS + quad * 8;
  const _Float16* bp = wh + ((size_t)(cg * 8 + wv * 2) * 64 + lane) * 8;
#pragma unroll
  for (int ks = 0; ks < 12; ++ks) {
    const half8 b0 = *(const half8*)(bp + (size_t)ks * 32768);
    const half8 b1v = *(const half8*)(bp + (size_t)ks * 32768 + 512);
#pragma unroll
    for (int i = 0; i < 4; ++i) {
      const half8 a = *(const half8*)(ap + (size_t)(i * 16) * FUS + ks * 32);
      acc[i][0] = __builtin_amdgcn_mfma_f32_16x16x32_f16(a, b0, acc[i][0], 0, 0, 0);
      acc[i][1] = __builtin_amdgcn_mfma_f32_16x16x32_f16(a, b1v, acc[i][1], 0, 0, 0);
    }
  }
#pragma unroll
  for (int i = 0; i < 4; ++i)
#pragma unroll
    for (int nt = 0; nt < 2; ++nt) {
      const int gcol = cg * 128 + wv * 32 + nt * 16 + m;
      const float bias = bfs[gcol];
#pragma unroll
      for (int r = 0; r < 4; ++r) {
        const int row = nbase + i * 16 + quad * 4 + r;
        if (row < NB)
          fs[(size_t)row * 1024 + gcol] = fmaxf(acc[i][nt][r] + bias, 0.f);
      }
    }
}

// ---------- concat [pooled | fsup | sb] -> f16 bbH[NB_PAD][K1], zero-padded ----
__global__ __launch_bounds__(256) void k_cvt_cat(
    const float* __restrict__ pooled, const float* __restrict__ fsup,
    const float* __restrict__ sb, _Float16* __restrict__ bbH) {
  const size_t off = ((size_t)blockIdx.x * 256 + threadIdx.x) * 8;
  const int row = (int)(off / K1);
  const int col = (int)(off - (size_t)row * K1);
  half8 v;
  if (row < NB) {
    const float* src;
    if (col < 1408)      src = pooled + (size_t)row * 1408 + col;
    else if (col < 2432) src = fsup + (size_t)row * 1024 + (col - 1408);
    else                 src = sb + (size_t)row * FUS + (col - 2432);
    const float4 f0 = *(const float4*)src;
    const float4 f1 = *(const float4*)(src + 4);
    v[0] = (_Float16)f0.x; v[1] = (_Float16)f0.y;
    v[2] = (_Float16)f0.z; v[3] = (_Float16)f0.w;
    v[4] = (_Float16)f1.x; v[5] = (_Float16)f1.y;
    v[6] = (_Float16)f1.z; v[7] = (_Float16)f1.w;
  } else {
#pragma unroll
    for (int j = 0; j < 8; ++j) v[j] = (_Float16)0.f;
  }
  *(half8*)(bbH + off) = v;
}

// ---------- h1 = relu(bbH @ W1 + b1) on matrix cores ----------
__global__ __launch_bounds__(256) void k_mlp1_mfma(
    const _Float16* __restrict__ bbH, const _Float16* __restrict__ wh,
    const float* __restrict__ b1, float* __restrict__ h1) {
  const int t = threadIdx.x, lane = t & 63, wv = t >> 6;
  const int nbase = blockIdx.x * 64;
  const int cg = blockIdx.y;
  const int m = lane & 15, quad = lane >> 4;
  f32x4 acc[4][2];
#pragma unroll
  for (int i = 0; i < 4; ++i)
#pragma unroll
    for (int nt = 0; nt < 2; ++nt) acc[i][nt] = (f32x4){0.f, 0.f, 0.f, 0.f};
  const _Float16* ap = bbH + (size_t)(nbase + m) * K1 + quad * 8;
  const _Float16* bp = wh + ((size_t)(cg * 8 + wv * 2) * 64 + lane) * 8;
#pragma unroll 4
  for (int ks = 0; ks < 88; ++ks) {
    const half8 b0 = *(const half8*)(bp + (size_t)ks * 16384);
    const half8 b1v = *(const half8*)(bp + (size_t)ks * 16384 + 512);
#pragma unroll
    for (int i = 0; i < 4; ++i) {
      const half8 a = *(const half8*)(ap + (size_t)(i * 16) * K1 + ks * 32);
      acc[i][0] = __builtin_amdgcn_mfma_f32_16x16x32_f16(a, b0, acc[i][0], 0, 0, 0);
      acc[i][1] = __builtin_amdgcn_mfma_f32_16x16x32_f16(a, b1v, acc[i][1], 0, 0, 0);
    }
  }
#pragma unroll
  for (int i = 0; i < 4; ++i)
#pragma unroll
    for (int nt = 0; nt < 2; ++nt) {
      const int gcol = cg * 128 + wv * 32 + nt * 16 + m;
      const float bias = b1[gcol];
#pragma unroll
      for (int r = 0; r < 4; ++r) {
        const int row = nbase + i * 16 + quad * 4 + r;
        if (row < NB)
          h1[(size_t)row * 512 + gcol] = fmaxf(acc[i][nt][r] + bias, 0.f);
      }
    }
}

// ---------- h2 = relu(h1 @ W2 + b2) ----------
__global__ __launch_bounds__(256) void k_mlp2(
    const float* __restrict__ h1, const float* __restrict__ W2,
    const float* __restrict__ b2, float* __restrict__ h2o) {
  const int r0 = blockIdx.x * 8, t = threadIdx.x;
  float acc[8];
#pragma unroll
  for (int u = 0; u < 8; ++u) acc[u] = 0.f;
  for (int k = 0; k < 512; ++k) {
    float w = W2[(size_t)k * 256 + t];
#pragma unroll
    for (int u = 0; u < 8; ++u) acc[u] += h1[(size_t)(r0 + u) * 512 + k] * w;
  }
  float bv = b2[t];
#pragma unroll
  for (int u = 0; u < 8; ++u)
    h2o[(size_t)(r0 + u) * 256 + t] = fmaxf(acc[u] + bv, 0.f);
}

// ---------- logits = h2 @ W3 + b3 ----------
__global__ __launch_bounds__(256) void k_mlp3(
    const float* __restrict__ h2i, const float* __restrict__ W3,
    const float* __restrict__ b3, float* __restrict__ out) {
  const int r0 = blockIdx.x * 8, t = threadIdx.x;
  const int u = t >> 5, oc = t & 31;
  const float* x = h2i + (size_t)(r0 + u) * 256;
  float acc = 0.f;
  for (int k = 0; k < 256; ++k) acc += x[k] * W3[(size_t)k * 32 + oc];
  out[(size_t)(r0 + u) * 32 + oc] = acc + b3[oc];
}

extern "C" void kernel_launch(void* const* d_in, const int* in_sizes, int n_in,
                              void* d_out, int out_size, void* d_ws, size_t ws_size,
                              hipStream_t stream) {
  const float* x     = (const float*)d_in[0];
  const float* eattr = (const float*)d_in[1];
  const float* W_h   = (const float*)d_in[2];
  const float* b_h   = (const float*)d_in[3];
  const float* Ws_h  = (const float*)d_in[4];
  const float* bs_h  = (const float*)d_in[5];
  const float* Wb    = (const float*)d_in[6];
  const float* bb    = (const float*)d_in[7];
  const float* Wbs   = (const float*)d_in[8];
  const float* bbs   = (const float*)d_in[9];
  const float* W_f   = (const float*)d_in[10];
  const float* b_f   = (const float*)d_in[11];
  const float* W_fs  = (const float*)d_in[12];
  const float* b_fs  = (const float*)d_in[13];
  const float* W1    = (const float*)d_in[14];
  const float* b1    = (const float*)d_in[15];
  const float* W2    = (const float*)d_in[16];
  const float* b2    = (const float*)d_in[17];
  const float* W3    = (const float*)d_in[18];
  const float* b3    = (const float*)d_in[19];
  const int*   edge  = (const int*)d_in[20];
  const int*   bbox  = (const int*)d_in[21];
  float* out = (float*)d_out;

  // ---- workspace layout (~224 MB; known-good budget >= 233 MB) ----
  float* p = (float*)d_ws;
  float* feats  = p; p += (size_t)NN * FUS;
  float* sfeats = p; p += (size_t)NN * FUS;
  float* PQ     = p; p += (size_t)2 * NN * CH;    // 12.8M floats
  _Float16* PQi = (_Float16*)PQ;
  _Float16* Qi  = PQi + (size_t)NN * 256;
  // overlays inside PQ (live only AFTER the last k_conv2):
  _Float16* aPack = (_Float16*)PQ;                  // [0, 38.5MB) - read by pool
  _Float16* WfH   = aPack + (size_t)784 * 12 * 2048;
  float* pooled   = (float*)(WfH + (size_t)FUS * 1024);
  float* sb   = PQ;
  float* fsup = sb + (size_t)NB * FUS;
  float* h1   = fsup + (size_t)NB * 1024;
  float* h2b  = h1 + (size_t)NB * 512;
  _Float16* bbH = (_Float16*)(h2b + (size_t)NB * 256);
  _Float16* W1H = bbH + (size_t)NB_PAD * K1;
  // CSR payload + misc after PQ region:
  _Float16* sea8 = (_Float16*)p;
  int* ssrc    = (int*)(sea8 + (size_t)NE * 8);
  int* row_ptr = ssrc + NE;
  int* deg     = row_ptr + NN + 1;
  int* cursor  = deg + NN;
  int* seg     = cursor + NN;
  _Float16* WcatN = (_Float16*)(seg + NB + 1);      // 2 blocks x 128x256
  _Float16* WcatS = WcatN + (size_t)2 * 128 * 256;
  int* bsum = (int*)(WcatS + (size_t)2 * 128 * 256);
  // R6 FIX: sbH/WfsH live OUTSIDE the PQ overlay (R5 placed WfsH inside
  // aPack and k_cvtB stomped packed A-fragments before k_pool_mfma read
  // them -> absmax 15.7). Fresh tail space, 128B-aligned, +2.4MB.
  _Float16* sbH = (_Float16*)(((uintptr_t)(bsum + SCAN_NBLK) + 127) &
                              ~(uintptr_t)127);     // [NB_PAD][FUS] f16
  _Float16* WfsH = sbH + (size_t)NB_PAD * FUS;      // 384x1024 B-frags

  hipMemsetAsync(deg, 0, 2 * NN * sizeof(int), stream);  // deg + cursor

  // ---- CSR build (dst-sorted payload, parallel scan) + bbox segments ----
  k_deg<<<(NE + 255) / 256, 256, 0, stream>>>(edge, deg);
  k_scan1<<<SCAN_NBLK, 1024, 0, stream>>>(deg, row_ptr, bsum);
  k_scan2<<<1, 64, 0, stream>>>(bsum);
  k_scan3<<<(NN + 255) / 256, 256, 0, stream>>>(bsum, row_ptr);
  k_fill<<<(NE + 255) / 256, 256, 0, stream>>>(edge, eattr, row_ptr, cursor,
                                               ssrc, sea8);
  k_segstart<<<(NN + 255) / 256, 256, 0, stream>>>(bbox, seg);

  const int npq_grid = (NN + 31) / 32;

  // ---- conv 0 (head): both streams in one launch (blockIdx.y = sel) ----
  k_node_pq<<<dim3(npq_grid, 2), 256, 0, stream>>>(x, INCH, INCH, W_h, b_h,
                                                   Ws_h, bs_h, PQi, Qi);
  k_conv2<<<NN / 4, 256, 0, stream>>>(row_ptr, ssrc, sea8, PQi, Qi,
                                      W_h + 2 * INCH * CH, Ws_h + 2 * INCH * CH,
                                      feats, sfeats, 0, -1);

  // ---- residual blocks (K=128): weight prep hoisted, both blocks ----
  k_cvtWnpq<<<dim3(64, 2, 2), 64, 0, stream>>>(Wb, Wbs, WcatN, WcatS);
  for (int i = 0; i < 2; ++i) {
    const float* Wi  = Wb  + (size_t)i * 262 * CH;
    const float* bi  = bb  + (size_t)i * CH;
    const float* Wsi = Wbs + (size_t)i * 262 * CH;
    const float* bsi = bbs + (size_t)i * CH;
    k_npq_mfma<<<dim3((NN + 63) / 64, 2), 256, 0, stream>>>(
        feats + i * CH, sfeats + i * CH, FUS, WcatN + (size_t)i * 32768,
        WcatS + (size_t)i * 32768, bi, bsi, PQi, Qi);
    k_conv2<<<NN / 4, 256, 0, stream>>>(row_ptr, ssrc, sea8, PQi, Qi,
                                        Wi + 2 * CH * CH, Wsi + 2 * CH * CH,
                                        feats, sfeats, i + 1, i);
  }

  // ---- pooling: packed-A f16 convert + MFMA GEMM + atomicMax ----
  k_cvtApack<<<784 * 12, 64, 0, stream>>>(feats, aPack);
  k_cvtB<1024, 64><<<12 * 64, 64, 0, stream>>>(W_f, WfH);
  k_cvtB<1024, 64><<<12 * 64, 64, 0, stream>>>(W_fs, WfsH);
  hipMemsetAsync(pooled, 0, (size_t)NB * 1408 * sizeof(float), stream);
  k_pool_mfma<<<784 * 8, 256, 0, stream>>>(aPack, WfH, bbox, b_f, pooled);
  k_poolraw<<<NB, 256, 0, stream>>>(feats, sfeats, seg, pooled, sb, sbH);
  k_fsup_mfma<<<dim3(NB_PAD / 64, 8), 256, 0, stream>>>(sbH, WfsH, b_fs, fsup);

  // ---- head MLP: concat->f16, W1->f16 frag, MFMA GEMM, then small MLPs ----
  k_cvt_cat<<<(int)(((size_t)NB_PAD * K1 / 8) / 256), 256, 0, stream>>>(
      pooled, fsup, sb, bbH);
  k_cvtB<512, 32><<<88 * 32, 64, 0, stream>>>(W1, W1H);
  k_mlp1_mfma<<<dim3(NB_PAD / 64, 4), 256, 0, stream>>>(bbH, W1H, b1, h1);
  k_mlp2<<<NB / 8, 256, 0, stream>>>(h1, W2, b2, h2b);
  k_mlp3<<<NB / 8, 256, 0, stream>>>(h2b, W3, b3, out);
}

// Round 8
// 787.731 us; speedup vs baseline: 1.3775x; 1.0727x over previous
//
#include <hip/hip_runtime.h>
#include <stdint.h>

#define NN      50000
#define NN_PAD  50176   // 784 * 64
#define NE      800000
#define INCH    8
#define CH      128
#define EA      6
#define NB      2000
#define NB_PAD  2048
#define NCLS    32
#define FUS     384
#define K1      2816   // 1408 + 1024 + 384
#define SCAN_NBLK 49   // (NN + 1023) / 1024

typedef _Float16 half8 __attribute__((ext_vector_type(8)));
typedef _Float16 h2 __attribute__((ext_vector_type(2)));
typedef float f32x4 __attribute__((ext_vector_type(4)));

// ---------- degree of dst nodes ----------
__global__ __launch_bounds__(256) void k_deg(const int* __restrict__ edge,
                                             int* __restrict__ deg) {
  int e = blockIdx.x * 256 + threadIdx.x;
  if (e < NE) atomicAdd(&deg[edge[NE + e]], 1);
}

// ---------- parallel scan, phase 1: per-block inclusive scan + block sums ----
__global__ __launch_bounds__(1024) void k_scan1(const int* __restrict__ deg,
                                                int* __restrict__ row_ptr,
                                                int* __restrict__ bsum) {
  __shared__ int wsum[16];
  const int t = threadIdx.x, lane = t & 63, w = t >> 6;
  const int i = blockIdx.x * 1024 + t;
  int x = (i < NN) ? deg[i] : 0;
#pragma unroll
  for (int off = 1; off < 64; off <<= 1) {
    int y = __shfl_up(x, off, 64);
    if (lane >= off) x += y;
  }
  if (lane == 63) wsum[w] = x;
  __syncthreads();
  if (w == 0 && lane < 16) {
    int s = wsum[lane];
#pragma unroll
    for (int off = 1; off < 16; off <<= 1) {
      int y = __shfl_up(s, off, 64);
      if (lane >= off) s += y;
    }
    wsum[lane] = s;
  }
  __syncthreads();
  int incl = x + ((w == 0) ? 0 : wsum[w - 1]);
  if (i < NN) row_ptr[i + 1] = incl;
  if (t == 1023) bsum[blockIdx.x] = incl;
}

// ---------- phase 2: single-wave exclusive scan of block sums ----------
__global__ __launch_bounds__(64) void k_scan2(int* __restrict__ bsum) {
  const int t = threadIdx.x;
  int x = (t < SCAN_NBLK) ? bsum[t] : 0;
#pragma unroll
  for (int off = 1; off < 64; off <<= 1) {
    int y = __shfl_up(x, off, 64);
    if (t >= off) x += y;
  }
  int ex = __shfl_up(x, 1, 64);
  if (t == 0) ex = 0;
  if (t < SCAN_NBLK) bsum[t] = ex;
}

// ---------- phase 3: add block offsets ----------
__global__ __launch_bounds__(256) void k_scan3(const int* __restrict__ bsum,
                                               int* __restrict__ row_ptr) {
  const int i = blockIdx.x * 256 + threadIdx.x;
  if (i == 0) row_ptr[0] = 0;
  if (i < NN) row_ptr[i + 1] += bsum[i >> 10];
}

// ---------- fill CSR payload: dst-sorted src + f16 e_attr ----------
__global__ __launch_bounds__(256) void k_fill(
    const int* __restrict__ edge, const float* __restrict__ eattr,
    const int* __restrict__ row_ptr, int* __restrict__ cursor,
    int* __restrict__ ssrc, _Float16* __restrict__ sea8) {
  int e = blockIdx.x * 256 + threadIdx.x;
  if (e >= NE) return;
  int s = edge[e], d = edge[NE + e];
  int idx = row_ptr[d] + atomicAdd(&cursor[d], 1);
  ssrc[idx] = s;
  half8 v;
#pragma unroll
  for (int j = 0; j < EA; ++j) v[j] = (_Float16)eattr[(size_t)e * EA + j];
  v[6] = (_Float16)0.f; v[7] = (_Float16)0.f;
  *(half8*)(sea8 + (size_t)idx * 8) = v;
}

// ---------- segment starts from sorted bbox_idx ----------
__global__ __launch_bounds__(256) void k_segstart(const int* __restrict__ bbox,
                                                  int* __restrict__ seg) {
  int i = blockIdx.x * 256 + threadIdx.x;
  if (i >= NN) return;
  int bc = bbox[i];
  int bp = (i == 0) ? -1 : bbox[i - 1];
  for (int j = bp + 1; j <= bc; ++j) seg[j] = i;
  if (i == NN - 1)
    for (int j = bc + 1; j <= NB; ++j) seg[j] = NN;
}

// ---------- head node transform (K=8), both streams via blockIdx.y ----------
__global__ __launch_bounds__(256) void k_node_pq(
    const float* __restrict__ X, int ldx, int K,
    const float* __restrict__ WN, const float* __restrict__ bN,
    const float* __restrict__ WS, const float* __restrict__ bS,
    _Float16* __restrict__ PQi, _Float16* __restrict__ Qi) {
  const int sel = blockIdx.y;
  const float* W = sel ? WS : WN;
  const float* bias = sel ? bS : bN;
  const int t = threadIdx.x, lane = t & 63, wv = t >> 6;
  const int nbase = blockIdx.x * 32 + wv * 8;
  const int c = lane * 2;
  const float2 bv = *(const float2*)(bias + c);
  float2 pacc[8], qacc[8];
#pragma unroll
  for (int u = 0; u < 8; ++u) { pacc[u] = bv; qacc[u] = make_float2(0.f, 0.f); }
  const int xrow = min(nbase + (lane >> 3), NN - 1);
  const int xk = lane & 7;
  for (int k0 = 0; k0 < K; k0 += 8) {
    const float xv = X[(size_t)xrow * ldx + k0 + xk];
#pragma unroll
    for (int j = 0; j < 8; ++j) {
      const float2 w1 = *(const float2*)(W + (size_t)(k0 + j) * CH + c);
      const float2 w2 = *(const float2*)(W + (size_t)(K + k0 + j) * CH + c);
      const float2 wd = {w1.x - w2.x, w1.y - w2.y};
#pragma unroll
      for (int u = 0; u < 8; ++u) {
        const float xs = __shfl(xv, u * 8 + j, 64);
        pacc[u].x += xs * wd.x; pacc[u].y += xs * wd.y;
        qacc[u].x += xs * w2.x; qacc[u].y += xs * w2.y;
      }
    }
  }
#pragma unroll
  for (int u = 0; u < 8; ++u) {
    const int node = nbase + u;
    if (node < NN) {
      const size_t o = ((size_t)node * 64 + lane) * 4 + sel * 2;
      *(h2*)(PQi + o) = (h2){(_Float16)pacc[u].x, (_Float16)pacc[u].y};
      *(h2*)(Qi + o)  = (h2){(_Float16)qacc[u].x, (_Float16)qacc[u].y};
    }
  }
}

// ---------- pack [W1-W2 | W2] into f16 B-frags, both res-blocks (z) ----------
__global__ __launch_bounds__(64) void k_cvtWnpq(
    const float* __restrict__ WbAll, const float* __restrict__ WbsAll,
    _Float16* __restrict__ whN, _Float16* __restrict__ whS) {
  const int blk = blockIdx.z;
  const float* W = (blockIdx.y ? WbsAll : WbAll) + (size_t)blk * 262 * CH;
  _Float16* wh   = (blockIdx.y ? whS : whN) + (size_t)blk * 32768;
  const int c = blockIdx.x >> 4, tile = blockIdx.x & 15;
  const int L = threadIdx.x;
  const int n = tile * 16 + (L & 15);
  const int k0 = c * 32 + (L >> 4) * 8;
  half8 v;
#pragma unroll
  for (int j = 0; j < 8; ++j) {
    const int k = k0 + j;
    float val;
    if (n < CH) val = W[(size_t)k * CH + n] - W[(size_t)(CH + k) * CH + n];
    else        val = W[(size_t)(CH + k) * CH + (n - CH)];
    v[j] = (_Float16)val;
  }
  *(half8*)(wh + (((size_t)(c * 16 + tile)) * 64 + L) * 8) = v;
}

// ---------- residual node transform on matrix cores (both streams) ----------
// R7: X is now f16 row-major [node][FUS] -> direct half8 A loads, no cvts.
__global__ __launch_bounds__(256) void k_npq_mfma(
    const _Float16* __restrict__ Xn, const _Float16* __restrict__ Xs, int ldx,
    const _Float16* __restrict__ whN, const _Float16* __restrict__ whS,
    const float* __restrict__ biasN, const float* __restrict__ biasS,
    _Float16* __restrict__ PQi, _Float16* __restrict__ Qi) {
  const int sel = blockIdx.y;
  const _Float16* X = sel ? Xs : Xn;
  const _Float16* wh = sel ? whS : whN;
  const float* bias = sel ? biasS : biasN;
  const int t = threadIdx.x, lane = t & 63, wv = t >> 6;
  const int nbase = blockIdx.x * 64;
  const int m = lane & 15, quad = lane >> 4;
  f32x4 acc[4][4];
#pragma unroll
  for (int i = 0; i < 4; ++i)
#pragma unroll
    for (int nt = 0; nt < 4; ++nt) acc[i][nt] = (f32x4){0.f, 0.f, 0.f, 0.f};
#pragma unroll
  for (int ks = 0; ks < 4; ++ks) {
    half8 b[4];
#pragma unroll
    for (int nt = 0; nt < 4; ++nt)
      b[nt] = *(const half8*)(wh + (((size_t)(ks * 16 + wv * 4 + nt)) * 64 + lane) * 8);
#pragma unroll
    for (int i = 0; i < 4; ++i) {
      const int row = min(nbase + i * 16 + m, NN - 1);
      const half8 a = *(const half8*)(X + (size_t)row * ldx + ks * 32 + quad * 8);
#pragma unroll
      for (int nt = 0; nt < 4; ++nt)
        acc[i][nt] = __builtin_amdgcn_mfma_f32_16x16x32_f16(a, b[nt], acc[i][nt],
                                                            0, 0, 0);
    }
  }
#pragma unroll
  for (int i = 0; i < 4; ++i)
#pragma unroll
    for (int nt = 0; nt < 4; ++nt) {
      const int col = wv * 64 + nt * 16 + m;
      const float bv = (col < CH) ? bias[col] : 0.f;
#pragma unroll
      for (int r = 0; r < 4; ++r) {
        const int row = nbase + i * 16 + quad * 4 + r;
        if (row < NN) {
          const float v = acc[i][nt][r] + bv;
          if (col < CH)
            PQi[((size_t)row * 64 + (col >> 1)) * 4 + sel * 2 + (col & 1)] =
                (_Float16)v;
          else {
            const int qc = col - CH;
            Qi[((size_t)row * 64 + (qc >> 1)) * 4 + sel * 2 + (qc & 1)] =
                (_Float16)v;
          }
        }
      }
    }
}

// ---------- fused dual-stream CSR conv ----------
// R2: packed-f16 edge math + gather prefetch. R7: feats/sfeats stored f16
// (halves write + residual-read traffic); gather prefetch deepened to 8
// (VGPR headroom was large; more L3 latency overlap).
__global__ __launch_bounds__(256) void k_conv2(
    const int* __restrict__ row_ptr, const int* __restrict__ ssrc,
    const _Float16* __restrict__ sea8,
    const _Float16* __restrict__ PQi, const _Float16* __restrict__ Qi,
    const float* __restrict__ Cn, const float* __restrict__ Cs,
    _Float16* __restrict__ feats, _Float16* __restrict__ sfeats,
    int cur, int prev) {
  const int t = threadIdx.x;
  const int lane = t & 63;
  const int node = blockIdx.x * 4 + (t >> 6);
  const int c = lane * 2;
  h2 cwnh[EA], cwsh[EA];
#pragma unroll
  for (int j = 0; j < EA; ++j) {
    const float2 a = *(const float2*)(Cn + j * CH + c);
    const float2 b = *(const float2*)(Cs + j * CH + c);
    cwnh[j] = (h2){(_Float16)a.x, (_Float16)a.y};
    cwsh[j] = (h2){(_Float16)b.x, (_Float16)b.y};
  }
  int i0 = __builtin_amdgcn_readfirstlane(row_ptr[node]);
  int i1 = __builtin_amdgcn_readfirstlane(row_ptr[node + 1]);
  const uint2 qv = *(const uint2*)(Qi + ((size_t)node * 64 + lane) * 4);
  const h2 qnh = *(const h2*)&qv.x;
  const h2 qsh = *(const h2*)&qv.y;
  const _Float16* pqL = PQi + (size_t)lane * 4;  // + s*256 per edge
  h2 anh = (h2){(_Float16)0.f, (_Float16)0.f};
  float as0 = 0.f, as1 = 0.f;
  const h2 zero = (h2){(_Float16)0.f, (_Float16)0.f};
#define COMP(PV, J)                                                        \
  {                                                                        \
    unsigned w0 = __shfl((int)ea_l.x, (J), 64);                            \
    unsigned w1 = __shfl((int)ea_l.y, (J), 64);                            \
    unsigned w2 = __shfl((int)ea_l.z, (J), 64);                            \
    const h2 ea01 = *(const h2*)&w0;                                       \
    const h2 ea23 = *(const h2*)&w1;                                       \
    const h2 ea45 = *(const h2*)&w2;                                       \
    h2 vn = *(const h2*)&PV.x + qnh;                                       \
    h2 vs = *(const h2*)&PV.y + qsh;                                       \
    h2 b;                                                                  \
    b = (h2){ea01[0], ea01[0]}; vn += b * cwnh[0]; vs += b * cwsh[0];      \
    b = (h2){ea01[1], ea01[1]}; vn += b * cwnh[1]; vs += b * cwsh[1];      \
    b = (h2){ea23[0], ea23[0]}; vn += b * cwnh[2]; vs += b * cwsh[2];      \
    b = (h2){ea23[1], ea23[1]}; vn += b * cwnh[3]; vs += b * cwsh[3];      \
    b = (h2){ea45[0], ea45[0]}; vn += b * cwnh[4]; vs += b * cwsh[4];      \
    b = (h2){ea45[1], ea45[1]}; vn += b * cwnh[5]; vs += b * cwsh[5];      \
    anh = __builtin_elementwise_max(anh, vn);                              \
    const h2 vsr = __builtin_elementwise_max(vs, zero);                    \
    as0 += (float)vsr[0]; as1 += (float)vsr[1];                            \
  }
  for (int base = i0; base < i1; base += 64) {
    const int cnt = min(64, i1 - base);
    int s_l = 0;
    uint4 ea_l = {0u, 0u, 0u, 0u};
    if (lane < cnt) {
      s_l = ssrc[base + lane];
      ea_l = *(const uint4*)(sea8 + (size_t)(base + lane) * 8);
    }
    int j = 0;
    for (; j + 8 <= cnt; j += 8) {
      // 8 independent row gathers in flight before any compute
      const int s0 = __shfl(s_l, j, 64),     s1 = __shfl(s_l, j + 1, 64);
      const int s2 = __shfl(s_l, j + 2, 64), s3 = __shfl(s_l, j + 3, 64);
      const int s4 = __shfl(s_l, j + 4, 64), s5 = __shfl(s_l, j + 5, 64);
      const int s6 = __shfl(s_l, j + 6, 64), s7 = __shfl(s_l, j + 7, 64);
      const uint2 p0 = *(const uint2*)(pqL + (size_t)s0 * 256);
      const uint2 p1 = *(const uint2*)(pqL + (size_t)s1 * 256);
      const uint2 p2 = *(const uint2*)(pqL + (size_t)s2 * 256);
      const uint2 p3 = *(const uint2*)(pqL + (size_t)s3 * 256);
      const uint2 p4 = *(const uint2*)(pqL + (size_t)s4 * 256);
      const uint2 p5 = *(const uint2*)(pqL + (size_t)s5 * 256);
      const uint2 p6 = *(const uint2*)(pqL + (size_t)s6 * 256);
      const uint2 p7 = *(const uint2*)(pqL + (size_t)s7 * 256);
      COMP(p0, j)     COMP(p1, j + 1) COMP(p2, j + 2) COMP(p3, j + 3)
      COMP(p4, j + 4) COMP(p5, j + 5) COMP(p6, j + 6) COMP(p7, j + 7)
    }
    for (; j + 4 <= cnt; j += 4) {
      const int s0 = __shfl(s_l, j, 64),     s1 = __shfl(s_l, j + 1, 64);
      const int s2 = __shfl(s_l, j + 2, 64), s3 = __shfl(s_l, j + 3, 64);
      const uint2 p0 = *(const uint2*)(pqL + (size_t)s0 * 256);
      const uint2 p1 = *(const uint2*)(pqL + (size_t)s1 * 256);
      const uint2 p2 = *(const uint2*)(pqL + (size_t)s2 * 256);
      const uint2 p3 = *(const uint2*)(pqL + (size_t)s3 * 256);
      COMP(p0, j) COMP(p1, j + 1) COMP(p2, j + 2) COMP(p3, j + 3)
    }
    for (; j < cnt; ++j) {
      const int s0 = __shfl(s_l, j, 64);
      const uint2 p0 = *(const uint2*)(pqL + (size_t)s0 * 256);
      COMP(p0, j)
    }
  }
#undef COMP
  float an0 = (float)anh[0], an1 = (float)anh[1];
  const float inv = 1.f / fmaxf((float)(i1 - i0), 1.f);
  as0 *= inv; as1 *= inv;
  const size_t o = (size_t)node * FUS + (size_t)cur * CH + c;
  if (prev >= 0) {
    const size_t op = (size_t)node * FUS + (size_t)prev * CH + c;
    const h2 prn = *(const h2*)(feats + op);
    const h2 prs = *(const h2*)(sfeats + op);
    an0 += (float)prn[0]; an1 += (float)prn[1];
    as0 += (float)prs[0]; as1 += (float)prs[1];
  }
  *(h2*)(feats + o)  = (h2){(_Float16)an0, (_Float16)an1};
  *(h2*)(sfeats + o) = (h2){(_Float16)as0, (_Float16)as1};
}

// ---------- convert + pack W (KxN f32) into f16 B-fragment order ----------
template <int N, int NT>
__global__ __launch_bounds__(64) void k_cvtB(const float* __restrict__ W,
                                             _Float16* __restrict__ wh) {
  const int c = blockIdx.x / NT;
  const int tile = blockIdx.x % NT;
  const int L = threadIdx.x;
  const int n = tile * 16 + (L & 15);
  const int k0 = c * 32 + (L >> 4) * 8;
  half8 v;
#pragma unroll
  for (int j = 0; j < 8; ++j) v[j] = (_Float16)W[(size_t)(k0 + j) * N + n];
  *(half8*)(wh + (((size_t)(c * NT + tile)) * 64 + L) * 8) = v;
}

// ---------- fusion GEMM + segment max ----
// R0: cg fastest within XCD (FETCH 123->22MB). R1: two-phase epilogue.
// R4: LDS-staged A, dbuf + 2-deep prefetch. R7: A staged directly from
// row-major feats16 (k_cvtApack eliminated) -- per lane one 16B chunk;
// the 4 quads of a row cover a full 64B line so no overfetch. Rows >= NN
// read the zeroed pad (feats16 has NN_PAD rows).
__global__ __launch_bounds__(256, 6) void k_pool_mfma(
    const _Float16* __restrict__ feats16, const _Float16* __restrict__ wh,
    const int* __restrict__ bbox, const float* __restrict__ bf,
    float* __restrict__ pooled) {
  __shared__ float cl[32 * 132];
  __shared__ int s_bb[64];
  _Float16* abuf = (_Float16*)cl;  // 2 x 2048 halves (8KB), K-loop life only
  const int t = threadIdx.x, lane = t & 63, wv = t >> 6;
  const int fid = blockIdx.x;
  const int xcd = fid & 7, slot = fid >> 3;
  const int cg = slot & 7;
  const int rb = xcd * 98 + (slot >> 3);
  const int nbase = rb * 64;
  const int m = lane & 15, quad = lane >> 4;
  if (t < 64) s_bb[t] = bbox[min(nbase + t, NN - 1)];
  f32x4 acc[4][2];
#pragma unroll
  for (int i = 0; i < 4; ++i)
#pragma unroll
    for (int nt = 0; nt < 2; ++nt) acc[i][nt] = (f32x4){0.f, 0.f, 0.f, 0.f};
  // wave wv stages fragment i==wv of each K-chunk, from row-major feats16
  const _Float16* apc = feats16 + (size_t)(nbase + wv * 16 + m) * FUS + quad * 8;
  const _Float16* bp = wh + ((size_t)(cg * 8 + wv * 2) * 64 + lane) * 8;
  _Float16* wslot = abuf + wv * 512 + lane * 8;
  const _Float16* rbase = abuf + lane * 8;
  half8 b0 = *(const half8*)(bp);
  half8 b1 = *(const half8*)(bp + 512);
  half8 rA = *(const half8*)(apc);             // chunk 0 quarter
  *(half8*)(wslot) = rA;                       // -> buf0
  half8 rN = *(const half8*)(apc + 32);        // chunk 1 quarter
  __syncthreads();                             // buf0 ready (+ s_bb ordered)
#pragma unroll
  for (int ks = 0; ks < 12; ++ks) {
    const int cur = ks & 1;
    half8 nb0, nb1;
    if (ks < 11) {
      nb0 = *(const half8*)(bp + (size_t)(ks + 1) * 32768);
      nb1 = *(const half8*)(bp + (size_t)(ks + 1) * 32768 + 512);
    }
#pragma unroll
    for (int i = 0; i < 4; ++i) {
      const half8 a = *(const half8*)(rbase + cur * 2048 + i * 512);
      acc[i][0] = __builtin_amdgcn_mfma_f32_16x16x32_f16(a, b0, acc[i][0], 0, 0, 0);
      acc[i][1] = __builtin_amdgcn_mfma_f32_16x16x32_f16(a, b1, acc[i][1], 0, 0, 0);
    }
    if (ks < 11) {
      *(half8*)(wslot + (cur ^ 1) * 2048) = rN;   // stage chunk ks+1
      b0 = nb0; b1 = nb1;
    }
    if (ks < 10) rN = *(const half8*)(apc + (size_t)(ks + 2) * 32);
    __syncthreads();   // buf[cur^1] ready; all reads of buf[cur] done
  }
  const int col = t & 127, rh = t >> 7;
  const int gcol = cg * 128 + col;
  const float bias = bf[gcol];
#pragma unroll
  for (int p = 0; p < 2; ++p) {
    __syncthreads();  // p=1: phase-0 readers done with cl
#pragma unroll
    for (int ii = 0; ii < 2; ++ii)
#pragma unroll
      for (int nt = 0; nt < 2; ++nt) {
        const int scol = wv * 32 + nt * 16 + m;
#pragma unroll
        for (int r = 0; r < 4; ++r)
          cl[(ii * 16 + quad * 4 + r) * 132 + scol] = acc[p * 2 + ii][nt][r];
      }
    __syncthreads();
    int curb = -1;
    float mx = 0.f;
    for (int rr = 0; rr < 16; ++rr) {
      const int rl = rh * 16 + rr;
      const int node = nbase + p * 32 + rl;
      if (node >= NN) break;
      const int bid = s_bb[p * 32 + rl];
      const float v = fmaxf(cl[rl * 132 + col] + bias, 0.f);
      if (bid != curb) {
        if (curb >= 0)
          atomicMax((unsigned*)(pooled + (size_t)curb * 1408 + gcol),
                    __float_as_uint(mx));
        curb = bid;
        mx = v;
      } else {
        mx = fmaxf(mx, v);
      }
    }
    if (curb >= 0)
      atomicMax((unsigned*)(pooled + (size_t)curb * 1408 + gcol),
                __float_as_uint(mx));
  }
}

// ---------- raw-feats bbox max + sfeats bbox mean (+ f16 sb copy) ----------
__global__ __launch_bounds__(256) void k_poolraw(
    const _Float16* __restrict__ feats, const _Float16* __restrict__ sfeats,
    const int* __restrict__ seg, float* __restrict__ pooled,
    float* __restrict__ sb, _Float16* __restrict__ sbH) {
  const int b = blockIdx.x, t = threadIdx.x;
  if (t >= 192) return;
  const int c2 = t * 2;
  const int n0 = __builtin_amdgcn_readfirstlane(seg[b]);
  const int n1 = __builtin_amdgcn_readfirstlane(seg[b + 1]);
  float2 fmx = {0.f, 0.f}, ss = {0.f, 0.f};
  for (int n = n0; n < n1; ++n) {
    const h2 f2 = *(const h2*)(feats + (size_t)n * FUS + c2);
    fmx.x = fmaxf(fmx.x, (float)f2[0]); fmx.y = fmaxf(fmx.y, (float)f2[1]);
    const h2 s2 = *(const h2*)(sfeats + (size_t)n * FUS + c2);
    ss.x += (float)s2[0]; ss.y += (float)s2[1];
  }
  *(float2*)(pooled + (size_t)b * 1408 + 1024 + c2) = fmx;
  const float inv = 1.f / fmaxf((float)(n1 - n0), 1.f);
  float2 o = {ss.x * inv, ss.y * inv};
  *(float2*)(sb + (size_t)b * FUS + c2) = o;
  *(h2*)(sbH + (size_t)b * FUS + c2) = (h2){(_Float16)o.x, (_Float16)o.y};
}

// ---------- fusion_super = relu(sbH @ WfsH + bfs) on matrix cores ----------
__global__ __launch_bounds__(256) void k_fsup_mfma(
    const _Float16* __restrict__ sbH, const _Float16* __restrict__ wh,
    const float* __restrict__ bfs, float* __restrict__ fs) {
  const int t = threadIdx.x, lane = t & 63, wv = t >> 6;
  const int nbase = blockIdx.x * 64;
  const int cg = blockIdx.y;
  const int m = lane & 15, quad = lane >> 4;
  f32x4 acc[4][2];
#pragma unroll
  for (int i = 0; i < 4; ++i)
#pragma unroll
    for (int nt = 0; nt < 2; ++nt) acc[i][nt] = (f32x4){0.f, 0.f, 0.f, 0.f};
  const _Float16* ap = sbH + (size_t)(nbase + m) * FUS + quad * 8;
  const _Float16* bp = wh + ((size_t)(cg * 8 + wv * 2) * 64 + lane) * 8;
#pragma unroll
  for (int ks = 0; ks < 12; ++ks) {
    const half8 b0 = *(const half8*)(bp + (size_t)ks * 32768);
    const half8 b1v = *(const half8*)(bp + (size_t)ks * 32768 + 512);
#pragma unroll
    for (int i = 0; i < 4; ++i) {
      const half8 a = *(const half8*)(ap + (size_t)(i * 16) * FUS + ks * 32);
      acc[i][0] = __builtin_amdgcn_mfma_f32_16x16x32_f16(a, b0, acc[i][0], 0, 0, 0);
      acc[i][1] = __builtin_amdgcn_mfma_f32_16x16x32_f16(a, b1v, acc[i][1], 0, 0, 0);
    }
  }
#pragma unroll
  for (int i = 0; i < 4; ++i)
#pragma unroll
    for (int nt = 0; nt < 2; ++nt) {
      const int gcol = cg * 128 + wv * 32 + nt * 16 + m;
      const float bias = bfs[gcol];
#pragma unroll
      for (int r = 0; r < 4; ++r) {
        const int row = nbase + i * 16 + quad * 4 + r;
        if (row < NB)
          fs[(size_t)row * 1024 + gcol] = fmaxf(acc[i][nt][r] + bias, 0.f);
      }
    }
}

// ---------- concat [pooled | fsup | sb] -> f16 bbH[NB_PAD][K1], zero-padded ----
__global__ __launch_bounds__(256) void k_cvt_cat(
    const float* __restrict__ pooled, const float* __restrict__ fsup,
    const float* __restrict__ sb, _Float16* __restrict__ bbH) {
  const size_t off = ((size_t)blockIdx.x * 256 + threadIdx.x) * 8;
  const int row = (int)(off / K1);
  const int col = (int)(off - (size_t)row * K1);
  half8 v;
  if (row < NB) {
    const float* src;
    if (col < 1408)      src = pooled + (size_t)row * 1408 + col;
    else if (col < 2432) src = fsup + (size_t)row * 1024 + (col - 1408);
    else                 src = sb + (size_t)row * FUS + (col - 2432);
    const float4 f0 = *(const float4*)src;
    const float4 f1 = *(const float4*)(src + 4);
    v[0] = (_Float16)f0.x; v[1] = (_Float16)f0.y;
    v[2] = (_Float16)f0.z; v[3] = (_Float16)f0.w;
    v[4] = (_Float16)f1.x; v[5] = (_Float16)f1.y;
    v[6] = (_Float16)f1.z; v[7] = (_Float16)f1.w;
  } else {
#pragma unroll
    for (int j = 0; j < 8; ++j) v[j] = (_Float16)0.f;
  }
  *(half8*)(bbH + off) = v;
}

// ---------- h1 = relu(bbH @ W1 + b1) on matrix cores ----------
__global__ __launch_bounds__(256) void k_mlp1_mfma(
    const _Float16* __restrict__ bbH, const _Float16* __restrict__ wh,
    const float* __restrict__ b1, float* __restrict__ h1) {
  const int t = threadIdx.x, lane = t & 63, wv = t >> 6;
  const int nbase = blockIdx.x * 64;
  const int cg = blockIdx.y;
  const int m = lane & 15, quad = lane >> 4;
  f32x4 acc[4][2];
#pragma unroll
  for (int i = 0; i < 4; ++i)
#pragma unroll
    for (int nt = 0; nt < 2; ++nt) acc[i][nt] = (f32x4){0.f, 0.f, 0.f, 0.f};
  const _Float16* ap = bbH + (size_t)(nbase + m) * K1 + quad * 8;
  const _Float16* bp = wh + ((size_t)(cg * 8 + wv * 2) * 64 + lane) * 8;
#pragma unroll 4
  for (int ks = 0; ks < 88; ++ks) {
    const half8 b0 = *(const half8*)(bp + (size_t)ks * 16384);
    const half8 b1v = *(const half8*)(bp + (size_t)ks * 16384 + 512);
#pragma unroll
    for (int i = 0; i < 4; ++i) {
      const half8 a = *(const half8*)(ap + (size_t)(i * 16) * K1 + ks * 32);
      acc[i][0] = __builtin_amdgcn_mfma_f32_16x16x32_f16(a, b0, acc[i][0], 0, 0, 0);
      acc[i][1] = __builtin_amdgcn_mfma_f32_16x16x32_f16(a, b1v, acc[i][1], 0, 0, 0);
    }
  }
#pragma unroll
  for (int i = 0; i < 4; ++i)
#pragma unroll
    for (int nt = 0; nt < 2; ++nt) {
      const int gcol = cg * 128 + wv * 32 + nt * 16 + m;
      const float bias = b1[gcol];
#pragma unroll
      for (int r = 0; r < 4; ++r) {
        const int row = nbase + i * 16 + quad * 4 + r;
        if (row < NB)
          h1[(size_t)row * 512 + gcol] = fmaxf(acc[i][nt][r] + bias, 0.f);
      }
    }
}

// ---------- h2 = relu(h1 @ W2 + b2) ----------
__global__ __launch_bounds__(256) void k_mlp2(
    const float* __restrict__ h1, const float* __restrict__ W2,
    const float* __restrict__ b2, float* __restrict__ h2o) {
  const int r0 = blockIdx.x * 8, t = threadIdx.x;
  float acc[8];
#pragma unroll
  for (int u = 0; u < 8; ++u) acc[u] = 0.f;
  for (int k = 0; k < 512; ++k) {
    float w = W2[(size_t)k * 256 + t];
#pragma unroll
    for (int u = 0; u < 8; ++u) acc[u] += h1[(size_t)(r0 + u) * 512 + k] * w;
  }
  float bv = b2[t];
#pragma unroll
  for (int u = 0; u < 8; ++u)
    h2o[(size_t)(r0 + u) * 256 + t] = fmaxf(acc[u] + bv, 0.f);
}

// ---------- logits = h2 @ W3 + b3 ----------
__global__ __launch_bounds__(256) void k_mlp3(
    const float* __restrict__ h2i, const float* __restrict__ W3,
    const float* __restrict__ b3, float* __restrict__ out) {
  const int r0 = blockIdx.x * 8, t = threadIdx.x;
  const int u = t >> 5, oc = t & 31;
  const float* x = h2i + (size_t)(r0 + u) * 256;
  float acc = 0.f;
  for (int k = 0; k < 256; ++k) acc += x[k] * W3[(size_t)k * 32 + oc];
  out[(size_t)(r0 + u) * 32 + oc] = acc + b3[oc];
}

extern "C" void kernel_launch(void* const* d_in, const int* in_sizes, int n_in,
                              void* d_out, int out_size, void* d_ws, size_t ws_size,
                              hipStream_t stream) {
  const float* x     = (const float*)d_in[0];
  const float* eattr = (const float*)d_in[1];
  const float* W_h   = (const float*)d_in[2];
  const float* b_h   = (const float*)d_in[3];
  const float* Ws_h  = (const float*)d_in[4];
  const float* bs_h  = (const float*)d_in[5];
  const float* Wb    = (const float*)d_in[6];
  const float* bb    = (const float*)d_in[7];
  const float* Wbs   = (const float*)d_in[8];
  const float* bbs   = (const float*)d_in[9];
  const float* W_f   = (const float*)d_in[10];
  const float* b_f   = (const float*)d_in[11];
  const float* W_fs  = (const float*)d_in[12];
  const float* b_fs  = (const float*)d_in[13];
  const float* W1    = (const float*)d_in[14];
  const float* b1    = (const float*)d_in[15];
  const float* W2    = (const float*)d_in[16];
  const float* b2    = (const float*)d_in[17];
  const float* W3    = (const float*)d_in[18];
  const float* b3    = (const float*)d_in[19];
  const int*   edge  = (const int*)d_in[20];
  const int*   bbox  = (const int*)d_in[21];
  float* out = (float*)d_out;

  // ---- workspace layout (~150 MB; budget >= 233 MB) ----
  // R7: feats/sfeats stored f16 row-major with NN_PAD rows (pad zeroed).
  _Float16* feats  = (_Float16*)d_ws;                 // [NN_PAD][FUS] f16
  _Float16* sfeats = feats + (size_t)NN_PAD * FUS;    // [NN_PAD][FUS] f16
  float* PQ = (float*)(sfeats + (size_t)NN_PAD * FUS); // 12.8M floats
  _Float16* PQi = (_Float16*)PQ;
  _Float16* Qi  = PQi + (size_t)NN * 256;
  // overlays inside PQ (live only AFTER the last k_conv2):
  float* sb   = PQ;
  float* fsup = sb + (size_t)NB * FUS;
  float* h1   = fsup + (size_t)NB * 1024;
  float* h2b  = h1 + (size_t)NB * 512;
  _Float16* bbH = (_Float16*)(h2b + (size_t)NB * 256);
  _Float16* W1H = bbH + (size_t)NB_PAD * K1;          // ends ~31.9MB
  _Float16* WfH = (_Float16*)PQ + (size_t)784 * 12 * 2048;  // at 38.5MB
  float* pooled = (float*)(WfH + (size_t)FUS * 1024);
  // CSR payload + misc after PQ region:
  _Float16* sea8 = (_Float16*)(PQ + (size_t)2 * NN * CH);
  int* ssrc    = (int*)(sea8 + (size_t)NE * 8);
  int* row_ptr = ssrc + NE;
  int* deg     = row_ptr + NN + 1;
  int* cursor  = deg + NN;
  int* seg     = cursor + NN;
  _Float16* WcatN = (_Float16*)(seg + NB + 1);        // 2 blocks x 128x256
  _Float16* WcatS = WcatN + (size_t)2 * 128 * 256;
  int* bsum = (int*)(WcatS + (size_t)2 * 128 * 256);
  _Float16* sbH = (_Float16*)(((uintptr_t)(bsum + SCAN_NBLK) + 127) &
                              ~(uintptr_t)127);       // [NB_PAD][FUS] f16
  _Float16* WfsH = sbH + (size_t)NB_PAD * FUS;        // 384x1024 B-frags

  hipMemsetAsync(deg, 0, 2 * NN * sizeof(int), stream);  // deg + cursor
  // zero the feats16 pad rows (read by pool_mfma staging)
  hipMemsetAsync(feats + (size_t)NN * FUS, 0,
                 (size_t)(NN_PAD - NN) * FUS * sizeof(_Float16), stream);

  // ---- CSR build (dst-sorted payload, parallel scan) + bbox segments ----
  k_deg<<<(NE + 255) / 256, 256, 0, stream>>>(edge, deg);
  k_scan1<<<SCAN_NBLK, 1024, 0, stream>>>(deg, row_ptr, bsum);
  k_scan2<<<1, 64, 0, stream>>>(bsum);
  k_scan3<<<(NN + 255) / 256, 256, 0, stream>>>(bsum, row_ptr);
  k_fill<<<(NE + 255) / 256, 256, 0, stream>>>(edge, eattr, row_ptr, cursor,
                                               ssrc, sea8);
  k_segstart<<<(NN + 255) / 256, 256, 0, stream>>>(bbox, seg);

  const int npq_grid = (NN + 31) / 32;

  // ---- conv 0 (head): both streams in one launch (blockIdx.y = sel) ----
  k_node_pq<<<dim3(npq_grid, 2), 256, 0, stream>>>(x, INCH, INCH, W_h, b_h,
                                                   Ws_h, bs_h, PQi, Qi);
  k_conv2<<<NN / 4, 256, 0, stream>>>(row_ptr, ssrc, sea8, PQi, Qi,
                                      W_h + 2 * INCH * CH, Ws_h + 2 * INCH * CH,
                                      feats, sfeats, 0, -1);

  // ---- residual blocks (K=128): weight prep hoisted, both blocks ----
  k_cvtWnpq<<<dim3(64, 2, 2), 64, 0, stream>>>(Wb, Wbs, WcatN, WcatS);
  for (int i = 0; i < 2; ++i) {
    const float* Wi  = Wb  + (size_t)i * 262 * CH;
    const float* bi  = bb  + (size_t)i * CH;
    const float* Wsi = Wbs + (size_t)i * 262 * CH;
    const float* bsi = bbs + (size_t)i * CH;
    k_npq_mfma<<<dim3((NN + 63) / 64, 2), 256, 0, stream>>>(
        feats + i * CH, sfeats + i * CH, FUS, WcatN + (size_t)i * 32768,
        WcatS + (size_t)i * 32768, bi, bsi, PQi, Qi);
    k_conv2<<<NN / 4, 256, 0, stream>>>(row_ptr, ssrc, sea8, PQi, Qi,
                                        Wi + 2 * CH * CH, Wsi + 2 * CH * CH,
                                        feats, sfeats, i + 1, i);
  }

  // ---- pooling: MFMA GEMM direct from feats16 + atomicMax ----
  k_cvtB<1024, 64><<<12 * 64, 64, 0, stream>>>(W_f, WfH);
  k_cvtB<1024, 64><<<12 * 64, 64, 0, stream>>>(W_fs, WfsH);
  hipMemsetAsync(pooled, 0, (size_t)NB * 1408 * sizeof(float), stream);
  k_pool_mfma<<<784 * 8, 256, 0, stream>>>(feats, WfH, bbox, b_f, pooled);
  k_poolraw<<<NB, 256, 0, stream>>>(feats, sfeats, seg, pooled, sb, sbH);
  k_fsup_mfma<<<dim3(NB_PAD / 64, 8), 256, 0, stream>>>(sbH, WfsH, b_fs, fsup);

  // ---- head MLP: concat->f16, W1->f16 frag, MFMA GEMM, then small MLPs ----
  k_cvt_cat<<<(int)(((size_t)NB_PAD * K1 / 8) / 256), 256, 0, stream>>>(
      pooled, fsup, sb, bbH);
  k_cvtB<512, 32><<<88 * 32, 64, 0, stream>>>(W1, W1H);
  k_mlp1_mfma<<<dim3(NB_PAD / 64, 4), 256, 0, stream>>>(bbH, W1H, b1, h1);
  k_mlp2<<<NB / 8, 256, 0, stream>>>(h1, W2, b2, h2b);
  k_mlp3<<<NB / 8, 256, 0, stream>>>(h2b, W3, b3, out);
}

// Round 9
// 785.764 us; speedup vs baseline: 1.3809x; 1.0025x over previous
//
#include <hip/hip_runtime.h>
#include <stdint.h>

#define NN      50000
#define NN_PAD  50176   // 784 * 64
#define NE      800000
#define INCH    8
#define CH      128
#define EA      6
#define NB      2000
#define NB_PAD  2048
#define NCLS    32
#define FUS     384
#define K1      2816   // 1408 + 1024 + 384
#define SCAN_NBLK 49   // (NN + 1023) / 1024

typedef _Float16 half8 __attribute__((ext_vector_type(8)));
typedef _Float16 h2 __attribute__((ext_vector_type(2)));
typedef float f32x4 __attribute__((ext_vector_type(4)));

// ---------- degree of dst nodes ----------
__global__ __launch_bounds__(256) void k_deg(const int* __restrict__ edge,
                                             int* __restrict__ deg) {
  int e = blockIdx.x * 256 + threadIdx.x;
  if (e < NE) atomicAdd(&deg[edge[NE + e]], 1);
}

// ---------- parallel scan, phase 1: per-block inclusive scan + block sums ----
__global__ __launch_bounds__(1024) void k_scan1(const int* __restrict__ deg,
                                                int* __restrict__ row_ptr,
                                                int* __restrict__ bsum) {
  __shared__ int wsum[16];
  const int t = threadIdx.x, lane = t & 63, w = t >> 6;
  const int i = blockIdx.x * 1024 + t;
  int x = (i < NN) ? deg[i] : 0;
#pragma unroll
  for (int off = 1; off < 64; off <<= 1) {
    int y = __shfl_up(x, off, 64);
    if (lane >= off) x += y;
  }
  if (lane == 63) wsum[w] = x;
  __syncthreads();
  if (w == 0 && lane < 16) {
    int s = wsum[lane];
#pragma unroll
    for (int off = 1; off < 16; off <<= 1) {
      int y = __shfl_up(s, off, 64);
      if (lane >= off) s += y;
    }
    wsum[lane] = s;
  }
  __syncthreads();
  int incl = x + ((w == 0) ? 0 : wsum[w - 1]);
  if (i < NN) row_ptr[i + 1] = incl;
  if (t == 1023) bsum[blockIdx.x] = incl;
}

// ---------- phase 2: single-wave exclusive scan of block sums ----------
__global__ __launch_bounds__(64) void k_scan2(int* __restrict__ bsum) {
  const int t = threadIdx.x;
  int x = (t < SCAN_NBLK) ? bsum[t] : 0;
#pragma unroll
  for (int off = 1; off < 64; off <<= 1) {
    int y = __shfl_up(x, off, 64);
    if (t >= off) x += y;
  }
  int ex = __shfl_up(x, 1, 64);
  if (t == 0) ex = 0;
  if (t < SCAN_NBLK) bsum[t] = ex;
}

// ---------- phase 3: add block offsets ----------
__global__ __launch_bounds__(256) void k_scan3(const int* __restrict__ bsum,
                                               int* __restrict__ row_ptr) {
  const int i = blockIdx.x * 256 + threadIdx.x;
  if (i == 0) row_ptr[0] = 0;
  if (i < NN) row_ptr[i + 1] += bsum[i >> 10];
}

// ---------- fill CSR payload: dst-sorted src + f16 e_attr ----------
__global__ __launch_bounds__(256) void k_fill(
    const int* __restrict__ edge, const float* __restrict__ eattr,
    const int* __restrict__ row_ptr, int* __restrict__ cursor,
    int* __restrict__ ssrc, _Float16* __restrict__ sea8) {
  int e = blockIdx.x * 256 + threadIdx.x;
  if (e >= NE) return;
  int s = edge[e], d = edge[NE + e];
  int idx = row_ptr[d] + atomicAdd(&cursor[d], 1);
  ssrc[idx] = s;
  half8 v;
#pragma unroll
  for (int j = 0; j < EA; ++j) v[j] = (_Float16)eattr[(size_t)e * EA + j];
  v[6] = (_Float16)0.f; v[7] = (_Float16)0.f;
  *(half8*)(sea8 + (size_t)idx * 8) = v;
}

// ---------- segment starts from sorted bbox_idx ----------
__global__ __launch_bounds__(256) void k_segstart(const int* __restrict__ bbox,
                                                  int* __restrict__ seg) {
  int i = blockIdx.x * 256 + threadIdx.x;
  if (i >= NN) return;
  int bc = bbox[i];
  int bp = (i == 0) ? -1 : bbox[i - 1];
  for (int j = bp + 1; j <= bc; ++j) seg[j] = i;
  if (i == NN - 1)
    for (int j = bc + 1; j <= NB; ++j) seg[j] = NN;
}

// ---------- head node transform (K=8), both streams via blockIdx.y ----------
__global__ __launch_bounds__(256) void k_node_pq(
    const float* __restrict__ X, int ldx, int K,
    const float* __restrict__ WN, const float* __restrict__ bN,
    const float* __restrict__ WS, const float* __restrict__ bS,
    _Float16* __restrict__ PQi, _Float16* __restrict__ Qi) {
  const int sel = blockIdx.y;
  const float* W = sel ? WS : WN;
  const float* bias = sel ? bS : bN;
  const int t = threadIdx.x, lane = t & 63, wv = t >> 6;
  const int nbase = blockIdx.x * 32 + wv * 8;
  const int c = lane * 2;
  const float2 bv = *(const float2*)(bias + c);
  float2 pacc[8], qacc[8];
#pragma unroll
  for (int u = 0; u < 8; ++u) { pacc[u] = bv; qacc[u] = make_float2(0.f, 0.f); }
  const int xrow = min(nbase + (lane >> 3), NN - 1);
  const int xk = lane & 7;
  for (int k0 = 0; k0 < K; k0 += 8) {
    const float xv = X[(size_t)xrow * ldx + k0 + xk];
#pragma unroll
    for (int j = 0; j < 8; ++j) {
      const float2 w1 = *(const float2*)(W + (size_t)(k0 + j) * CH + c);
      const float2 w2 = *(const float2*)(W + (size_t)(K + k0 + j) * CH + c);
      const float2 wd = {w1.x - w2.x, w1.y - w2.y};
#pragma unroll
      for (int u = 0; u < 8; ++u) {
        const float xs = __shfl(xv, u * 8 + j, 64);
        pacc[u].x += xs * wd.x; pacc[u].y += xs * wd.y;
        qacc[u].x += xs * w2.x; qacc[u].y += xs * w2.y;
      }
    }
  }
#pragma unroll
  for (int u = 0; u < 8; ++u) {
    const int node = nbase + u;
    if (node < NN) {
      const size_t o = ((size_t)node * 64 + lane) * 4 + sel * 2;
      *(h2*)(PQi + o) = (h2){(_Float16)pacc[u].x, (_Float16)pacc[u].y};
      *(h2*)(Qi + o)  = (h2){(_Float16)qacc[u].x, (_Float16)qacc[u].y};
    }
  }
}

// ---------- pack [W1-W2 | W2] into f16 B-frags, both res-blocks (z) ----------
__global__ __launch_bounds__(64) void k_cvtWnpq(
    const float* __restrict__ WbAll, const float* __restrict__ WbsAll,
    _Float16* __restrict__ whN, _Float16* __restrict__ whS) {
  const int blk = blockIdx.z;
  const float* W = (blockIdx.y ? WbsAll : WbAll) + (size_t)blk * 262 * CH;
  _Float16* wh   = (blockIdx.y ? whS : whN) + (size_t)blk * 32768;
  const int c = blockIdx.x >> 4, tile = blockIdx.x & 15;
  const int L = threadIdx.x;
  const int n = tile * 16 + (L & 15);
  const int k0 = c * 32 + (L >> 4) * 8;
  half8 v;
#pragma unroll
  for (int j = 0; j < 8; ++j) {
    const int k = k0 + j;
    float val;
    if (n < CH) val = W[(size_t)k * CH + n] - W[(size_t)(CH + k) * CH + n];
    else        val = W[(size_t)(CH + k) * CH + (n - CH)];
    v[j] = (_Float16)val;
  }
  *(half8*)(wh + (((size_t)(c * 16 + tile)) * 64 + L) * 8) = v;
}

// ---------- residual node transform on matrix cores (both streams) ----------
// R7: X is f16 row-major [node][FUS] -> direct half8 A loads, no cvts.
__global__ __launch_bounds__(256) void k_npq_mfma(
    const _Float16* __restrict__ Xn, const _Float16* __restrict__ Xs, int ldx,
    const _Float16* __restrict__ whN, const _Float16* __restrict__ whS,
    const float* __restrict__ biasN, const float* __restrict__ biasS,
    _Float16* __restrict__ PQi, _Float16* __restrict__ Qi) {
  const int sel = blockIdx.y;
  const _Float16* X = sel ? Xs : Xn;
  const _Float16* wh = sel ? whS : whN;
  const float* bias = sel ? biasS : biasN;
  const int t = threadIdx.x, lane = t & 63, wv = t >> 6;
  const int nbase = blockIdx.x * 64;
  const int m = lane & 15, quad = lane >> 4;
  f32x4 acc[4][4];
#pragma unroll
  for (int i = 0; i < 4; ++i)
#pragma unroll
    for (int nt = 0; nt < 4; ++nt) acc[i][nt] = (f32x4){0.f, 0.f, 0.f, 0.f};
#pragma unroll
  for (int ks = 0; ks < 4; ++ks) {
    half8 b[4];
#pragma unroll
    for (int nt = 0; nt < 4; ++nt)
      b[nt] = *(const half8*)(wh + (((size_t)(ks * 16 + wv * 4 + nt)) * 64 + lane) * 8);
#pragma unroll
    for (int i = 0; i < 4; ++i) {
      const int row = min(nbase + i * 16 + m, NN - 1);
      const half8 a = *(const half8*)(X + (size_t)row * ldx + ks * 32 + quad * 8);
#pragma unroll
      for (int nt = 0; nt < 4; ++nt)
        acc[i][nt] = __builtin_amdgcn_mfma_f32_16x16x32_f16(a, b[nt], acc[i][nt],
                                                            0, 0, 0);
    }
  }
#pragma unroll
  for (int i = 0; i < 4; ++i)
#pragma unroll
    for (int nt = 0; nt < 4; ++nt) {
      const int col = wv * 64 + nt * 16 + m;
      const float bv = (col < CH) ? bias[col] : 0.f;
#pragma unroll
      for (int r = 0; r < 4; ++r) {
        const int row = nbase + i * 16 + quad * 4 + r;
        if (row < NN) {
          const float v = acc[i][nt][r] + bv;
          if (col < CH)
            PQi[((size_t)row * 64 + (col >> 1)) * 4 + sel * 2 + (col & 1)] =
                (_Float16)v;
          else {
            const int qc = col - CH;
            Qi[((size_t)row * 64 + (qc >> 1)) * 4 + sel * 2 + (qc & 1)] =
                (_Float16)v;
          }
        }
      }
    }
}

// ---------- fused dual-stream CSR conv ----------
// R2: packed-f16 edge math + gather prefetch. R7: f16 feats + 8-deep gathers.
__global__ __launch_bounds__(256) void k_conv2(
    const int* __restrict__ row_ptr, const int* __restrict__ ssrc,
    const _Float16* __restrict__ sea8,
    const _Float16* __restrict__ PQi, const _Float16* __restrict__ Qi,
    const float* __restrict__ Cn, const float* __restrict__ Cs,
    _Float16* __restrict__ feats, _Float16* __restrict__ sfeats,
    int cur, int prev) {
  const int t = threadIdx.x;
  const int lane = t & 63;
  const int node = blockIdx.x * 4 + (t >> 6);
  const int c = lane * 2;
  h2 cwnh[EA], cwsh[EA];
#pragma unroll
  for (int j = 0; j < EA; ++j) {
    const float2 a = *(const float2*)(Cn + j * CH + c);
    const float2 b = *(const float2*)(Cs + j * CH + c);
    cwnh[j] = (h2){(_Float16)a.x, (_Float16)a.y};
    cwsh[j] = (h2){(_Float16)b.x, (_Float16)b.y};
  }
  int i0 = __builtin_amdgcn_readfirstlane(row_ptr[node]);
  int i1 = __builtin_amdgcn_readfirstlane(row_ptr[node + 1]);
  const uint2 qv = *(const uint2*)(Qi + ((size_t)node * 64 + lane) * 4);
  const h2 qnh = *(const h2*)&qv.x;
  const h2 qsh = *(const h2*)&qv.y;
  const _Float16* pqL = PQi + (size_t)lane * 4;  // + s*256 per edge
  h2 anh = (h2){(_Float16)0.f, (_Float16)0.f};
  float as0 = 0.f, as1 = 0.f;
  const h2 zero = (h2){(_Float16)0.f, (_Float16)0.f};
#define COMP(PV, J)                                                        \
  {                                                                        \
    unsigned w0 = __shfl((int)ea_l.x, (J), 64);                            \
    unsigned w1 = __shfl((int)ea_l.y, (J), 64);                            \
    unsigned w2 = __shfl((int)ea_l.z, (J), 64);                            \
    const h2 ea01 = *(const h2*)&w0;                                       \
    const h2 ea23 = *(const h2*)&w1;                                       \
    const h2 ea45 = *(const h2*)&w2;                                       \
    h2 vn = *(const h2*)&PV.x + qnh;                                       \
    h2 vs = *(const h2*)&PV.y + qsh;                                       \
    h2 b;                                                                  \
    b = (h2){ea01[0], ea01[0]}; vn += b * cwnh[0]; vs += b * cwsh[0];      \
    b = (h2){ea01[1], ea01[1]}; vn += b * cwnh[1]; vs += b * cwsh[1];      \
    b = (h2){ea23[0], ea23[0]}; vn += b * cwnh[2]; vs += b * cwsh[2];      \
    b = (h2){ea23[1], ea23[1]}; vn += b * cwnh[3]; vs += b * cwsh[3];      \
    b = (h2){ea45[0], ea45[0]}; vn += b * cwnh[4]; vs += b * cwsh[4];      \
    b = (h2){ea45[1], ea45[1]}; vn += b * cwnh[5]; vs += b * cwsh[5];      \
    anh = __builtin_elementwise_max(anh, vn);                              \
    const h2 vsr = __builtin_elementwise_max(vs, zero);                    \
    as0 += (float)vsr[0]; as1 += (float)vsr[1];                            \
  }
  for (int base = i0; base < i1; base += 64) {
    const int cnt = min(64, i1 - base);
    int s_l = 0;
    uint4 ea_l = {0u, 0u, 0u, 0u};
    if (lane < cnt) {
      s_l = ssrc[base + lane];
      ea_l = *(const uint4*)(sea8 + (size_t)(base + lane) * 8);
    }
    int j = 0;
    for (; j + 8 <= cnt; j += 8) {
      // 8 independent row gathers in flight before any compute
      const int s0 = __shfl(s_l, j, 64),     s1 = __shfl(s_l, j + 1, 64);
      const int s2 = __shfl(s_l, j + 2, 64), s3 = __shfl(s_l, j + 3, 64);
      const int s4 = __shfl(s_l, j + 4, 64), s5 = __shfl(s_l, j + 5, 64);
      const int s6 = __shfl(s_l, j + 6, 64), s7 = __shfl(s_l, j + 7, 64);
      const uint2 p0 = *(const uint2*)(pqL + (size_t)s0 * 256);
      const uint2 p1 = *(const uint2*)(pqL + (size_t)s1 * 256);
      const uint2 p2 = *(const uint2*)(pqL + (size_t)s2 * 256);
      const uint2 p3 = *(const uint2*)(pqL + (size_t)s3 * 256);
      const uint2 p4 = *(const uint2*)(pqL + (size_t)s4 * 256);
      const uint2 p5 = *(const uint2*)(pqL + (size_t)s5 * 256);
      const uint2 p6 = *(const uint2*)(pqL + (size_t)s6 * 256);
      const uint2 p7 = *(const uint2*)(pqL + (size_t)s7 * 256);
      COMP(p0, j)     COMP(p1, j + 1) COMP(p2, j + 2) COMP(p3, j + 3)
      COMP(p4, j + 4) COMP(p5, j + 5) COMP(p6, j + 6) COMP(p7, j + 7)
    }
    for (; j + 4 <= cnt; j += 4) {
      const int s0 = __shfl(s_l, j, 64),     s1 = __shfl(s_l, j + 1, 64);
      const int s2 = __shfl(s_l, j + 2, 64), s3 = __shfl(s_l, j + 3, 64);
      const uint2 p0 = *(const uint2*)(pqL + (size_t)s0 * 256);
      const uint2 p1 = *(const uint2*)(pqL + (size_t)s1 * 256);
      const uint2 p2 = *(const uint2*)(pqL + (size_t)s2 * 256);
      const uint2 p3 = *(const uint2*)(pqL + (size_t)s3 * 256);
      COMP(p0, j) COMP(p1, j + 1) COMP(p2, j + 2) COMP(p3, j + 3)
    }
    for (; j < cnt; ++j) {
      const int s0 = __shfl(s_l, j, 64);
      const uint2 p0 = *(const uint2*)(pqL + (size_t)s0 * 256);
      COMP(p0, j)
    }
  }
#undef COMP
  float an0 = (float)anh[0], an1 = (float)anh[1];
  const float inv = 1.f / fmaxf((float)(i1 - i0), 1.f);
  as0 *= inv; as1 *= inv;
  const size_t o = (size_t)node * FUS + (size_t)cur * CH + c;
  if (prev >= 0) {
    const size_t op = (size_t)node * FUS + (size_t)prev * CH + c;
    const h2 prn = *(const h2*)(feats + op);
    const h2 prs = *(const h2*)(sfeats + op);
    an0 += (float)prn[0]; an1 += (float)prn[1];
    as0 += (float)prs[0]; as1 += (float)prs[1];
  }
  *(h2*)(feats + o)  = (h2){(_Float16)an0, (_Float16)an1};
  *(h2*)(sfeats + o) = (h2){(_Float16)as0, (_Float16)as1};
}

// ---------- convert + pack W (KxN f32) into f16 B-fragment order ----------
template <int N, int NT>
__global__ __launch_bounds__(64) void k_cvtB(const float* __restrict__ W,
                                             _Float16* __restrict__ wh) {
  const int c = blockIdx.x / NT;
  const int tile = blockIdx.x % NT;
  const int L = threadIdx.x;
  const int n = tile * 16 + (L & 15);
  const int k0 = c * 32 + (L >> 4) * 8;
  half8 v;
#pragma unroll
  for (int j = 0; j < 8; ++j) v[j] = (_Float16)W[(size_t)(k0 + j) * N + n];
  *(half8*)(wh + (((size_t)(c * NT + tile)) * 64 + L) * 8) = v;
}

// ---------- dual-source variant (merged launch for W_f / W_fs) ----------
template <int N, int NT>
__global__ __launch_bounds__(64) void k_cvtB2(const float* __restrict__ WA,
                                              const float* __restrict__ WB,
                                              _Float16* __restrict__ whA,
                                              _Float16* __restrict__ whB) {
  const float* W = blockIdx.y ? WB : WA;
  _Float16* wh   = blockIdx.y ? whB : whA;
  const int c = blockIdx.x / NT;
  const int tile = blockIdx.x % NT;
  const int L = threadIdx.x;
  const int n = tile * 16 + (L & 15);
  const int k0 = c * 32 + (L >> 4) * 8;
  half8 v;
#pragma unroll
  for (int j = 0; j < 8; ++j) v[j] = (_Float16)W[(size_t)(k0 + j) * N + n];
  *(half8*)(wh + (((size_t)(c * NT + tile)) * 64 + L) * 8) = v;
}

// ---------- fusion GEMM + segment max ----
// R0: cg fastest within XCD. R1: two-phase epilogue. R4: LDS-staged A.
// R7: A staged direct from row-major feats16. R8: phase-carry epilogue --
// phase p spills acc[p] and acc[p+2], so thread rh covers the CONTIGUOUS
// global rows 32*rh + 16*p + rr across both phases; the (curb,mx) run
// carries across phases and flushes once at the end. AtomicMax count
// drops 5.3M -> ~3.65M (-31%) -- the epilogue atomic stream is the
// hypothesized 77us bottleneck (K-loop is only ~480 MFMA-cyc/block).
__global__ __launch_bounds__(256, 6) void k_pool_mfma(
    const _Float16* __restrict__ feats16, const _Float16* __restrict__ wh,
    const int* __restrict__ bbox, const float* __restrict__ bf,
    float* __restrict__ pooled) {
  __shared__ float cl[32 * 132];
  __shared__ int s_bb[64];
  _Float16* abuf = (_Float16*)cl;  // 2 x 2048 halves (8KB), K-loop life only
  const int t = threadIdx.x, lane = t & 63, wv = t >> 6;
  const int fid = blockIdx.x;
  const int xcd = fid & 7, slot = fid >> 3;
  const int cg = slot & 7;
  const int rb = xcd * 98 + (slot >> 3);
  const int nbase = rb * 64;
  const int m = lane & 15, quad = lane >> 4;
  if (t < 64) s_bb[t] = bbox[min(nbase + t, NN - 1)];
  f32x4 acc[4][2];
#pragma unroll
  for (int i = 0; i < 4; ++i)
#pragma unroll
    for (int nt = 0; nt < 2; ++nt) acc[i][nt] = (f32x4){0.f, 0.f, 0.f, 0.f};
  // wave wv stages fragment i==wv of each K-chunk, from row-major feats16
  const _Float16* apc = feats16 + (size_t)(nbase + wv * 16 + m) * FUS + quad * 8;
  const _Float16* bp = wh + ((size_t)(cg * 8 + wv * 2) * 64 + lane) * 8;
  _Float16* wslot = abuf + wv * 512 + lane * 8;
  const _Float16* rbase = abuf + lane * 8;
  half8 b0 = *(const half8*)(bp);
  half8 b1 = *(const half8*)(bp + 512);
  half8 rA = *(const half8*)(apc);             // chunk 0 quarter
  *(half8*)(wslot) = rA;                       // -> buf0
  half8 rN = *(const half8*)(apc + 32);        // chunk 1 quarter
  __syncthreads();                             // buf0 ready (+ s_bb ordered)
#pragma unroll
  for (int ks = 0; ks < 12; ++ks) {
    const int cur = ks & 1;
    half8 nb0, nb1;
    if (ks < 11) {
      nb0 = *(const half8*)(bp + (size_t)(ks + 1) * 32768);
      nb1 = *(const half8*)(bp + (size_t)(ks + 1) * 32768 + 512);
    }
#pragma unroll
    for (int i = 0; i < 4; ++i) {
      const half8 a = *(const half8*)(rbase + cur * 2048 + i * 512);
      acc[i][0] = __builtin_amdgcn_mfma_f32_16x16x32_f16(a, b0, acc[i][0], 0, 0, 0);
      acc[i][1] = __builtin_amdgcn_mfma_f32_16x16x32_f16(a, b1, acc[i][1], 0, 0, 0);
    }
    if (ks < 11) {
      *(half8*)(wslot + (cur ^ 1) * 2048) = rN;   // stage chunk ks+1
      b0 = nb0; b1 = nb1;
    }
    if (ks < 10) rN = *(const half8*)(apc + (size_t)(ks + 2) * 32);
    __syncthreads();   // buf[cur^1] ready; all reads of buf[cur] done
  }
  const int col = t & 127, rh = t >> 7;
  const int gcol = cg * 128 + col;
  const float bias = bf[gcol];
  int curb = -1;
  float mx = 0.f;
#pragma unroll
  for (int p = 0; p < 2; ++p) {
    __syncthreads();  // p=1: phase-0 readers done with cl
#pragma unroll
    for (int ii = 0; ii < 2; ++ii)
#pragma unroll
      for (int nt = 0; nt < 2; ++nt) {
        const int scol = wv * 32 + nt * 16 + m;
#pragma unroll
        for (int r = 0; r < 4; ++r)
          cl[(ii * 16 + quad * 4 + r) * 132 + scol] = acc[p + 2 * ii][nt][r];
      }
    __syncthreads();
    for (int rr = 0; rr < 16; ++rr) {
      const int g = rh * 32 + p * 16 + rr;   // contiguous per-thread span
      const int node = nbase + g;
      if (node >= NN) break;
      const int bid = s_bb[g];
      const float v = fmaxf(cl[(rh * 16 + rr) * 132 + col] + bias, 0.f);
      if (bid != curb) {
        if (curb >= 0)
          atomicMax((unsigned*)(pooled + (size_t)curb * 1408 + gcol),
                    __float_as_uint(mx));
        curb = bid;
        mx = v;
      } else {
        mx = fmaxf(mx, v);
      }
    }
  }
  if (curb >= 0)
    atomicMax((unsigned*)(pooled + (size_t)curb * 1408 + gcol),
              __float_as_uint(mx));
}

// ---------- raw-feats bbox max + sfeats bbox mean (+ f16 sb copy) ----------
__global__ __launch_bounds__(256) void k_poolraw(
    const _Float16* __restrict__ feats, const _Float16* __restrict__ sfeats,
    const int* __restrict__ seg, float* __restrict__ pooled,
    float* __restrict__ sb, _Float16* __restrict__ sbH) {
  const int b = blockIdx.x, t = threadIdx.x;
  if (t >= 192) return;
  const int c2 = t * 2;
  const int n0 = __builtin_amdgcn_readfirstlane(seg[b]);
  const int n1 = __builtin_amdgcn_readfirstlane(seg[b + 1]);
  float2 fmx = {0.f, 0.f}, ss = {0.f, 0.f};
  for (int n = n0; n < n1; ++n) {
    const h2 f2 = *(const h2*)(feats + (size_t)n * FUS + c2);
    fmx.x = fmaxf(fmx.x, (float)f2[0]); fmx.y = fmaxf(fmx.y, (float)f2[1]);
    const h2 s2 = *(const h2*)(sfeats + (size_t)n * FUS + c2);
    ss.x += (float)s2[0]; ss.y += (float)s2[1];
  }
  *(float2*)(pooled + (size_t)b * 1408 + 1024 + c2) = fmx;
  const float inv = 1.f / fmaxf((float)(n1 - n0), 1.f);
  float2 o = {ss.x * inv, ss.y * inv};
  *(float2*)(sb + (size_t)b * FUS + c2) = o;
  *(h2*)(sbH + (size_t)b * FUS + c2) = (h2){(_Float16)o.x, (_Float16)o.y};
}

// ---------- fusion_super = relu(sbH @ WfsH + bfs) on matrix cores ----------
__global__ __launch_bounds__(256) void k_fsup_mfma(
    const _Float16* __restrict__ sbH, const _Float16* __restrict__ wh,
    const float* __restrict__ bfs, float* __restrict__ fs) {
  const int t = threadIdx.x, lane = t & 63, wv = t >> 6;
  const int nbase = blockIdx.x * 64;
  const int cg = blockIdx.y;
  const int m = lane & 15, quad = lane >> 4;
  f32x4 acc[4][2];
#pragma unroll
  for (int i = 0; i < 4; ++i)
#pragma unroll
    for (int nt = 0; nt < 2; ++nt) acc[i][nt] = (f32x4){0.f, 0.f, 0.f, 0.f};
  const _Float16* ap = sbH + (size_t)(nbase + m) * FUS + quad * 8;
  const _Float16* bp = wh + ((size_t)(cg * 8 + wv * 2) * 64 + lane) * 8;
#pragma unroll
  for (int ks = 0; ks < 12; ++ks) {
    const half8 b0 = *(const half8*)(bp + (size_t)ks * 32768);
    const half8 b1v = *(const half8*)(bp + (size_t)ks * 32768 + 512);
#pragma unroll
    for (int i = 0; i < 4; ++i) {
      const half8 a = *(const half8*)(ap + (size_t)(i * 16) * FUS + ks * 32);
      acc[i][0] = __builtin_amdgcn_mfma_f32_16x16x32_f16(a, b0, acc[i][0], 0, 0, 0);
      acc[i][1] = __builtin_amdgcn_mfma_f32_16x16x32_f16(a, b1v, acc[i][1], 0, 0, 0);
    }
  }
#pragma unroll
  for (int i = 0; i < 4; ++i)
#pragma unroll
    for (int nt = 0; nt < 2; ++nt) {
      const int gcol = cg * 128 + wv * 32 + nt * 16 + m;
      const float bias = bfs[gcol];
#pragma unroll
      for (int r = 0; r < 4; ++r) {
        const int row = nbase + i * 16 + quad * 4 + r;
        if (row < NB)
          fs[(size_t)row * 1024 + gcol] = fmaxf(acc[i][nt][r] + bias, 0.f);
      }
    }
}

// ---------- concat [pooled | fsup | sb] -> f16 bbH[NB_PAD][K1], zero-padded ----
__global__ __launch_bounds__(256) void k_cvt_cat(
    const float* __restrict__ pooled, const float* __restrict__ fsup,
    const float* __restrict__ sb, _Float16* __restrict__ bbH) {
  const size_t off = ((size_t)blockIdx.x * 256 + threadIdx.x) * 8;
  const int row = (int)(off / K1);
  const int col = (int)(off - (size_t)row * K1);
  half8 v;
  if (row < NB) {
    const float* src;
    if (col < 1408)      src = pooled + (size_t)row * 1408 + col;
    else if (col < 2432) src = fsup + (size_t)row * 1024 + (col - 1408);
    else                 src = sb + (size_t)row * FUS + (col - 2432);
    const float4 f0 = *(const float4*)src;
    const float4 f1 = *(const float4*)(src + 4);
    v[0] = (_Float16)f0.x; v[1] = (_Float16)f0.y;
    v[2] = (_Float16)f0.z; v[3] = (_Float16)f0.w;
    v[4] = (_Float16)f1.x; v[5] = (_Float16)f1.y;
    v[6] = (_Float16)f1.z; v[7] = (_Float16)f1.w;
  } else {
#pragma unroll
    for (int j = 0; j < 8; ++j) v[j] = (_Float16)0.f;
  }
  *(half8*)(bbH + off) = v;
}

// ---------- h1 = relu(bbH @ W1 + b1) on matrix cores ----------
__global__ __launch_bounds__(256) void k_mlp1_mfma(
    const _Float16* __restrict__ bbH, const _Float16* __restrict__ wh,
    const float* __restrict__ b1, float* __restrict__ h1) {
  const int t = threadIdx.x, lane = t & 63, wv = t >> 6;
  const int nbase = blockIdx.x * 64;
  const int cg = blockIdx.y;
  const int m = lane & 15, quad = lane >> 4;
  f32x4 acc[4][2];
#pragma unroll
  for (int i = 0; i < 4; ++i)
#pragma unroll
    for (int nt = 0; nt < 2; ++nt) acc[i][nt] = (f32x4){0.f, 0.f, 0.f, 0.f};
  const _Float16* ap = bbH + (size_t)(nbase + m) * K1 + quad * 8;
  const _Float16* bp = wh + ((size_t)(cg * 8 + wv * 2) * 64 + lane) * 8;
#pragma unroll 4
  for (int ks = 0; ks < 88; ++ks) {
    const half8 b0 = *(const half8*)(bp + (size_t)ks * 16384);
    const half8 b1v = *(const half8*)(bp + (size_t)ks * 16384 + 512);
#pragma unroll
    for (int i = 0; i < 4; ++i) {
      const half8 a = *(const half8*)(ap + (size_t)(i * 16) * K1 + ks * 32);
      acc[i][0] = __builtin_amdgcn_mfma_f32_16x16x32_f16(a, b0, acc[i][0], 0, 0, 0);
      acc[i][1] = __builtin_amdgcn_mfma_f32_16x16x32_f16(a, b1v, acc[i][1], 0, 0, 0);
    }
  }
#pragma unroll
  for (int i = 0; i < 4; ++i)
#pragma unroll
    for (int nt = 0; nt < 2; ++nt) {
      const int gcol = cg * 128 + wv * 32 + nt * 16 + m;
      const float bias = b1[gcol];
#pragma unroll
      for (int r = 0; r < 4; ++r) {
        const int row = nbase + i * 16 + quad * 4 + r;
        if (row < NB)
          h1[(size_t)row * 512 + gcol] = fmaxf(acc[i][nt][r] + bias, 0.f);
      }
    }
}

// ---------- h2 = relu(h1 @ W2 + b2) ----------
__global__ __launch_bounds__(256) void k_mlp2(
    const float* __restrict__ h1, const float* __restrict__ W2,
    const float* __restrict__ b2, float* __restrict__ h2o) {
  const int r0 = blockIdx.x * 8, t = threadIdx.x;
  float acc[8];
#pragma unroll
  for (int u = 0; u < 8; ++u) acc[u] = 0.f;
  for (int k = 0; k < 512; ++k) {
    float w = W2[(size_t)k * 256 + t];
#pragma unroll
    for (int u = 0; u < 8; ++u) acc[u] += h1[(size_t)(r0 + u) * 512 + k] * w;
  }
  float bv = b2[t];
#pragma unroll
  for (int u = 0; u < 8; ++u)
    h2o[(size_t)(r0 + u) * 256 + t] = fmaxf(acc[u] + bv, 0.f);
}

// ---------- logits = h2 @ W3 + b3 ----------
__global__ __launch_bounds__(256) void k_mlp3(
    const float* __restrict__ h2i, const float* __restrict__ W3,
    const float* __restrict__ b3, float* __restrict__ out) {
  const int r0 = blockIdx.x * 8, t = threadIdx.x;
  const int u = t >> 5, oc = t & 31;
  const float* x = h2i + (size_t)(r0 + u) * 256;
  float acc = 0.f;
  for (int k = 0; k < 256; ++k) acc += x[k] * W3[(size_t)k * 32 + oc];
  out[(size_t)(r0 + u) * 32 + oc] = acc + b3[oc];
}

extern "C" void kernel_launch(void* const* d_in, const int* in_sizes, int n_in,
                              void* d_out, int out_size, void* d_ws, size_t ws_size,
                              hipStream_t stream) {
  const float* x     = (const float*)d_in[0];
  const float* eattr = (const float*)d_in[1];
  const float* W_h   = (const float*)d_in[2];
  const float* b_h   = (const float*)d_in[3];
  const float* Ws_h  = (const float*)d_in[4];
  const float* bs_h  = (const float*)d_in[5];
  const float* Wb    = (const float*)d_in[6];
  const float* bb    = (const float*)d_in[7];
  const float* Wbs   = (const float*)d_in[8];
  const float* bbs   = (const float*)d_in[9];
  const float* W_f   = (const float*)d_in[10];
  const float* b_f   = (const float*)d_in[11];
  const float* W_fs  = (const float*)d_in[12];
  const float* b_fs  = (const float*)d_in[13];
  const float* W1    = (const float*)d_in[14];
  const float* b1    = (const float*)d_in[15];
  const float* W2    = (const float*)d_in[16];
  const float* b2    = (const float*)d_in[17];
  const float* W3    = (const float*)d_in[18];
  const float* b3    = (const float*)d_in[19];
  const int*   edge  = (const int*)d_in[20];
  const int*   bbox  = (const int*)d_in[21];
  float* out = (float*)d_out;

  // ---- workspace layout (~150 MB; budget >= 233 MB) ----
  _Float16* feats  = (_Float16*)d_ws;                 // [NN_PAD][FUS] f16
  _Float16* sfeats = feats + (size_t)NN_PAD * FUS;    // [NN_PAD][FUS] f16
  float* PQ = (float*)(sfeats + (size_t)NN_PAD * FUS); // 12.8M floats
  _Float16* PQi = (_Float16*)PQ;
  _Float16* Qi  = PQi + (size_t)NN * 256;
  // overlays inside PQ (live only AFTER the last k_conv2):
  float* sb   = PQ;
  float* fsup = sb + (size_t)NB * FUS;
  float* h1   = fsup + (size_t)NB * 1024;
  float* h2b  = h1 + (size_t)NB * 512;
  _Float16* bbH = (_Float16*)(h2b + (size_t)NB * 256);
  _Float16* W1H = bbH + (size_t)NB_PAD * K1;          // ends ~31.9MB
  _Float16* WfH = (_Float16*)PQ + (size_t)784 * 12 * 2048;  // at 38.5MB
  float* pooled = (float*)(WfH + (size_t)FUS * 1024);
  // CSR payload + misc after PQ region:
  _Float16* sea8 = (_Float16*)(PQ + (size_t)2 * NN * CH);
  int* ssrc    = (int*)(sea8 + (size_t)NE * 8);
  int* row_ptr = ssrc + NE;
  int* deg     = row_ptr + NN + 1;
  int* cursor  = deg + NN;
  int* seg     = cursor + NN;
  _Float16* WcatN = (_Float16*)(seg + NB + 1);        // 2 blocks x 128x256
  _Float16* WcatS = WcatN + (size_t)2 * 128 * 256;
  int* bsum = (int*)(WcatS + (size_t)2 * 128 * 256);
  _Float16* sbH = (_Float16*)(((uintptr_t)(bsum + SCAN_NBLK) + 127) &
                              ~(uintptr_t)127);       // [NB_PAD][FUS] f16
  _Float16* WfsH = sbH + (size_t)NB_PAD * FUS;        // 384x1024 B-frags

  hipMemsetAsync(deg, 0, 2 * NN * sizeof(int), stream);  // deg + cursor
  // zero the feats16 pad rows (read by pool_mfma staging)
  hipMemsetAsync(feats + (size_t)NN * FUS, 0,
                 (size_t)(NN_PAD - NN) * FUS * sizeof(_Float16), stream);

  // ---- CSR build (dst-sorted payload, parallel scan) + bbox segments ----
  k_deg<<<(NE + 255) / 256, 256, 0, stream>>>(edge, deg);
  k_scan1<<<SCAN_NBLK, 1024, 0, stream>>>(deg, row_ptr, bsum);
  k_scan2<<<1, 64, 0, stream>>>(bsum);
  k_scan3<<<(NN + 255) / 256, 256, 0, stream>>>(bsum, row_ptr);
  k_fill<<<(NE + 255) / 256, 256, 0, stream>>>(edge, eattr, row_ptr, cursor,
                                               ssrc, sea8);
  k_segstart<<<(NN + 255) / 256, 256, 0, stream>>>(bbox, seg);

  const int npq_grid = (NN + 31) / 32;

  // ---- conv 0 (head): both streams in one launch (blockIdx.y = sel) ----
  k_node_pq<<<dim3(npq_grid, 2), 256, 0, stream>>>(x, INCH, INCH, W_h, b_h,
                                                   Ws_h, bs_h, PQi, Qi);
  k_conv2<<<NN / 4, 256, 0, stream>>>(row_ptr, ssrc, sea8, PQi, Qi,
                                      W_h + 2 * INCH * CH, Ws_h + 2 * INCH * CH,
                                      feats, sfeats, 0, -1);

  // ---- residual blocks (K=128): weight prep hoisted, both blocks ----
  k_cvtWnpq<<<dim3(64, 2, 2), 64, 0, stream>>>(Wb, Wbs, WcatN, WcatS);
  for (int i = 0; i < 2; ++i) {
    const float* Wi  = Wb  + (size_t)i * 262 * CH;
    const float* bi  = bb  + (size_t)i * CH;
    const float* Wsi = Wbs + (size_t)i * 262 * CH;
    const float* bsi = bbs + (size_t)i * CH;
    k_npq_mfma<<<dim3((NN + 63) / 64, 2), 256, 0, stream>>>(
        feats + i * CH, sfeats + i * CH, FUS, WcatN + (size_t)i * 32768,
        WcatS + (size_t)i * 32768, bi, bsi, PQi, Qi);
    k_conv2<<<NN / 4, 256, 0, stream>>>(row_ptr, ssrc, sea8, PQi, Qi,
                                        Wi + 2 * CH * CH, Wsi + 2 * CH * CH,
                                        feats, sfeats, i + 1, i);
  }

  // ---- pooling: MFMA GEMM direct from feats16 + phase-carry atomicMax ----
  k_cvtB2<1024, 64><<<dim3(12 * 64, 2), 64, 0, stream>>>(W_f, W_fs, WfH, WfsH);
  hipMemsetAsync(pooled, 0, (size_t)NB * 1408 * sizeof(float), stream);
  k_pool_mfma<<<784 * 8, 256, 0, stream>>>(feats, WfH, bbox, b_f, pooled);
  k_poolraw<<<NB, 256, 0, stream>>>(feats, sfeats, seg, pooled, sb, sbH);
  k_fsup_mfma<<<dim3(NB_PAD / 64, 8), 256, 0, stream>>>(sbH, WfsH, b_fs, fsup);

  // ---- head MLP: concat->f16, W1->f16 frag, MFMA GEMM, then small MLPs ----
  k_cvt_cat<<<(int)(((size_t)NB_PAD * K1 / 8) / 256), 256, 0, stream>>>(
      pooled, fsup, sb, bbH);
  k_cvtB<512, 32><<<88 * 32, 64, 0, stream>>>(W1, W1H);
  k_mlp1_mfma<<<dim3(NB_PAD / 64, 4), 256, 0, stream>>>(bbH, W1H, b1, h1);
  k_mlp2<<<NB / 8, 256, 0, stream>>>(h1, W2, b2, h2b);
  k_mlp3<<<NB / 8, 256, 0, stream>>>(h2b, W3, b3, out);
}